// Round 1
// baseline (1052.762 us; speedup 1.0000x reference)
//
#include <hip/hip_runtime.h>
#include <cstdint>
#include <cstddef>

#define NEG_SLOPE 0.2f

__device__ __forceinline__ float lrelu(float v) { return v > 0.f ? v : NEG_SLOPE * v; }

// ---------------- CSR build ----------------
__global__ void k_count(const int* __restrict__ ei, int E, int* __restrict__ counts) {
    int i = blockIdx.x * blockDim.x + threadIdx.x;
    if (i < E) atomicAdd(&counts[ei[E + i]], 1);
}

__global__ void k_scan(const int* __restrict__ counts, int* __restrict__ indptr,
                       int* __restrict__ cursor, int Nn) {
    __shared__ int sdata[1024];
    int tid = threadIdx.x;
    int chunk = (Nn + 1023) >> 10;
    int start = tid * chunk;
    int end = start + chunk; if (end > Nn) end = Nn;
    int local = 0;
    for (int i = start; i < end; ++i) local += counts[i];
    sdata[tid] = local;
    __syncthreads();
    for (int off = 1; off < 1024; off <<= 1) {
        int v = (tid >= off) ? sdata[tid - off] : 0;
        __syncthreads();
        sdata[tid] += v;
        __syncthreads();
    }
    int run = sdata[tid] - local;  // exclusive prefix
    for (int i = start; i < end; ++i) {
        indptr[i] = run; cursor[i] = run; run += counts[i];
    }
    if (tid == 0) indptr[Nn] = sdata[1023];
}

__global__ void k_scatter(const int* __restrict__ ei, int E, int* __restrict__ cursor,
                          int* __restrict__ csr_src) {
    int i = blockIdx.x * blockDim.x + threadIdx.x;
    if (i < E) {
        int s = ei[i], d = ei[E + i];
        int pos = atomicAdd(&cursor[d], 1);
        csr_src[pos] = s;
    }
}

// ---------------- f32 GEMM: C[N,M] = A[N,K] @ W[K,M] ----------------
// 64x64 tile, 256 threads, 4x4 acc per thread, K step 32.
__global__ __launch_bounds__(256) void k_gemm(const float* __restrict__ A,
                                              const float* __restrict__ W,
                                              float* __restrict__ C,
                                              int Nrows, int K, int M) {
    __shared__ float As[32][68];   // transposed [k][row], pad for banks/alignment
    __shared__ float Ws[32][64];   // [k][col]
    int tid = threadIdx.x;
    int tx = tid & 15, ty = tid >> 4;
    int row0 = blockIdx.x * 64;
    int col0 = blockIdx.y * 64;

    float acc[4][4] = {};

    for (int k0 = 0; k0 < K; k0 += 32) {
        // A tile: 64 rows x 32 k. thread: kk=(tid&7)*4, row=tid>>3 (+32)
        int kk = (tid & 7) * 4;
        int arow = tid >> 3;
        #pragma unroll
        for (int p = 0; p < 2; ++p) {
            int r = arow + p * 32;
            int gr = row0 + r;
            float4 v = make_float4(0.f, 0.f, 0.f, 0.f);
            if (gr < Nrows)
                v = *reinterpret_cast<const float4*>(&A[(size_t)gr * K + k0 + kk]);
            As[kk + 0][r] = v.x; As[kk + 1][r] = v.y;
            As[kk + 2][r] = v.z; As[kk + 3][r] = v.w;
        }
        // W tile: 32 k x 64 cols. thread: col=tx*4, kr=ty (+16)
        int wc = tx * 4;
        #pragma unroll
        for (int p = 0; p < 2; ++p) {
            int kr = ty + p * 16;
            float4 v = *reinterpret_cast<const float4*>(&W[(size_t)(k0 + kr) * M + col0 + wc]);
            *reinterpret_cast<float4*>(&Ws[kr][wc]) = v;
        }
        __syncthreads();
        #pragma unroll
        for (int k = 0; k < 32; ++k) {
            float4 av = *reinterpret_cast<const float4*>(&As[k][ty * 4]);
            float4 wv = *reinterpret_cast<const float4*>(&Ws[k][tx * 4]);
            float a_[4] = {av.x, av.y, av.z, av.w};
            float w_[4] = {wv.x, wv.y, wv.z, wv.w};
            #pragma unroll
            for (int i = 0; i < 4; ++i)
                #pragma unroll
                for (int j = 0; j < 4; ++j)
                    acc[i][j] += a_[i] * w_[j];
        }
        __syncthreads();
    }

    #pragma unroll
    for (int i = 0; i < 4; ++i) {
        int gr = row0 + ty * 4 + i;
        if (gr < Nrows) {
            float4 o = make_float4(acc[i][0], acc[i][1], acc[i][2], acc[i][3]);
            *reinterpret_cast<float4*>(&C[(size_t)gr * M + col0 + tx * 4]) = o;
        }
    }
}

// ---------------- attention coefficients: al_s[n,h] = <h[n,h,:], a_src[h,:]> ----------------
template <int D, int H>   // D = H*64
__global__ void k_attn(const float* __restrict__ h, const float* __restrict__ a_src,
                       const float* __restrict__ a_dst, float* __restrict__ al_s,
                       float* __restrict__ al_d, int Nn) {
    constexpr int VEC = D / 64;
    constexpr int GRP = 64 / H;   // lanes per head
    int wid = (blockIdx.x * blockDim.x + threadIdx.x) >> 6;
    int lane = threadIdx.x & 63;
    if (wid >= Nn) return;
    const float* hp = h + (size_t)wid * D + lane * VEC;
    float s = 0.f, d = 0.f;
    if constexpr (VEC == 4) {
        float4 hv = *reinterpret_cast<const float4*>(hp);
        float4 as = *reinterpret_cast<const float4*>(&a_src[lane * 4]);
        float4 ad = *reinterpret_cast<const float4*>(&a_dst[lane * 4]);
        s = hv.x * as.x + hv.y * as.y + hv.z * as.z + hv.w * as.w;
        d = hv.x * ad.x + hv.y * ad.y + hv.z * ad.z + hv.w * ad.w;
    } else {
        float hv = hp[0];
        s = hv * a_src[lane];
        d = hv * a_dst[lane];
    }
    #pragma unroll
    for (int off = 1; off < GRP; off <<= 1) {
        s += __shfl_xor(s, off);
        d += __shfl_xor(d, off);
    }
    if ((lane & (GRP - 1)) == 0) {
        int head = lane / GRP;
        al_s[(size_t)wid * H + head] = s;
        al_d[(size_t)wid * H + head] = d;
    }
}

// ---------------- fused softmax + aggregate (wave per destination node) ----------------
template <int H, bool ACT>    // TOT = H*64
__global__ void k_agg(const float* __restrict__ hlin, const float* __restrict__ al_s,
                      const float* __restrict__ al_d, const int* __restrict__ indptr,
                      const int* __restrict__ csr_src, const float* __restrict__ bias,
                      float* __restrict__ outf, int Nn) {
    constexpr int TOT = H * 64;
    constexpr int VEC = TOT / 64;
    int wid = (blockIdx.x * blockDim.x + threadIdx.x) >> 6;
    int lane = threadIdx.x & 63;
    if (wid >= Nn) return;
    int d = wid;
    int head = (lane * VEC) >> 6;    // H=4 -> lane>>4 ; H=1 -> 0

    float adh = al_d[(size_t)d * H + head];
    float e_self = lrelu(al_s[(size_t)d * H + head] + adh);
    int p0 = indptr[d], p1 = indptr[d + 1];

    // pass 1: max
    float m = e_self;
    for (int e = p0; e < p1; ++e) {
        int s = csr_src[e];
        m = fmaxf(m, lrelu(al_s[(size_t)s * H + head] + adh));
    }
    // pass 2: denom
    float den = __expf(e_self - m);
    for (int e = p0; e < p1; ++e) {
        int s = csr_src[e];
        den += __expf(lrelu(al_s[(size_t)s * H + head] + adh) - m);
    }
    den = 1.f / den;

    // pass 3: aggregate
    float accv[VEC] = {};
    {
        float alpha = __expf(e_self - m) * den;
        const float* hp = hlin + (size_t)d * TOT + lane * VEC;
        if constexpr (VEC == 4) {
            float4 hv = *reinterpret_cast<const float4*>(hp);
            accv[0] += alpha * hv.x; accv[1] += alpha * hv.y;
            accv[2] += alpha * hv.z; accv[3] += alpha * hv.w;
        } else {
            accv[0] += alpha * hp[0];
        }
    }
    for (int e = p0; e < p1; ++e) {
        int s = csr_src[e];
        float alpha = __expf(lrelu(al_s[(size_t)s * H + head] + adh) - m) * den;
        const float* hp = hlin + (size_t)s * TOT + lane * VEC;
        if constexpr (VEC == 4) {
            float4 hv = *reinterpret_cast<const float4*>(hp);
            accv[0] += alpha * hv.x; accv[1] += alpha * hv.y;
            accv[2] += alpha * hv.z; accv[3] += alpha * hv.w;
        } else {
            accv[0] += alpha * hp[0];
        }
    }

    #pragma unroll
    for (int v = 0; v < VEC; ++v) {
        int c = lane * VEC + v;
        float o = accv[v] + bias[c];
        if (ACT) o = o > 0.f ? o : expm1f(o);
        accv[v] = o;
    }
    if constexpr (VEC == 4) {
        float4 o = make_float4(accv[0], accv[1], accv[2], accv[3]);
        *reinterpret_cast<float4*>(&outf[(size_t)d * TOT + lane * 4]) = o;
    } else {
        outf[(size_t)d * TOT + lane] = accv[0];
    }
}

// ---------------- global mean pool (accumulate) ----------------
__global__ void k_pool(const float* __restrict__ feat, const int* __restrict__ batch,
                       float* __restrict__ gsum, int* __restrict__ gcnt, int Nn) {
    int node = blockIdx.x * 4 + (threadIdx.x >> 6);
    int lane = threadIdx.x & 63;
    if (node >= Nn) return;
    int g = batch[node];
    atomicAdd(&gsum[(size_t)g * 64 + lane], feat[(size_t)node * 64 + lane]);
    if (lane == 0) atomicAdd(&gcnt[g], 1);
}

// ---------------- final linear ----------------
__global__ void k_final(const float* __restrict__ gsum, const int* __restrict__ gcnt,
                        const float* __restrict__ lin_w, const float* __restrict__ lin_b,
                        float* __restrict__ out, int Gn) {
    int g = (blockIdx.x * blockDim.x + threadIdx.x) >> 6;
    int lane = threadIdx.x & 63;
    if (g >= Gn) return;
    float cnt = (float)gcnt[g];
    float inv = 1.f / fmaxf(cnt, 1.f);
    float v = gsum[(size_t)g * 64 + lane] * inv * lin_w[lane];
    #pragma unroll
    for (int off = 32; off >= 1; off >>= 1) v += __shfl_xor(v, off);
    if (lane == 0) out[g] = v + lin_b[0];
}

extern "C" void kernel_launch(void* const* d_in, const int* in_sizes, int n_in,
                              void* d_out, int out_size, void* d_ws, size_t ws_size,
                              hipStream_t stream) {
    const float* x    = (const float*)d_in[0];
    const int*   ei   = (const int*)d_in[1];
    const int*   batch= (const int*)d_in[2];
    const float* W1   = (const float*)d_in[3];
    const float* a1s  = (const float*)d_in[4];
    const float* a1d  = (const float*)d_in[5];
    const float* b1   = (const float*)d_in[6];
    const float* W2   = (const float*)d_in[7];
    const float* a2s  = (const float*)d_in[8];
    const float* a2d  = (const float*)d_in[9];
    const float* b2   = (const float*)d_in[10];
    const float* W3   = (const float*)d_in[11];
    const float* a3s  = (const float*)d_in[12];
    const float* a3d  = (const float*)d_in[13];
    const float* b3   = (const float*)d_in[14];
    const float* lw   = (const float*)d_in[15];
    const float* lb   = (const float*)d_in[16];

    int N = in_sizes[0] / 128;
    int E = in_sizes[1] / 2;
    int G = out_size;

    char* p = (char*)d_ws;
    auto alloc = [&](size_t bytes) {
        char* r = p;
        p += (bytes + 255) & ~(size_t)255;
        return r;
    };
    float* bufA  = (float*)alloc((size_t)N * 256 * 4);
    float* bufB  = (float*)alloc((size_t)N * 256 * 4);
    float* al_s  = (float*)alloc((size_t)N * 4 * 4);
    float* al_d  = (float*)alloc((size_t)N * 4 * 4);
    int* indptr  = (int*)alloc((size_t)(N + 1) * 4);
    int* counts  = (int*)alloc((size_t)N * 4);
    int* cursor  = (int*)alloc((size_t)N * 4);
    int* csr     = (int*)alloc((size_t)E * 4);
    float* gsum  = (float*)alloc((size_t)G * 64 * 4);
    int* gcnt    = (int*)alloc((size_t)G * 4);
    if ((size_t)(p - (char*)d_ws) > ws_size) return;  // workspace too small

    hipMemsetAsync(counts, 0, (size_t)N * 4, stream);
    hipMemsetAsync(gsum, 0, (size_t)G * 64 * 4, stream);
    hipMemsetAsync(gcnt, 0, (size_t)G * 4, stream);

    int eb = (E + 255) / 256;
    k_count<<<eb, 256, 0, stream>>>(ei, E, counts);
    k_scan<<<1, 1024, 0, stream>>>(counts, indptr, cursor, N);
    k_scatter<<<eb, 256, 0, stream>>>(ei, E, cursor, csr);

    dim3 g1((N + 63) / 64, 4);
    dim3 g3((N + 63) / 64, 1);
    int wb = (N * 64 + 255) / 256;   // one wave per node

    // layer 1: 128 -> 256 (H=4, concat, ELU)
    k_gemm<<<g1, 256, 0, stream>>>(x, W1, bufA, N, 128, 256);
    k_attn<256, 4><<<wb, 256, 0, stream>>>(bufA, a1s, a1d, al_s, al_d, N);
    k_agg<4, true><<<wb, 256, 0, stream>>>(bufA, al_s, al_d, indptr, csr, b1, bufB, N);

    // layer 2: 256 -> 256 (H=4, concat, ELU)
    k_gemm<<<g1, 256, 0, stream>>>(bufB, W2, bufA, N, 256, 256);
    k_attn<256, 4><<<wb, 256, 0, stream>>>(bufA, a2s, a2d, al_s, al_d, N);
    k_agg<4, true><<<wb, 256, 0, stream>>>(bufA, al_s, al_d, indptr, csr, b2, bufB, N);

    // layer 3: 256 -> 64 (H=1, no concat, no act)
    k_gemm<<<g3, 256, 0, stream>>>(bufB, W3, bufA, N, 256, 64);
    k_attn<64, 1><<<wb, 256, 0, stream>>>(bufA, a3s, a3d, al_s, al_d, N);
    k_agg<1, false><<<wb, 256, 0, stream>>>(bufA, al_s, al_d, indptr, csr, b3, bufB, N);

    // pool + final linear
    int pb = (N + 3) / 4;
    k_pool<<<pb, 256, 0, stream>>>(bufB, batch, gsum, gcnt, N);
    int fb = (G * 64 + 255) / 256;
    k_final<<<fb, 256, 0, stream>>>(gsum, gcnt, lw, lb, (float*)d_out, G);
}

// Round 2
// 772.718 us; speedup vs baseline: 1.3624x; 1.3624x over previous
//
#include <hip/hip_runtime.h>
#include <cstdint>
#include <cstddef>

#define NEG_SLOPE 0.2f

__device__ __forceinline__ float lrelu(float v) { return v > 0.f ? v : NEG_SLOPE * v; }

// ---------------- CSR build ----------------
__global__ void k_count(const int* __restrict__ ei, int E, int* __restrict__ counts) {
    int i = blockIdx.x * blockDim.x + threadIdx.x;
    if (i < E) atomicAdd(&counts[ei[E + i]], 1);
}

__global__ void k_scan(const int* __restrict__ counts, int* __restrict__ indptr,
                       int* __restrict__ cursor, int Nn) {
    __shared__ int sdata[1024];
    int tid = threadIdx.x;
    int chunk = (Nn + 1023) >> 10;
    int start = tid * chunk;
    int end = start + chunk; if (end > Nn) end = Nn;
    int local = 0;
    for (int i = start; i < end; ++i) local += counts[i];
    sdata[tid] = local;
    __syncthreads();
    for (int off = 1; off < 1024; off <<= 1) {
        int v = (tid >= off) ? sdata[tid - off] : 0;
        __syncthreads();
        sdata[tid] += v;
        __syncthreads();
    }
    int run = sdata[tid] - local;  // exclusive prefix
    for (int i = start; i < end; ++i) {
        indptr[i] = run; cursor[i] = run; run += counts[i];
    }
    if (tid == 0) indptr[Nn] = sdata[1023];
}

__global__ void k_scatter(const int* __restrict__ ei, int E, int* __restrict__ cursor,
                          int* __restrict__ csr_src) {
    int i = blockIdx.x * blockDim.x + threadIdx.x;
    if (i < E) {
        int s = ei[i], d = ei[E + i];
        int pos = atomicAdd(&cursor[d], 1);
        csr_src[pos] = s;
    }
}

// ---------------- f32 GEMM + fused attention-coefficient epilogue ----------------
// C[N,M] = A[N,K] @ W[K,M]; 128x128 tile, 256 threads, 8x8 acc, K-step 16.
// Epilogue: al_s[n,h] = sum_c C[n,h*64+c]*a_src[h*64+c] (same for al_d).
__global__ __launch_bounds__(256) void k_gemm(const float* __restrict__ A,
                                              const float* __restrict__ W,
                                              float* __restrict__ C,
                                              const float* __restrict__ a_src,
                                              const float* __restrict__ a_dst,
                                              float* __restrict__ al_s,
                                              float* __restrict__ al_d,
                                              int Nrows, int K, int M) {
    __shared__ float As[16][132];   // [k][row] transposed
    __shared__ float Ws[16][128];   // [k][col]
    int tid = threadIdx.x;
    int tx = tid & 15, ty = tid >> 4;
    int row0 = blockIdx.x * 128;
    int col0 = blockIdx.y * 128;

    // staging coords
    int ar = tid >> 1;               // 0..127 row within tile
    int akk = (tid & 1) * 8;         // 0 or 8 within K-step
    int wkr = tid >> 4;              // 0..15 k row
    int wc = (tid & 15) * 8;         // 0..120 col within tile
    bool wvalid = (col0 + wc) < M;

    float acc[8][8] = {};

    for (int k0 = 0; k0 < K; k0 += 16) {
        // A tile
        {
            int gr = row0 + ar;
            float4 v0 = make_float4(0.f, 0.f, 0.f, 0.f), v1 = v0;
            if (gr < Nrows) {
                const float* ap = &A[(size_t)gr * K + k0 + akk];
                v0 = *reinterpret_cast<const float4*>(ap);
                v1 = *reinterpret_cast<const float4*>(ap + 4);
            }
            As[akk + 0][ar] = v0.x; As[akk + 1][ar] = v0.y;
            As[akk + 2][ar] = v0.z; As[akk + 3][ar] = v0.w;
            As[akk + 4][ar] = v1.x; As[akk + 5][ar] = v1.y;
            As[akk + 6][ar] = v1.z; As[akk + 7][ar] = v1.w;
        }
        // W tile
        {
            float4 v0 = make_float4(0.f, 0.f, 0.f, 0.f), v1 = v0;
            if (wvalid) {
                const float* wp = &W[(size_t)(k0 + wkr) * M + col0 + wc];
                v0 = *reinterpret_cast<const float4*>(wp);
                v1 = *reinterpret_cast<const float4*>(wp + 4);
            }
            *reinterpret_cast<float4*>(&Ws[wkr][wc]) = v0;
            *reinterpret_cast<float4*>(&Ws[wkr][wc + 4]) = v1;
        }
        __syncthreads();
        #pragma unroll
        for (int k = 0; k < 16; ++k) {
            float4 a0 = *reinterpret_cast<const float4*>(&As[k][ty * 8]);
            float4 a1 = *reinterpret_cast<const float4*>(&As[k][ty * 8 + 4]);
            float4 w0 = *reinterpret_cast<const float4*>(&Ws[k][tx * 8]);
            float4 w1 = *reinterpret_cast<const float4*>(&Ws[k][tx * 8 + 4]);
            float a_[8] = {a0.x, a0.y, a0.z, a0.w, a1.x, a1.y, a1.z, a1.w};
            float w_[8] = {w0.x, w0.y, w0.z, w0.w, w1.x, w1.y, w1.z, w1.w};
            #pragma unroll
            for (int i = 0; i < 8; ++i)
                #pragma unroll
                for (int j = 0; j < 8; ++j)
                    acc[i][j] += a_[i] * w_[j];
        }
        __syncthreads();
    }

    // C store
    int cbase = col0 + tx * 8;
    bool cvalid = cbase < M;
    #pragma unroll
    for (int i = 0; i < 8; ++i) {
        int gr = row0 + ty * 8 + i;
        if (gr < Nrows && cvalid) {
            float* cp = &C[(size_t)gr * M + cbase];
            *reinterpret_cast<float4*>(cp) =
                make_float4(acc[i][0], acc[i][1], acc[i][2], acc[i][3]);
            *reinterpret_cast<float4*>(cp + 4) =
                make_float4(acc[i][4], acc[i][5], acc[i][6], acc[i][7]);
        }
    }

    // fused attention-coefficient epilogue
    int head_t = cbase >> 6;            // global head index for this thread's cols
    int Hn = M >> 6;
    int ch0 = (tx & 7) * 8;             // channel base within head
    float as_[8], ad_[8];
    #pragma unroll
    for (int j = 0; j < 8; ++j) {
        as_[j] = cvalid ? a_src[head_t * 64 + ch0 + j] : 0.f;
        ad_[j] = cvalid ? a_dst[head_t * 64 + ch0 + j] : 0.f;
    }
    #pragma unroll
    for (int i = 0; i < 8; ++i) {
        float s = 0.f, dd = 0.f;
        #pragma unroll
        for (int j = 0; j < 8; ++j) { s += acc[i][j] * as_[j]; dd += acc[i][j] * ad_[j]; }
        // reduce across the 8 lanes with same ty, same (tx&8)
        #pragma unroll
        for (int off = 1; off < 8; off <<= 1) {
            s += __shfl_xor(s, off);
            dd += __shfl_xor(dd, off);
        }
        int gr = row0 + ty * 8 + i;
        if ((tx & 7) == 0 && cvalid && gr < Nrows) {
            al_s[(size_t)gr * Hn + head_t] = s;
            al_d[(size_t)gr * Hn + head_t] = dd;
        }
    }
}

// ---------------- fused softmax + aggregate (wave per destination node) ----------------
template <int H, bool ACT, bool POOL>    // TOT = H*64
__global__ __launch_bounds__(256) void k_agg(const float* __restrict__ hlin,
                      const float* __restrict__ al_s,
                      const float* __restrict__ al_d, const int* __restrict__ indptr,
                      const int* __restrict__ csr_src, const float* __restrict__ bias,
                      float* __restrict__ outf, const int* __restrict__ batch,
                      int* __restrict__ gcnt, int Nn) {
    constexpr int TOT = H * 64;
    constexpr int VEC = TOT / 64;
    constexpr int CAP = 128;
    __shared__ float sp[4][CAP * H];
    __shared__ int   si[4][CAP];
    int w = threadIdx.x >> 6;
    int lane = threadIdx.x & 63;
    int node = (blockIdx.x * blockDim.x + threadIdx.x) >> 6;
    if (node >= Nn) return;
    int d = node;
    int p0 = indptr[d], p1 = indptr[d + 1];
    int deg = p1 - p0;
    int head = (lane * VEC) >> 6;       // H=4: lane>>4 ; H=1: 0

    float ad[H], e_self[H];
    if constexpr (H == 4) {
        float4 adv = *reinterpret_cast<const float4*>(&al_d[(size_t)d * 4]);
        float4 asv = *reinterpret_cast<const float4*>(&al_s[(size_t)d * 4]);
        ad[0] = adv.x; ad[1] = adv.y; ad[2] = adv.z; ad[3] = adv.w;
        e_self[0] = lrelu(asv.x + ad[0]); e_self[1] = lrelu(asv.y + ad[1]);
        e_self[2] = lrelu(asv.z + ad[2]); e_self[3] = lrelu(asv.w + ad[3]);
    } else {
        ad[0] = al_d[d];
        e_self[0] = lrelu(al_s[d] + ad[0]);
    }

    float mh, invden, alpha_self;

    if (deg <= CAP) {
        int nb = (deg + 63) >> 6;
        float m[H];
        #pragma unroll
        for (int h = 0; h < H; ++h) m[h] = e_self[h];
        // phase A: compute e per lane-edge, stash e + src in LDS, track max
        for (int b = 0; b < nb; ++b) {
            int l = b * 64 + lane;
            float e_h[H];
            if (l < deg) {
                int s = csr_src[p0 + l];
                si[w][l] = s;
                if constexpr (H == 4) {
                    float4 sv = *reinterpret_cast<const float4*>(&al_s[(size_t)s * 4]);
                    e_h[0] = lrelu(sv.x + ad[0]); e_h[1] = lrelu(sv.y + ad[1]);
                    e_h[2] = lrelu(sv.z + ad[2]); e_h[3] = lrelu(sv.w + ad[3]);
                } else {
                    e_h[0] = lrelu(al_s[s] + ad[0]);
                }
            } else {
                #pragma unroll
                for (int h = 0; h < H; ++h) e_h[h] = -1e30f;
            }
            #pragma unroll
            for (int h = 0; h < H; ++h) {
                sp[w][l * H + h] = e_h[h];
                m[h] = fmaxf(m[h], e_h[h]);
            }
        }
        #pragma unroll
        for (int h = 0; h < H; ++h)
            #pragma unroll
            for (int off = 1; off < 64; off <<= 1)
                m[h] = fmaxf(m[h], __shfl_xor(m[h], off));
        // phase B: p = exp(e - m) back to LDS, accumulate denom
        float den[H];
        #pragma unroll
        for (int h = 0; h < H; ++h) den[h] = 0.f;
        for (int b = 0; b < nb; ++b) {
            int l = b * 64 + lane;
            #pragma unroll
            for (int h = 0; h < H; ++h) {
                float pv = __expf(sp[w][l * H + h] - m[h]);
                sp[w][l * H + h] = pv;
                den[h] += pv;
            }
        }
        #pragma unroll
        for (int h = 0; h < H; ++h) {
            #pragma unroll
            for (int off = 1; off < 64; off <<= 1)
                den[h] += __shfl_xor(den[h], off);
            den[h] += __expf(e_self[h] - m[h]);
        }
        mh = m[head];
        invden = 1.f / den[head];
        alpha_self = __expf(e_self[head] - mh) * invden;

        // pass 3: aggregate (weights from LDS, 4x unrolled for MLP)
        float4 accv = make_float4(0.f, 0.f, 0.f, 0.f);
        {
            const float* hp = hlin + (size_t)d * TOT + lane * VEC;
            if constexpr (VEC == 4) {
                float4 hv = *reinterpret_cast<const float4*>(hp);
                accv.x = alpha_self * hv.x; accv.y = alpha_self * hv.y;
                accv.z = alpha_self * hv.z; accv.w = alpha_self * hv.w;
            } else {
                accv.x = alpha_self * hp[0];
            }
        }
        int e = 0;
        for (; e + 4 <= deg; e += 4) {
            int s0 = si[w][e + 0], s1 = si[w][e + 1];
            int s2 = si[w][e + 2], s3 = si[w][e + 3];
            float a0 = sp[w][(e + 0) * H + head] * invden;
            float a1 = sp[w][(e + 1) * H + head] * invden;
            float a2 = sp[w][(e + 2) * H + head] * invden;
            float a3 = sp[w][(e + 3) * H + head] * invden;
            if constexpr (VEC == 4) {
                float4 r0 = *reinterpret_cast<const float4*>(hlin + (size_t)s0 * TOT + lane * 4);
                float4 r1 = *reinterpret_cast<const float4*>(hlin + (size_t)s1 * TOT + lane * 4);
                float4 r2 = *reinterpret_cast<const float4*>(hlin + (size_t)s2 * TOT + lane * 4);
                float4 r3 = *reinterpret_cast<const float4*>(hlin + (size_t)s3 * TOT + lane * 4);
                accv.x += a0 * r0.x + a1 * r1.x + a2 * r2.x + a3 * r3.x;
                accv.y += a0 * r0.y + a1 * r1.y + a2 * r2.y + a3 * r3.y;
                accv.z += a0 * r0.z + a1 * r1.z + a2 * r2.z + a3 * r3.z;
                accv.w += a0 * r0.w + a1 * r1.w + a2 * r2.w + a3 * r3.w;
            } else {
                float r0 = hlin[(size_t)s0 * TOT + lane];
                float r1 = hlin[(size_t)s1 * TOT + lane];
                float r2 = hlin[(size_t)s2 * TOT + lane];
                float r3 = hlin[(size_t)s3 * TOT + lane];
                accv.x += a0 * r0 + a1 * r1 + a2 * r2 + a3 * r3;
            }
        }
        for (; e < deg; ++e) {
            int s = si[w][e];
            float a = sp[w][e * H + head] * invden;
            if constexpr (VEC == 4) {
                float4 rv = *reinterpret_cast<const float4*>(hlin + (size_t)s * TOT + lane * 4);
                accv.x += a * rv.x; accv.y += a * rv.y;
                accv.z += a * rv.z; accv.w += a * rv.w;
            } else {
                accv.x += a * hlin[(size_t)s * TOT + lane];
            }
        }
        // epilogue
        if constexpr (VEC == 4) {
            int c0 = lane * 4;
            accv.x += bias[c0 + 0]; accv.y += bias[c0 + 1];
            accv.z += bias[c0 + 2]; accv.w += bias[c0 + 3];
            if (ACT) {
                accv.x = accv.x > 0.f ? accv.x : expm1f(accv.x);
                accv.y = accv.y > 0.f ? accv.y : expm1f(accv.y);
                accv.z = accv.z > 0.f ? accv.z : expm1f(accv.z);
                accv.w = accv.w > 0.f ? accv.w : expm1f(accv.w);
            }
            *reinterpret_cast<float4*>(&outf[(size_t)d * TOT + lane * 4]) = accv;
        } else {
            float o = accv.x + bias[lane];
            if (ACT) o = o > 0.f ? o : expm1f(o);
            if constexpr (POOL) {
                int g = batch[d];
                atomicAdd(&outf[(size_t)g * 64 + lane], o);
                if (lane == 0) atomicAdd(&gcnt[g], 1);
            } else {
                outf[(size_t)d * TOT + lane] = o;
            }
        }
        return;
    }

    // ---- fallback: deg > CAP, serial 3-pass (no LDS) ----
    {
        float adh = ad[head];
        float es = e_self[head];
        float m = es;
        for (int e = p0; e < p1; ++e) {
            int s = csr_src[e];
            m = fmaxf(m, lrelu(al_s[(size_t)s * H + head] + adh));
        }
        float den = __expf(es - m);
        for (int e = p0; e < p1; ++e) {
            int s = csr_src[e];
            den += __expf(lrelu(al_s[(size_t)s * H + head] + adh) - m);
        }
        den = 1.f / den;
        float accv[VEC] = {};
        {
            float alpha = __expf(es - m) * den;
            const float* hp = hlin + (size_t)d * TOT + lane * VEC;
            #pragma unroll
            for (int v = 0; v < VEC; ++v) accv[v] = alpha * hp[v];
        }
        for (int e = p0; e < p1; ++e) {
            int s = csr_src[e];
            float alpha = __expf(lrelu(al_s[(size_t)s * H + head] + adh) - m) * den;
            const float* hp = hlin + (size_t)s * TOT + lane * VEC;
            #pragma unroll
            for (int v = 0; v < VEC; ++v) accv[v] += alpha * hp[v];
        }
        #pragma unroll
        for (int v = 0; v < VEC; ++v) {
            int c = lane * VEC + v;
            float o = accv[v] + bias[c];
            if (ACT) o = o > 0.f ? o : expm1f(o);
            accv[v] = o;
        }
        if constexpr (POOL) {
            int g = batch[d];
            atomicAdd(&outf[(size_t)g * 64 + lane], accv[0]);
            if (lane == 0) atomicAdd(&gcnt[g], 1);
        } else {
            #pragma unroll
            for (int v = 0; v < VEC; ++v)
                outf[(size_t)d * TOT + lane * VEC + v] = accv[v];
        }
    }
}

// ---------------- final linear ----------------
__global__ void k_final(const float* __restrict__ gsum, const int* __restrict__ gcnt,
                        const float* __restrict__ lin_w, const float* __restrict__ lin_b,
                        float* __restrict__ out, int Gn) {
    int g = (blockIdx.x * blockDim.x + threadIdx.x) >> 6;
    int lane = threadIdx.x & 63;
    if (g >= Gn) return;
    float cnt = (float)gcnt[g];
    float inv = 1.f / fmaxf(cnt, 1.f);
    float v = gsum[(size_t)g * 64 + lane] * inv * lin_w[lane];
    #pragma unroll
    for (int off = 32; off >= 1; off >>= 1) v += __shfl_xor(v, off);
    if (lane == 0) out[g] = v + lin_b[0];
}

extern "C" void kernel_launch(void* const* d_in, const int* in_sizes, int n_in,
                              void* d_out, int out_size, void* d_ws, size_t ws_size,
                              hipStream_t stream) {
    const float* x    = (const float*)d_in[0];
    const int*   ei   = (const int*)d_in[1];
    const int*   batch= (const int*)d_in[2];
    const float* W1   = (const float*)d_in[3];
    const float* a1s  = (const float*)d_in[4];
    const float* a1d  = (const float*)d_in[5];
    const float* b1   = (const float*)d_in[6];
    const float* W2   = (const float*)d_in[7];
    const float* a2s  = (const float*)d_in[8];
    const float* a2d  = (const float*)d_in[9];
    const float* b2   = (const float*)d_in[10];
    const float* W3   = (const float*)d_in[11];
    const float* a3s  = (const float*)d_in[12];
    const float* a3d  = (const float*)d_in[13];
    const float* b3   = (const float*)d_in[14];
    const float* lw   = (const float*)d_in[15];
    const float* lb   = (const float*)d_in[16];

    int N = in_sizes[0] / 128;
    int E = in_sizes[1] / 2;
    int G = out_size;

    char* p = (char*)d_ws;
    auto alloc = [&](size_t bytes) {
        char* r = p;
        p += (bytes + 255) & ~(size_t)255;
        return r;
    };
    float* bufA  = (float*)alloc((size_t)N * 256 * 4);
    float* bufB  = (float*)alloc((size_t)N * 256 * 4);
    float* al_s  = (float*)alloc((size_t)N * 4 * 4);
    float* al_d  = (float*)alloc((size_t)N * 4 * 4);
    int* indptr  = (int*)alloc((size_t)(N + 1) * 4);
    int* counts  = (int*)alloc((size_t)N * 4);
    int* cursor  = (int*)alloc((size_t)N * 4);
    int* csr     = (int*)alloc((size_t)E * 4);
    float* gsum  = (float*)alloc((size_t)G * 64 * 4);
    int* gcnt    = (int*)alloc((size_t)G * 4);
    if ((size_t)(p - (char*)d_ws) > ws_size) return;  // workspace too small

    hipMemsetAsync(counts, 0, (size_t)N * 4, stream);
    hipMemsetAsync(gsum, 0, (size_t)G * 64 * 4, stream);
    hipMemsetAsync(gcnt, 0, (size_t)G * 4, stream);

    int eb = (E + 255) / 256;
    k_count<<<eb, 256, 0, stream>>>(ei, E, counts);
    k_scan<<<1, 1024, 0, stream>>>(counts, indptr, cursor, N);
    k_scatter<<<eb, 256, 0, stream>>>(ei, E, cursor, csr);

    int gx = (N + 127) / 128;
    int wb = (N * 64 + 255) / 256;   // one wave per node

    // layer 1: 128 -> 256 (H=4, concat, ELU)
    k_gemm<<<dim3(gx, 2), 256, 0, stream>>>(x, W1, bufA, a1s, a1d, al_s, al_d, N, 128, 256);
    k_agg<4, true, false><<<wb, 256, 0, stream>>>(bufA, al_s, al_d, indptr, csr, b1, bufB,
                                                  nullptr, nullptr, N);

    // layer 2: 256 -> 256 (H=4, concat, ELU)
    k_gemm<<<dim3(gx, 2), 256, 0, stream>>>(bufB, W2, bufA, a2s, a2d, al_s, al_d, N, 256, 256);
    k_agg<4, true, false><<<wb, 256, 0, stream>>>(bufA, al_s, al_d, indptr, csr, b2, bufB,
                                                  nullptr, nullptr, N);

    // layer 3: 256 -> 64 (H=1, no concat, no act) + fused mean-pool accumulate
    k_gemm<<<dim3(gx, 1), 256, 0, stream>>>(bufB, W3, bufA, a3s, a3d, al_s, al_d, N, 256, 64);
    k_agg<1, false, true><<<wb, 256, 0, stream>>>(bufA, al_s, al_d, indptr, csr, b3, gsum,
                                                  batch, gcnt, N);

    int fb = (G * 64 + 255) / 256;
    k_final<<<fb, 256, 0, stream>>>(gsum, gcnt, lw, lb, (float*)d_out, G);
}

// Round 3
// 659.276 us; speedup vs baseline: 1.5968x; 1.1721x over previous
//
#include <hip/hip_runtime.h>
#include <cstdint>
#include <cstddef>

#define NEG_SLOPE 0.2f

typedef __attribute__((ext_vector_type(8))) short short8;
typedef __attribute__((ext_vector_type(4))) float f32x4;

__device__ __forceinline__ float lrelu(float v) { return v > 0.f ? v : NEG_SLOPE * v; }

__device__ __forceinline__ unsigned short f2bf(float x) {
    unsigned u = __float_as_uint(x);
    u = (u + 0x7FFFu + ((u >> 16) & 1u)) >> 16;
    return (unsigned short)u;
}
__device__ __forceinline__ float bf2f(unsigned short h) {
    return __uint_as_float(((unsigned)h) << 16);
}

// ---------------- CSR build ----------------
__global__ void k_count(const int* __restrict__ ei, int E, int* __restrict__ counts) {
    int i = blockIdx.x * blockDim.x + threadIdx.x;
    if (i < E) atomicAdd(&counts[ei[E + i]], 1);
}

__global__ void k_scan(const int* __restrict__ counts, int* __restrict__ indptr,
                       int* __restrict__ cursor, int Nn) {
    __shared__ int sdata[1024];
    int tid = threadIdx.x;
    int chunk = (Nn + 1023) >> 10;
    int start = tid * chunk;
    int end = start + chunk; if (end > Nn) end = Nn;
    int local = 0;
    for (int i = start; i < end; ++i) local += counts[i];
    sdata[tid] = local;
    __syncthreads();
    for (int off = 1; off < 1024; off <<= 1) {
        int v = (tid >= off) ? sdata[tid - off] : 0;
        __syncthreads();
        sdata[tid] += v;
        __syncthreads();
    }
    int run = sdata[tid] - local;  // exclusive prefix
    for (int i = start; i < end; ++i) {
        indptr[i] = run; cursor[i] = run; run += counts[i];
    }
    if (tid == 0) indptr[Nn] = sdata[1023];
}

__global__ void k_scatter(const int* __restrict__ ei, int E, int* __restrict__ cursor,
                          int* __restrict__ csr_src) {
    int i = blockIdx.x * blockDim.x + threadIdx.x;
    if (i < E) {
        int s = ei[i], d = ei[E + i];
        int pos = atomicAdd(&cursor[d], 1);
        csr_src[pos] = s;
    }
}

// ---------------- pack A (f32 [Nrows,K] -> fragment-packed bf16 hi/lo) ----------------
// element (row,k): rt=row>>7, fb=(row&127)>>4, rl=row&15, ks=k>>5, kg=(k>>3)&3, j=k&7
// slot16B = ((rt*(K/32)+ks)*8+fb)*64 + (rl|(kg<<4)), elem j
__global__ __launch_bounds__(256) void k_packA(const float* __restrict__ A,
        unsigned short* __restrict__ Ph, unsigned short* __restrict__ Pl,
        int Nrows, int K, int RT) {
    int tid = blockIdx.x * 256 + threadIdx.x;
    int KS8 = K >> 3;
    int total = RT * 128 * KS8;
    if (tid >= total) return;
    int row = tid / KS8;
    int k = (tid - row * KS8) << 3;
    float v[8];
    if (row < Nrows) {
        const float4* ap = reinterpret_cast<const float4*>(&A[(size_t)row * K + k]);
        float4 x0 = ap[0], x1 = ap[1];
        v[0] = x0.x; v[1] = x0.y; v[2] = x0.z; v[3] = x0.w;
        v[4] = x1.x; v[5] = x1.y; v[6] = x1.z; v[7] = x1.w;
    } else {
        #pragma unroll
        for (int j = 0; j < 8; ++j) v[j] = 0.f;
    }
    short8 hv, lv;
    #pragma unroll
    for (int j = 0; j < 8; ++j) {
        unsigned short hb = f2bf(v[j]);
        hv[j] = (short)hb;
        lv[j] = (short)f2bf(v[j] - bf2f(hb));
    }
    int rt = row >> 7, r = row & 127;
    int ks = k >> 5, kg = (k >> 3) & 3;
    int fb = r >> 4, rl = r & 15;
    int lane = rl | (kg << 4);
    size_t off = (((size_t)rt * (K >> 5) + ks) * 8 + fb) * 64 + lane;
    *reinterpret_cast<short8*>(Ph + off * 8) = hv;
    *reinterpret_cast<short8*>(Pl + off * 8) = lv;
}

// ---------------- pack B (W f32 [K,M] -> fragment-packed bf16 hi/lo) ----------------
// element (k,col): ct64=col>>6, fb=(col&63)>>4, cl=col&15, ks=k>>5, kg=(k>>3)&3, j=k&7
// slot16B = ((ct64*(K/32)+ks)*4+fb)*64 + (cl|(kg<<4)), elem j
__global__ __launch_bounds__(256) void k_packB(const float* __restrict__ W,
        unsigned short* __restrict__ Ph, unsigned short* __restrict__ Pl, int K, int M) {
    int tid = blockIdx.x * 256 + threadIdx.x;
    int KS8 = K >> 3;
    int total = M * KS8;
    if (tid >= total) return;
    int col = tid / KS8;
    int k = (tid - col * KS8) << 3;
    short8 hv, lv;
    #pragma unroll
    for (int j = 0; j < 8; ++j) {
        float x = W[(size_t)(k + j) * M + col];
        unsigned short hb = f2bf(x);
        hv[j] = (short)hb;
        lv[j] = (short)f2bf(x - bf2f(hb));
    }
    int ct64 = col >> 6, c = col & 63;
    int fb = c >> 4, cl = c & 15;
    int ks = k >> 5, kg = (k >> 3) & 3;
    int lane = cl | (kg << 4);
    size_t off = (((size_t)ct64 * (K >> 5) + ks) * 4 + fb) * 64 + lane;
    *reinterpret_cast<short8*>(Ph + off * 8) = hv;
    *reinterpret_cast<short8*>(Pl + off * 8) = lv;
}

// ---------------- split-bf16 MFMA GEMM + fused attention epilogue ----------------
// block = 256 threads = 4 waves (WR x WC); wave tile = AF*16 rows x 64 cols (BF=4)
// C = A@W in ~f32 accuracy: acc = Al*Bh + Ah*Bl + Ah*Bh
template<int AF, int WR, int WC>
__global__ __launch_bounds__(256) void k_mm(const unsigned short* __restrict__ Ah,
        const unsigned short* __restrict__ Al,
        const unsigned short* __restrict__ Bh, const unsigned short* __restrict__ Bl,
        float* __restrict__ C, const float* __restrict__ a_src, const float* __restrict__ a_dst,
        float* __restrict__ al_s, float* __restrict__ al_d, int Nrows, int K, int M) {
    constexpr int BF = 4;
    int wave = threadIdx.x >> 6, lane = threadIdx.x & 63;
    int wr = wave / WC, wc = wave % WC;
    int rt = blockIdx.x;
    int ct64 = blockIdx.y * WC + wc;
    int KS = K >> 5;
    const short8* A8h = reinterpret_cast<const short8*>(Ah);
    const short8* A8l = reinterpret_cast<const short8*>(Al);
    const short8* B8h = reinterpret_cast<const short8*>(Bh);
    const short8* B8l = reinterpret_cast<const short8*>(Bl);

    f32x4 acc[AF][BF];
    #pragma unroll
    for (int i = 0; i < AF; ++i)
        #pragma unroll
        for (int j = 0; j < BF; ++j)
            acc[i][j] = (f32x4){0.f, 0.f, 0.f, 0.f};

    for (int ks = 0; ks < KS; ++ks) {
        short8 a_h[AF], a_l[AF], b_h[BF], b_l[BF];
        #pragma unroll
        for (int f = 0; f < AF; ++f) {
            size_t off = (((size_t)rt * KS + ks) * 8 + wr * AF + f) * 64 + lane;
            a_h[f] = A8h[off]; a_l[f] = A8l[off];
        }
        #pragma unroll
        for (int f = 0; f < BF; ++f) {
            size_t off = (((size_t)ct64 * KS + ks) * 4 + f) * 64 + lane;
            b_h[f] = B8h[off]; b_l[f] = B8l[off];
        }
        #pragma unroll
        for (int i = 0; i < AF; ++i)
            #pragma unroll
            for (int j = 0; j < BF; ++j) {
                acc[i][j] = __builtin_amdgcn_mfma_f32_16x16x32_bf16(a_l[i], b_h[j], acc[i][j], 0, 0, 0);
                acc[i][j] = __builtin_amdgcn_mfma_f32_16x16x32_bf16(a_h[i], b_l[j], acc[i][j], 0, 0, 0);
                acc[i][j] = __builtin_amdgcn_mfma_f32_16x16x32_bf16(a_h[i], b_h[j], acc[i][j], 0, 0, 0);
            }
    }

    int H = M >> 6;
    int head = ct64;                 // wave col span 64 == one head
    int col0 = ct64 * 64;
    int cl = lane & 15, rgrp = lane >> 4;

    float as_[BF], ad_[BF];
    #pragma unroll
    for (int j = 0; j < BF; ++j) {
        as_[j] = a_src[col0 + j * 16 + cl];
        ad_[j] = a_dst[col0 + j * 16 + cl];
    }

    #pragma unroll
    for (int i = 0; i < AF; ++i) {
        int rowb = rt * 128 + wr * (AF * 16) + i * 16 + rgrp * 4;
        #pragma unroll
        for (int r = 0; r < 4; ++r) {
            float sv = acc[i][0][r] * as_[0] + acc[i][1][r] * as_[1]
                     + acc[i][2][r] * as_[2] + acc[i][3][r] * as_[3];
            float dv = acc[i][0][r] * ad_[0] + acc[i][1][r] * ad_[1]
                     + acc[i][2][r] * ad_[2] + acc[i][3][r] * ad_[3];
            #pragma unroll
            for (int o = 1; o < 16; o <<= 1) {
                sv += __shfl_xor(sv, o);
                dv += __shfl_xor(dv, o);
            }
            int row = rowb + r;
            if (row < Nrows) {
                float* cp = &C[(size_t)row * M + col0 + cl];
                cp[0]  = acc[i][0][r];
                cp[16] = acc[i][1][r];
                cp[32] = acc[i][2][r];
                cp[48] = acc[i][3][r];
                if (cl == 0) {
                    al_s[(size_t)row * H + head] = sv;
                    al_d[(size_t)row * H + head] = dv;
                }
            }
        }
    }
}

// ---------------- fused softmax + aggregate (wave per destination node) ----------------
template <int H, bool ACT, bool POOL>    // TOT = H*64
__global__ __launch_bounds__(256) void k_agg(const float* __restrict__ hlin,
                      const float* __restrict__ al_s,
                      const float* __restrict__ al_d, const int* __restrict__ indptr,
                      const int* __restrict__ csr_src, const float* __restrict__ bias,
                      float* __restrict__ outf, const int* __restrict__ batch,
                      int* __restrict__ gcnt, int Nn) {
    constexpr int TOT = H * 64;
    constexpr int VEC = TOT / 64;
    constexpr int CAP = 128;
    __shared__ float sp[4][CAP * H];
    __shared__ int   si[4][CAP];
    int w = threadIdx.x >> 6;
    int lane = threadIdx.x & 63;
    int node = (blockIdx.x * blockDim.x + threadIdx.x) >> 6;
    if (node >= Nn) return;
    int d = node;
    int p0 = indptr[d], p1 = indptr[d + 1];
    int deg = p1 - p0;
    int head = (lane * VEC) >> 6;       // H=4: lane>>4 ; H=1: 0

    float ad[H], e_self[H];
    if constexpr (H == 4) {
        float4 adv = *reinterpret_cast<const float4*>(&al_d[(size_t)d * 4]);
        float4 asv = *reinterpret_cast<const float4*>(&al_s[(size_t)d * 4]);
        ad[0] = adv.x; ad[1] = adv.y; ad[2] = adv.z; ad[3] = adv.w;
        e_self[0] = lrelu(asv.x + ad[0]); e_self[1] = lrelu(asv.y + ad[1]);
        e_self[2] = lrelu(asv.z + ad[2]); e_self[3] = lrelu(asv.w + ad[3]);
    } else {
        ad[0] = al_d[d];
        e_self[0] = lrelu(al_s[d] + ad[0]);
    }

    float mh, invden, alpha_self;

    if (deg <= CAP) {
        int nb = (deg + 63) >> 6;
        float m[H];
        #pragma unroll
        for (int h = 0; h < H; ++h) m[h] = e_self[h];
        for (int b = 0; b < nb; ++b) {
            int l = b * 64 + lane;
            float e_h[H];
            if (l < deg) {
                int s = csr_src[p0 + l];
                si[w][l] = s;
                if constexpr (H == 4) {
                    float4 sv = *reinterpret_cast<const float4*>(&al_s[(size_t)s * 4]);
                    e_h[0] = lrelu(sv.x + ad[0]); e_h[1] = lrelu(sv.y + ad[1]);
                    e_h[2] = lrelu(sv.z + ad[2]); e_h[3] = lrelu(sv.w + ad[3]);
                } else {
                    e_h[0] = lrelu(al_s[s] + ad[0]);
                }
            } else {
                #pragma unroll
                for (int h = 0; h < H; ++h) e_h[h] = -1e30f;
            }
            #pragma unroll
            for (int h = 0; h < H; ++h) {
                sp[w][l * H + h] = e_h[h];
                m[h] = fmaxf(m[h], e_h[h]);
            }
        }
        #pragma unroll
        for (int h = 0; h < H; ++h)
            #pragma unroll
            for (int off = 1; off < 64; off <<= 1)
                m[h] = fmaxf(m[h], __shfl_xor(m[h], off));
        float den[H];
        #pragma unroll
        for (int h = 0; h < H; ++h) den[h] = 0.f;
        for (int b = 0; b < nb; ++b) {
            int l = b * 64 + lane;
            #pragma unroll
            for (int h = 0; h < H; ++h) {
                float pv = __expf(sp[w][l * H + h] - m[h]);
                sp[w][l * H + h] = pv;
                den[h] += pv;
            }
        }
        #pragma unroll
        for (int h = 0; h < H; ++h) {
            #pragma unroll
            for (int off = 1; off < 64; off <<= 1)
                den[h] += __shfl_xor(den[h], off);
            den[h] += __expf(e_self[h] - m[h]);
        }
        mh = m[head];
        invden = 1.f / den[head];
        alpha_self = __expf(e_self[head] - mh) * invden;

        float4 accv = make_float4(0.f, 0.f, 0.f, 0.f);
        {
            const float* hp = hlin + (size_t)d * TOT + lane * VEC;
            if constexpr (VEC == 4) {
                float4 hv = *reinterpret_cast<const float4*>(hp);
                accv.x = alpha_self * hv.x; accv.y = alpha_self * hv.y;
                accv.z = alpha_self * hv.z; accv.w = alpha_self * hv.w;
            } else {
                accv.x = alpha_self * hp[0];
            }
        }
        int e = 0;
        for (; e + 8 <= deg; e += 8) {
            int s0 = si[w][e + 0], s1 = si[w][e + 1], s2 = si[w][e + 2], s3 = si[w][e + 3];
            int s4 = si[w][e + 4], s5 = si[w][e + 5], s6 = si[w][e + 6], s7 = si[w][e + 7];
            float a0 = sp[w][(e + 0) * H + head] * invden;
            float a1 = sp[w][(e + 1) * H + head] * invden;
            float a2 = sp[w][(e + 2) * H + head] * invden;
            float a3 = sp[w][(e + 3) * H + head] * invden;
            float a4 = sp[w][(e + 4) * H + head] * invden;
            float a5 = sp[w][(e + 5) * H + head] * invden;
            float a6 = sp[w][(e + 6) * H + head] * invden;
            float a7 = sp[w][(e + 7) * H + head] * invden;
            if constexpr (VEC == 4) {
                float4 r0 = *reinterpret_cast<const float4*>(hlin + (size_t)s0 * TOT + lane * 4);
                float4 r1 = *reinterpret_cast<const float4*>(hlin + (size_t)s1 * TOT + lane * 4);
                float4 r2 = *reinterpret_cast<const float4*>(hlin + (size_t)s2 * TOT + lane * 4);
                float4 r3 = *reinterpret_cast<const float4*>(hlin + (size_t)s3 * TOT + lane * 4);
                float4 r4 = *reinterpret_cast<const float4*>(hlin + (size_t)s4 * TOT + lane * 4);
                float4 r5 = *reinterpret_cast<const float4*>(hlin + (size_t)s5 * TOT + lane * 4);
                float4 r6 = *reinterpret_cast<const float4*>(hlin + (size_t)s6 * TOT + lane * 4);
                float4 r7 = *reinterpret_cast<const float4*>(hlin + (size_t)s7 * TOT + lane * 4);
                accv.x += a0*r0.x + a1*r1.x + a2*r2.x + a3*r3.x + a4*r4.x + a5*r5.x + a6*r6.x + a7*r7.x;
                accv.y += a0*r0.y + a1*r1.y + a2*r2.y + a3*r3.y + a4*r4.y + a5*r5.y + a6*r6.y + a7*r7.y;
                accv.z += a0*r0.z + a1*r1.z + a2*r2.z + a3*r3.z + a4*r4.z + a5*r5.z + a6*r6.z + a7*r7.z;
                accv.w += a0*r0.w + a1*r1.w + a2*r2.w + a3*r3.w + a4*r4.w + a5*r5.w + a6*r6.w + a7*r7.w;
            } else {
                float r0 = hlin[(size_t)s0 * TOT + lane];
                float r1 = hlin[(size_t)s1 * TOT + lane];
                float r2 = hlin[(size_t)s2 * TOT + lane];
                float r3 = hlin[(size_t)s3 * TOT + lane];
                float r4 = hlin[(size_t)s4 * TOT + lane];
                float r5 = hlin[(size_t)s5 * TOT + lane];
                float r6 = hlin[(size_t)s6 * TOT + lane];
                float r7 = hlin[(size_t)s7 * TOT + lane];
                accv.x += a0*r0 + a1*r1 + a2*r2 + a3*r3 + a4*r4 + a5*r5 + a6*r6 + a7*r7;
            }
        }
        for (; e + 4 <= deg; e += 4) {
            int s0 = si[w][e + 0], s1 = si[w][e + 1];
            int s2 = si[w][e + 2], s3 = si[w][e + 3];
            float a0 = sp[w][(e + 0) * H + head] * invden;
            float a1 = sp[w][(e + 1) * H + head] * invden;
            float a2 = sp[w][(e + 2) * H + head] * invden;
            float a3 = sp[w][(e + 3) * H + head] * invden;
            if constexpr (VEC == 4) {
                float4 r0 = *reinterpret_cast<const float4*>(hlin + (size_t)s0 * TOT + lane * 4);
                float4 r1 = *reinterpret_cast<const float4*>(hlin + (size_t)s1 * TOT + lane * 4);
                float4 r2 = *reinterpret_cast<const float4*>(hlin + (size_t)s2 * TOT + lane * 4);
                float4 r3 = *reinterpret_cast<const float4*>(hlin + (size_t)s3 * TOT + lane * 4);
                accv.x += a0 * r0.x + a1 * r1.x + a2 * r2.x + a3 * r3.x;
                accv.y += a0 * r0.y + a1 * r1.y + a2 * r2.y + a3 * r3.y;
                accv.z += a0 * r0.z + a1 * r1.z + a2 * r2.z + a3 * r3.z;
                accv.w += a0 * r0.w + a1 * r1.w + a2 * r2.w + a3 * r3.w;
            } else {
                float r0 = hlin[(size_t)s0 * TOT + lane];
                float r1 = hlin[(size_t)s1 * TOT + lane];
                float r2 = hlin[(size_t)s2 * TOT + lane];
                float r3 = hlin[(size_t)s3 * TOT + lane];
                accv.x += a0 * r0 + a1 * r1 + a2 * r2 + a3 * r3;
            }
        }
        for (; e < deg; ++e) {
            int s = si[w][e];
            float a = sp[w][e * H + head] * invden;
            if constexpr (VEC == 4) {
                float4 rv = *reinterpret_cast<const float4*>(hlin + (size_t)s * TOT + lane * 4);
                accv.x += a * rv.x; accv.y += a * rv.y;
                accv.z += a * rv.z; accv.w += a * rv.w;
            } else {
                accv.x += a * hlin[(size_t)s * TOT + lane];
            }
        }
        if constexpr (VEC == 4) {
            int c0 = lane * 4;
            accv.x += bias[c0 + 0]; accv.y += bias[c0 + 1];
            accv.z += bias[c0 + 2]; accv.w += bias[c0 + 3];
            if (ACT) {
                accv.x = accv.x > 0.f ? accv.x : expm1f(accv.x);
                accv.y = accv.y > 0.f ? accv.y : expm1f(accv.y);
                accv.z = accv.z > 0.f ? accv.z : expm1f(accv.z);
                accv.w = accv.w > 0.f ? accv.w : expm1f(accv.w);
            }
            *reinterpret_cast<float4*>(&outf[(size_t)d * TOT + lane * 4]) = accv;
        } else {
            float o = accv.x + bias[lane];
            if (ACT) o = o > 0.f ? o : expm1f(o);
            if constexpr (POOL) {
                int g = batch[d];
                atomicAdd(&outf[(size_t)g * 64 + lane], o);
                if (lane == 0) atomicAdd(&gcnt[g], 1);
            } else {
                outf[(size_t)d * TOT + lane] = o;
            }
        }
        return;
    }

    // ---- fallback: deg > CAP, serial 3-pass (no LDS) ----
    {
        float adh = ad[head];
        float es = e_self[head];
        float m = es;
        for (int e = p0; e < p1; ++e) {
            int s = csr_src[e];
            m = fmaxf(m, lrelu(al_s[(size_t)s * H + head] + adh));
        }
        float den = __expf(es - m);
        for (int e = p0; e < p1; ++e) {
            int s = csr_src[e];
            den += __expf(lrelu(al_s[(size_t)s * H + head] + adh) - m);
        }
        den = 1.f / den;
        float accv[VEC] = {};
        {
            float alpha = __expf(es - m) * den;
            const float* hp = hlin + (size_t)d * TOT + lane * VEC;
            #pragma unroll
            for (int v = 0; v < VEC; ++v) accv[v] = alpha * hp[v];
        }
        for (int e = p0; e < p1; ++e) {
            int s = csr_src[e];
            float alpha = __expf(lrelu(al_s[(size_t)s * H + head] + adh) - m) * den;
            const float* hp = hlin + (size_t)s * TOT + lane * VEC;
            #pragma unroll
            for (int v = 0; v < VEC; ++v) accv[v] += alpha * hp[v];
        }
        #pragma unroll
        for (int v = 0; v < VEC; ++v) {
            int c = lane * VEC + v;
            float o = accv[v] + bias[c];
            if (ACT) o = o > 0.f ? o : expm1f(o);
            accv[v] = o;
        }
        if constexpr (POOL) {
            int g = batch[d];
            atomicAdd(&outf[(size_t)g * 64 + lane], accv[0]);
            if (lane == 0) atomicAdd(&gcnt[g], 1);
        } else {
            #pragma unroll
            for (int v = 0; v < VEC; ++v)
                outf[(size_t)d * TOT + lane * VEC + v] = accv[v];
        }
    }
}

// ---------------- final linear ----------------
__global__ void k_final(const float* __restrict__ gsum, const int* __restrict__ gcnt,
                        const float* __restrict__ lin_w, const float* __restrict__ lin_b,
                        float* __restrict__ out, int Gn) {
    int g = (blockIdx.x * blockDim.x + threadIdx.x) >> 6;
    int lane = threadIdx.x & 63;
    if (g >= Gn) return;
    float cnt = (float)gcnt[g];
    float inv = 1.f / fmaxf(cnt, 1.f);
    float v = gsum[(size_t)g * 64 + lane] * inv * lin_w[lane];
    #pragma unroll
    for (int off = 32; off >= 1; off >>= 1) v += __shfl_xor(v, off);
    if (lane == 0) out[g] = v + lin_b[0];
}

extern "C" void kernel_launch(void* const* d_in, const int* in_sizes, int n_in,
                              void* d_out, int out_size, void* d_ws, size_t ws_size,
                              hipStream_t stream) {
    const float* x    = (const float*)d_in[0];
    const int*   ei   = (const int*)d_in[1];
    const int*   batch= (const int*)d_in[2];
    const float* W1   = (const float*)d_in[3];
    const float* a1s  = (const float*)d_in[4];
    const float* a1d  = (const float*)d_in[5];
    const float* b1   = (const float*)d_in[6];
    const float* W2   = (const float*)d_in[7];
    const float* a2s  = (const float*)d_in[8];
    const float* a2d  = (const float*)d_in[9];
    const float* b2   = (const float*)d_in[10];
    const float* W3   = (const float*)d_in[11];
    const float* a3s  = (const float*)d_in[12];
    const float* a3d  = (const float*)d_in[13];
    const float* b3   = (const float*)d_in[14];
    const float* lw   = (const float*)d_in[15];
    const float* lb   = (const float*)d_in[16];

    int N = in_sizes[0] / 128;
    int E = in_sizes[1] / 2;
    int G = out_size;
    int RT = (N + 127) >> 7;
    int Np = RT * 128;

    char* p = (char*)d_ws;
    auto alloc = [&](size_t bytes) {
        char* r = p;
        p += (bytes + 255) & ~(size_t)255;
        return r;
    };
    float* bufA  = (float*)alloc((size_t)N * 256 * 4);
    float* bufB  = (float*)alloc((size_t)N * 256 * 4);
    unsigned short* pAh = (unsigned short*)alloc((size_t)Np * 256 * 2);
    unsigned short* pAl = (unsigned short*)alloc((size_t)Np * 256 * 2);
    unsigned short* pBh = (unsigned short*)alloc((size_t)256 * 256 * 2);
    unsigned short* pBl = (unsigned short*)alloc((size_t)256 * 256 * 2);
    float* al_s  = (float*)alloc((size_t)N * 4 * 4);
    float* al_d  = (float*)alloc((size_t)N * 4 * 4);
    int* indptr  = (int*)alloc((size_t)(N + 1) * 4);
    int* counts  = (int*)alloc((size_t)N * 4);
    int* cursor  = (int*)alloc((size_t)N * 4);
    int* csr     = (int*)alloc((size_t)E * 4);
    float* gsum  = (float*)alloc((size_t)G * 64 * 4);
    int* gcnt    = (int*)alloc((size_t)G * 4);
    if ((size_t)(p - (char*)d_ws) > ws_size) return;  // workspace too small

    hipMemsetAsync(counts, 0, (size_t)N * 4, stream);
    hipMemsetAsync(gsum, 0, (size_t)G * 64 * 4, stream);
    hipMemsetAsync(gcnt, 0, (size_t)G * 4, stream);

    int eb = (E + 255) / 256;
    k_count<<<eb, 256, 0, stream>>>(ei, E, counts);
    k_scan<<<1, 1024, 0, stream>>>(counts, indptr, cursor, N);
    k_scatter<<<eb, 256, 0, stream>>>(ei, E, cursor, csr);

    int wb = (N * 64 + 255) / 256;   // one wave per node
    auto packA_blocks = [&](int K) { return (RT * 128 * (K >> 3) + 255) / 256; };
    auto packB_blocks = [&](int K, int M) { return (M * (K >> 3) + 255) / 256; };

    // layer 1: 128 -> 256 (H=4, concat, ELU)
    k_packA<<<packA_blocks(128), 256, 0, stream>>>(x, pAh, pAl, N, 128, RT);
    k_packB<<<packB_blocks(128, 256), 256, 0, stream>>>(W1, pBh, pBl, 128, 256);
    k_mm<4, 2, 2><<<dim3(RT, 2), 256, 0, stream>>>(pAh, pAl, pBh, pBl, bufA,
                                                   a1s, a1d, al_s, al_d, N, 128, 256);
    k_agg<4, true, false><<<wb, 256, 0, stream>>>(bufA, al_s, al_d, indptr, csr, b1, bufB,
                                                  nullptr, nullptr, N);

    // layer 2: 256 -> 256 (H=4, concat, ELU)
    k_packA<<<packA_blocks(256), 256, 0, stream>>>(bufB, pAh, pAl, N, 256, RT);
    k_packB<<<packB_blocks(256, 256), 256, 0, stream>>>(W2, pBh, pBl, 256, 256);
    k_mm<4, 2, 2><<<dim3(RT, 2), 256, 0, stream>>>(pAh, pAl, pBh, pBl, bufA,
                                                   a2s, a2d, al_s, al_d, N, 256, 256);
    k_agg<4, true, false><<<wb, 256, 0, stream>>>(bufA, al_s, al_d, indptr, csr, b2, bufB,
                                                  nullptr, nullptr, N);

    // layer 3: 256 -> 64 (H=1, no concat, no act) + fused mean-pool accumulate
    k_packA<<<packA_blocks(256), 256, 0, stream>>>(bufB, pAh, pAl, N, 256, RT);
    k_packB<<<packB_blocks(256, 64), 256, 0, stream>>>(W3, pBh, pBl, 256, 64);
    k_mm<2, 4, 1><<<dim3(RT, 1), 256, 0, stream>>>(pAh, pAl, pBh, pBl, bufA,
                                                   a3s, a3d, al_s, al_d, N, 256, 64);
    k_agg<1, false, true><<<wb, 256, 0, stream>>>(bufA, al_s, al_d, indptr, csr, b3, gsum,
                                                  batch, gcnt, N);

    int fb = (G * 64 + 255) / 256;
    k_final<<<fb, 256, 0, stream>>>(gsum, gcnt, lw, lb, (float*)d_out, G);
}

// Round 4
// 641.778 us; speedup vs baseline: 1.6404x; 1.0273x over previous
//
#include <hip/hip_runtime.h>
#include <cstdint>
#include <cstddef>

#define NEG_SLOPE 0.2f

typedef __attribute__((ext_vector_type(8))) short short8;
typedef __attribute__((ext_vector_type(4))) float f32x4;

__device__ __forceinline__ float lrelu(float v) { return v > 0.f ? v : NEG_SLOPE * v; }

__device__ __forceinline__ unsigned short f2bf(float x) {
    unsigned u = __float_as_uint(x);
    u = (u + 0x7FFFu + ((u >> 16) & 1u)) >> 16;
    return (unsigned short)u;
}
__device__ __forceinline__ float bf2f(unsigned short h) {
    return __uint_as_float(((unsigned)h) << 16);
}

// ---------------- CSR build ----------------
__global__ void k_count(const int* __restrict__ ei, int E, int* __restrict__ counts) {
    int i = blockIdx.x * blockDim.x + threadIdx.x;
    if (i < E) atomicAdd(&counts[ei[E + i]], 1);
}

__global__ void k_scan(const int* __restrict__ counts, int* __restrict__ indptr,
                       int* __restrict__ cursor, int Nn) {
    __shared__ int sdata[1024];
    int tid = threadIdx.x;
    int chunk = (Nn + 1023) >> 10;
    int start = tid * chunk;
    int end = start + chunk; if (end > Nn) end = Nn;
    int local = 0;
    for (int i = start; i < end; ++i) local += counts[i];
    sdata[tid] = local;
    __syncthreads();
    for (int off = 1; off < 1024; off <<= 1) {
        int v = (tid >= off) ? sdata[tid - off] : 0;
        __syncthreads();
        sdata[tid] += v;
        __syncthreads();
    }
    int run = sdata[tid] - local;  // exclusive prefix
    for (int i = start; i < end; ++i) {
        indptr[i] = run; cursor[i] = run; run += counts[i];
    }
    if (tid == 0) indptr[Nn] = sdata[1023];
}

__global__ void k_scatter(const int* __restrict__ ei, int E, int* __restrict__ cursor,
                          int* __restrict__ csr_src) {
    int i = blockIdx.x * blockDim.x + threadIdx.x;
    if (i < E) {
        int s = ei[i], d = ei[E + i];
        int pos = atomicAdd(&cursor[d], 1);
        csr_src[pos] = s;
    }
}

// ---------------- pack B (W f32 [K,M] -> fragment-packed bf16 hi/lo, RNE) ----------------
// element (k,col): ct64=col>>6, fb=(col&63)>>4, cl=col&15, ks=k>>5, kg=(k>>3)&3, j=k&7
// slot16B = ((ct64*(K/32)+ks)*4+fb)*64 + (cl|(kg<<4)), elem j
__global__ __launch_bounds__(256) void k_packB(const float* __restrict__ W,
        unsigned short* __restrict__ Ph, unsigned short* __restrict__ Pl, int K, int M) {
    int tid = blockIdx.x * 256 + threadIdx.x;
    int KS8 = K >> 3;
    int total = M * KS8;
    if (tid >= total) return;
    int col = tid / KS8;
    int k = (tid - col * KS8) << 3;
    short8 hv, lv;
    #pragma unroll
    for (int j = 0; j < 8; ++j) {
        float x = W[(size_t)(k + j) * M + col];
        unsigned short hb = f2bf(x);
        hv[j] = (short)hb;
        lv[j] = (short)f2bf(x - bf2f(hb));
    }
    int ct64 = col >> 6, c = col & 63;
    int fb = c >> 4, cl = c & 15;
    int ks = k >> 5, kg = (k >> 3) & 3;
    int lane = cl | (kg << 4);
    size_t off = (((size_t)ct64 * (K >> 5) + ks) * 4 + fb) * 64 + lane;
    *reinterpret_cast<short8*>(Ph + off * 8) = hv;
    *reinterpret_cast<short8*>(Pl + off * 8) = lv;
}

// ---------------- split-bf16 MFMA GEMM, A converted in-kernel ----------------
// block = 256 threads = 4 waves (WR x WC); wave tile = AF*16 rows x 64 cols (BF=4)
// C = A@W in ~f32 accuracy: acc = Al*Bh + Ah*Bl + Ah*Bh
// A loaded from row-major f32; lanes of each frag read 16 rows x 128B contiguous.
template<int AF, int WR, int WC>
__global__ __launch_bounds__(256) void k_mm(const float* __restrict__ A,
        const unsigned short* __restrict__ Bh, const unsigned short* __restrict__ Bl,
        float* __restrict__ C, const float* __restrict__ a_src, const float* __restrict__ a_dst,
        float* __restrict__ al_s, float* __restrict__ al_d, int Nrows, int K, int M) {
    constexpr int BF = 4;
    int wave = threadIdx.x >> 6, lane = threadIdx.x & 63;
    int wr = wave / WC, wc = wave % WC;
    int rt = blockIdx.x;
    int ct64 = blockIdx.y * WC + wc;
    int KS = K >> 5;
    int rl = lane & 15, kg = lane >> 4;
    const short8* B8h = reinterpret_cast<const short8*>(Bh);
    const short8* B8l = reinterpret_cast<const short8*>(Bl);

    const float* aptr[AF];
    #pragma unroll
    for (int f = 0; f < AF; ++f) {
        int row = rt * 128 + wr * (AF * 16) + f * 16 + rl;
        if (row > Nrows - 1) row = Nrows - 1;   // clamp: OOB rows produce junk, discarded at store
        aptr[f] = A + (size_t)row * K + kg * 8;
    }

    f32x4 acc[AF][BF];
    #pragma unroll
    for (int i = 0; i < AF; ++i)
        #pragma unroll
        for (int j = 0; j < BF; ++j)
            acc[i][j] = (f32x4){0.f, 0.f, 0.f, 0.f};

    for (int ks = 0; ks < KS; ++ks) {
        short8 a_h[AF], a_l[AF], b_h[BF], b_l[BF];
        #pragma unroll
        for (int f = 0; f < AF; ++f) {
            const float* ap = aptr[f] + ks * 32;
            float4 v0 = *reinterpret_cast<const float4*>(ap);
            float4 v1 = *reinterpret_cast<const float4*>(ap + 4);
            float vv[8] = {v0.x, v0.y, v0.z, v0.w, v1.x, v1.y, v1.z, v1.w};
            #pragma unroll
            for (int j = 0; j < 8; ++j) {
                unsigned u = __float_as_uint(vv[j]);
                unsigned short hb = (unsigned short)(u >> 16);        // trunc split
                float hf = __uint_as_float(u & 0xFFFF0000u);
                float lf = vv[j] - hf;
                unsigned short lb = (unsigned short)(__float_as_uint(lf) >> 16);
                a_h[f][j] = (short)hb;
                a_l[f][j] = (short)lb;
            }
        }
        #pragma unroll
        for (int f = 0; f < BF; ++f) {
            size_t off = (((size_t)ct64 * KS + ks) * 4 + f) * 64 + lane;
            b_h[f] = B8h[off]; b_l[f] = B8l[off];
        }
        #pragma unroll
        for (int i = 0; i < AF; ++i)
            #pragma unroll
            for (int j = 0; j < BF; ++j) {
                acc[i][j] = __builtin_amdgcn_mfma_f32_16x16x32_bf16(a_l[i], b_h[j], acc[i][j], 0, 0, 0);
                acc[i][j] = __builtin_amdgcn_mfma_f32_16x16x32_bf16(a_h[i], b_l[j], acc[i][j], 0, 0, 0);
                acc[i][j] = __builtin_amdgcn_mfma_f32_16x16x32_bf16(a_h[i], b_h[j], acc[i][j], 0, 0, 0);
            }
    }

    int H = M >> 6;
    int head = ct64;                 // wave col span 64 == one head
    int col0 = ct64 * 64;
    int cl = lane & 15, rgrp = lane >> 4;

    float as_[BF], ad_[BF];
    #pragma unroll
    for (int j = 0; j < BF; ++j) {
        as_[j] = a_src[col0 + j * 16 + cl];
        ad_[j] = a_dst[col0 + j * 16 + cl];
    }

    #pragma unroll
    for (int i = 0; i < AF; ++i) {
        int rowb = rt * 128 + wr * (AF * 16) + i * 16 + rgrp * 4;
        #pragma unroll
        for (int r = 0; r < 4; ++r) {
            float sv = acc[i][0][r] * as_[0] + acc[i][1][r] * as_[1]
                     + acc[i][2][r] * as_[2] + acc[i][3][r] * as_[3];
            float dv = acc[i][0][r] * ad_[0] + acc[i][1][r] * ad_[1]
                     + acc[i][2][r] * ad_[2] + acc[i][3][r] * ad_[3];
            #pragma unroll
            for (int o = 1; o < 16; o <<= 1) {
                sv += __shfl_xor(sv, o);
                dv += __shfl_xor(dv, o);
            }
            int row = rowb + r;
            if (row < Nrows) {
                float* cp = &C[(size_t)row * M + col0 + cl];
                cp[0]  = acc[i][0][r];
                cp[16] = acc[i][1][r];
                cp[32] = acc[i][2][r];
                cp[48] = acc[i][3][r];
                if (cl == 0) {
                    al_s[(size_t)row * H + head] = sv;
                    al_d[(size_t)row * H + head] = dv;
                }
            }
        }
    }
}

// ---------------- fused softmax + aggregate (wave per destination node) ----------------
template <int H, bool ACT, bool POOL>    // TOT = H*64
__global__ __launch_bounds__(256) void k_agg(const float* __restrict__ hlin,
                      const float* __restrict__ al_s,
                      const float* __restrict__ al_d, const int* __restrict__ indptr,
                      const int* __restrict__ csr_src, const float* __restrict__ bias,
                      float* __restrict__ outf, const int* __restrict__ batch,
                      int* __restrict__ gcnt, int Nn) {
    constexpr int TOT = H * 64;
    constexpr int VEC = TOT / 64;
    constexpr int CAP = 128;
    __shared__ float sp[4][CAP * H];
    __shared__ int   si[4][CAP];
    int w = threadIdx.x >> 6;
    int lane = threadIdx.x & 63;
    int node = (blockIdx.x * blockDim.x + threadIdx.x) >> 6;
    if (node >= Nn) return;
    int d = node;
    int p0 = indptr[d], p1 = indptr[d + 1];
    int deg = p1 - p0;
    int head = (lane * VEC) >> 6;       // H=4: lane>>4 ; H=1: 0

    float ad[H], e_self[H];
    if constexpr (H == 4) {
        float4 adv = *reinterpret_cast<const float4*>(&al_d[(size_t)d * 4]);
        float4 asv = *reinterpret_cast<const float4*>(&al_s[(size_t)d * 4]);
        ad[0] = adv.x; ad[1] = adv.y; ad[2] = adv.z; ad[3] = adv.w;
        e_self[0] = lrelu(asv.x + ad[0]); e_self[1] = lrelu(asv.y + ad[1]);
        e_self[2] = lrelu(asv.z + ad[2]); e_self[3] = lrelu(asv.w + ad[3]);
    } else {
        ad[0] = al_d[d];
        e_self[0] = lrelu(al_s[d] + ad[0]);
    }

    float mh, invden, alpha_self;

    if (deg <= CAP) {
        int nb = (deg + 63) >> 6;
        float m[H];
        #pragma unroll
        for (int h = 0; h < H; ++h) m[h] = e_self[h];
        for (int b = 0; b < nb; ++b) {
            int l = b * 64 + lane;
            float e_h[H];
            if (l < deg) {
                int s = csr_src[p0 + l];
                si[w][l] = s;
                if constexpr (H == 4) {
                    float4 sv = *reinterpret_cast<const float4*>(&al_s[(size_t)s * 4]);
                    e_h[0] = lrelu(sv.x + ad[0]); e_h[1] = lrelu(sv.y + ad[1]);
                    e_h[2] = lrelu(sv.z + ad[2]); e_h[3] = lrelu(sv.w + ad[3]);
                } else {
                    e_h[0] = lrelu(al_s[s] + ad[0]);
                }
            } else {
                #pragma unroll
                for (int h = 0; h < H; ++h) e_h[h] = -1e30f;
            }
            #pragma unroll
            for (int h = 0; h < H; ++h) {
                sp[w][l * H + h] = e_h[h];
                m[h] = fmaxf(m[h], e_h[h]);
            }
        }
        #pragma unroll
        for (int h = 0; h < H; ++h)
            #pragma unroll
            for (int off = 1; off < 64; off <<= 1)
                m[h] = fmaxf(m[h], __shfl_xor(m[h], off));
        float den[H];
        #pragma unroll
        for (int h = 0; h < H; ++h) den[h] = 0.f;
        for (int b = 0; b < nb; ++b) {
            int l = b * 64 + lane;
            #pragma unroll
            for (int h = 0; h < H; ++h) {
                float pv = __expf(sp[w][l * H + h] - m[h]);
                sp[w][l * H + h] = pv;
                den[h] += pv;
            }
        }
        #pragma unroll
        for (int h = 0; h < H; ++h) {
            #pragma unroll
            for (int off = 1; off < 64; off <<= 1)
                den[h] += __shfl_xor(den[h], off);
            den[h] += __expf(e_self[h] - m[h]);
        }
        mh = m[head];
        invden = 1.f / den[head];
        alpha_self = __expf(e_self[head] - mh) * invden;

        float4 accv = make_float4(0.f, 0.f, 0.f, 0.f);
        {
            const float* hp = hlin + (size_t)d * TOT + lane * VEC;
            if constexpr (VEC == 4) {
                float4 hv = *reinterpret_cast<const float4*>(hp);
                accv.x = alpha_self * hv.x; accv.y = alpha_self * hv.y;
                accv.z = alpha_self * hv.z; accv.w = alpha_self * hv.w;
            } else {
                accv.x = alpha_self * hp[0];
            }
        }
        int e = 0;
        for (; e + 8 <= deg; e += 8) {
            int s0 = si[w][e + 0], s1 = si[w][e + 1], s2 = si[w][e + 2], s3 = si[w][e + 3];
            int s4 = si[w][e + 4], s5 = si[w][e + 5], s6 = si[w][e + 6], s7 = si[w][e + 7];
            float a0 = sp[w][(e + 0) * H + head] * invden;
            float a1 = sp[w][(e + 1) * H + head] * invden;
            float a2 = sp[w][(e + 2) * H + head] * invden;
            float a3 = sp[w][(e + 3) * H + head] * invden;
            float a4 = sp[w][(e + 4) * H + head] * invden;
            float a5 = sp[w][(e + 5) * H + head] * invden;
            float a6 = sp[w][(e + 6) * H + head] * invden;
            float a7 = sp[w][(e + 7) * H + head] * invden;
            if constexpr (VEC == 4) {
                float4 r0 = *reinterpret_cast<const float4*>(hlin + (size_t)s0 * TOT + lane * 4);
                float4 r1 = *reinterpret_cast<const float4*>(hlin + (size_t)s1 * TOT + lane * 4);
                float4 r2 = *reinterpret_cast<const float4*>(hlin + (size_t)s2 * TOT + lane * 4);
                float4 r3 = *reinterpret_cast<const float4*>(hlin + (size_t)s3 * TOT + lane * 4);
                float4 r4 = *reinterpret_cast<const float4*>(hlin + (size_t)s4 * TOT + lane * 4);
                float4 r5 = *reinterpret_cast<const float4*>(hlin + (size_t)s5 * TOT + lane * 4);
                float4 r6 = *reinterpret_cast<const float4*>(hlin + (size_t)s6 * TOT + lane * 4);
                float4 r7 = *reinterpret_cast<const float4*>(hlin + (size_t)s7 * TOT + lane * 4);
                accv.x += a0*r0.x + a1*r1.x + a2*r2.x + a3*r3.x + a4*r4.x + a5*r5.x + a6*r6.x + a7*r7.x;
                accv.y += a0*r0.y + a1*r1.y + a2*r2.y + a3*r3.y + a4*r4.y + a5*r5.y + a6*r6.y + a7*r7.y;
                accv.z += a0*r0.z + a1*r1.z + a2*r2.z + a3*r3.z + a4*r4.z + a5*r5.z + a6*r6.z + a7*r7.z;
                accv.w += a0*r0.w + a1*r1.w + a2*r2.w + a3*r3.w + a4*r4.w + a5*r5.w + a6*r6.w + a7*r7.w;
            } else {
                float r0 = hlin[(size_t)s0 * TOT + lane];
                float r1 = hlin[(size_t)s1 * TOT + lane];
                float r2 = hlin[(size_t)s2 * TOT + lane];
                float r3 = hlin[(size_t)s3 * TOT + lane];
                float r4 = hlin[(size_t)s4 * TOT + lane];
                float r5 = hlin[(size_t)s5 * TOT + lane];
                float r6 = hlin[(size_t)s6 * TOT + lane];
                float r7 = hlin[(size_t)s7 * TOT + lane];
                accv.x += a0*r0 + a1*r1 + a2*r2 + a3*r3 + a4*r4 + a5*r5 + a6*r6 + a7*r7;
            }
        }
        for (; e + 4 <= deg; e += 4) {
            int s0 = si[w][e + 0], s1 = si[w][e + 1];
            int s2 = si[w][e + 2], s3 = si[w][e + 3];
            float a0 = sp[w][(e + 0) * H + head] * invden;
            float a1 = sp[w][(e + 1) * H + head] * invden;
            float a2 = sp[w][(e + 2) * H + head] * invden;
            float a3 = sp[w][(e + 3) * H + head] * invden;
            if constexpr (VEC == 4) {
                float4 r0 = *reinterpret_cast<const float4*>(hlin + (size_t)s0 * TOT + lane * 4);
                float4 r1 = *reinterpret_cast<const float4*>(hlin + (size_t)s1 * TOT + lane * 4);
                float4 r2 = *reinterpret_cast<const float4*>(hlin + (size_t)s2 * TOT + lane * 4);
                float4 r3 = *reinterpret_cast<const float4*>(hlin + (size_t)s3 * TOT + lane * 4);
                accv.x += a0 * r0.x + a1 * r1.x + a2 * r2.x + a3 * r3.x;
                accv.y += a0 * r0.y + a1 * r1.y + a2 * r2.y + a3 * r3.y;
                accv.z += a0 * r0.z + a1 * r1.z + a2 * r2.z + a3 * r3.z;
                accv.w += a0 * r0.w + a1 * r1.w + a2 * r2.w + a3 * r3.w;
            } else {
                float r0 = hlin[(size_t)s0 * TOT + lane];
                float r1 = hlin[(size_t)s1 * TOT + lane];
                float r2 = hlin[(size_t)s2 * TOT + lane];
                float r3 = hlin[(size_t)s3 * TOT + lane];
                accv.x += a0 * r0 + a1 * r1 + a2 * r2 + a3 * r3;
            }
        }
        for (; e < deg; ++e) {
            int s = si[w][e];
            float a = sp[w][e * H + head] * invden;
            if constexpr (VEC == 4) {
                float4 rv = *reinterpret_cast<const float4*>(hlin + (size_t)s * TOT + lane * 4);
                accv.x += a * rv.x; accv.y += a * rv.y;
                accv.z += a * rv.z; accv.w += a * rv.w;
            } else {
                accv.x += a * hlin[(size_t)s * TOT + lane];
            }
        }
        if constexpr (VEC == 4) {
            int c0 = lane * 4;
            accv.x += bias[c0 + 0]; accv.y += bias[c0 + 1];
            accv.z += bias[c0 + 2]; accv.w += bias[c0 + 3];
            if (ACT) {
                accv.x = accv.x > 0.f ? accv.x : expm1f(accv.x);
                accv.y = accv.y > 0.f ? accv.y : expm1f(accv.y);
                accv.z = accv.z > 0.f ? accv.z : expm1f(accv.z);
                accv.w = accv.w > 0.f ? accv.w : expm1f(accv.w);
            }
            *reinterpret_cast<float4*>(&outf[(size_t)d * TOT + lane * 4]) = accv;
        } else {
            float o = accv.x + bias[lane];
            if (ACT) o = o > 0.f ? o : expm1f(o);
            if constexpr (POOL) {
                int g = batch[d];
                atomicAdd(&outf[(size_t)g * 64 + lane], o);
                if (lane == 0) atomicAdd(&gcnt[g], 1);
            } else {
                outf[(size_t)d * TOT + lane] = o;
            }
        }
        return;
    }

    // ---- fallback: deg > CAP, serial 3-pass (no LDS) ----
    {
        float adh = ad[head];
        float es = e_self[head];
        float m = es;
        for (int e = p0; e < p1; ++e) {
            int s = csr_src[e];
            m = fmaxf(m, lrelu(al_s[(size_t)s * H + head] + adh));
        }
        float den = __expf(es - m);
        for (int e = p0; e < p1; ++e) {
            int s = csr_src[e];
            den += __expf(lrelu(al_s[(size_t)s * H + head] + adh) - m);
        }
        den = 1.f / den;
        float accv[VEC] = {};
        {
            float alpha = __expf(es - m) * den;
            const float* hp = hlin + (size_t)d * TOT + lane * VEC;
            #pragma unroll
            for (int v = 0; v < VEC; ++v) accv[v] = alpha * hp[v];
        }
        for (int e = p0; e < p1; ++e) {
            int s = csr_src[e];
            float alpha = __expf(lrelu(al_s[(size_t)s * H + head] + adh) - m) * den;
            const float* hp = hlin + (size_t)s * TOT + lane * VEC;
            #pragma unroll
            for (int v = 0; v < VEC; ++v) accv[v] += alpha * hp[v];
        }
        #pragma unroll
        for (int v = 0; v < VEC; ++v) {
            int c = lane * VEC + v;
            float o = accv[v] + bias[c];
            if (ACT) o = o > 0.f ? o : expm1f(o);
            accv[v] = o;
        }
        if constexpr (POOL) {
            int g = batch[d];
            atomicAdd(&outf[(size_t)g * 64 + lane], accv[0]);
            if (lane == 0) atomicAdd(&gcnt[g], 1);
        } else {
            #pragma unroll
            for (int v = 0; v < VEC; ++v)
                outf[(size_t)d * TOT + lane * VEC + v] = accv[v];
        }
    }
}

// ---------------- final linear ----------------
__global__ void k_final(const float* __restrict__ gsum, const int* __restrict__ gcnt,
                        const float* __restrict__ lin_w, const float* __restrict__ lin_b,
                        float* __restrict__ out, int Gn) {
    int g = (blockIdx.x * blockDim.x + threadIdx.x) >> 6;
    int lane = threadIdx.x & 63;
    if (g >= Gn) return;
    float cnt = (float)gcnt[g];
    float inv = 1.f / fmaxf(cnt, 1.f);
    float v = gsum[(size_t)g * 64 + lane] * inv * lin_w[lane];
    #pragma unroll
    for (int off = 32; off >= 1; off >>= 1) v += __shfl_xor(v, off);
    if (lane == 0) out[g] = v + lin_b[0];
}

extern "C" void kernel_launch(void* const* d_in, const int* in_sizes, int n_in,
                              void* d_out, int out_size, void* d_ws, size_t ws_size,
                              hipStream_t stream) {
    const float* x    = (const float*)d_in[0];
    const int*   ei   = (const int*)d_in[1];
    const int*   batch= (const int*)d_in[2];
    const float* W1   = (const float*)d_in[3];
    const float* a1s  = (const float*)d_in[4];
    const float* a1d  = (const float*)d_in[5];
    const float* b1   = (const float*)d_in[6];
    const float* W2   = (const float*)d_in[7];
    const float* a2s  = (const float*)d_in[8];
    const float* a2d  = (const float*)d_in[9];
    const float* b2   = (const float*)d_in[10];
    const float* W3   = (const float*)d_in[11];
    const float* a3s  = (const float*)d_in[12];
    const float* a3d  = (const float*)d_in[13];
    const float* b3   = (const float*)d_in[14];
    const float* lw   = (const float*)d_in[15];
    const float* lb   = (const float*)d_in[16];

    int N = in_sizes[0] / 128;
    int E = in_sizes[1] / 2;
    int G = out_size;
    int RT = (N + 127) >> 7;
    int Np = RT * 128;

    char* p = (char*)d_ws;
    auto alloc = [&](size_t bytes) {
        char* r = p;
        p += (bytes + 255) & ~(size_t)255;
        return r;
    };
    float* bufA  = (float*)alloc((size_t)Np * 256 * 4);
    float* bufB  = (float*)alloc((size_t)Np * 256 * 4);
    unsigned short* pB1h = (unsigned short*)alloc((size_t)128 * 256 * 2);
    unsigned short* pB1l = (unsigned short*)alloc((size_t)128 * 256 * 2);
    unsigned short* pB2h = (unsigned short*)alloc((size_t)256 * 256 * 2);
    unsigned short* pB2l = (unsigned short*)alloc((size_t)256 * 256 * 2);
    unsigned short* pB3h = (unsigned short*)alloc((size_t)256 * 64 * 2);
    unsigned short* pB3l = (unsigned short*)alloc((size_t)256 * 64 * 2);
    float* al_s  = (float*)alloc((size_t)N * 4 * 4);
    float* al_d  = (float*)alloc((size_t)N * 4 * 4);
    int* indptr  = (int*)alloc((size_t)(N + 1) * 4);
    int* counts  = (int*)alloc((size_t)N * 4);
    int* cursor  = (int*)alloc((size_t)N * 4);
    int* csr     = (int*)alloc((size_t)E * 4);
    float* gsum  = (float*)alloc((size_t)G * 64 * 4);
    int* gcnt    = (int*)alloc((size_t)G * 4);
    if ((size_t)(p - (char*)d_ws) > ws_size) return;  // workspace too small

    hipMemsetAsync(counts, 0, (size_t)N * 4, stream);
    hipMemsetAsync(gsum, 0, (size_t)G * 64 * 4, stream);
    hipMemsetAsync(gcnt, 0, (size_t)G * 4, stream);

    // pack all weight matrices upfront (tiny)
    k_packB<<<(256 * (128 >> 3) + 255) / 256, 256, 0, stream>>>(W1, pB1h, pB1l, 128, 256);
    k_packB<<<(256 * (256 >> 3) + 255) / 256, 256, 0, stream>>>(W2, pB2h, pB2l, 256, 256);
    k_packB<<<(64 * (256 >> 3) + 255) / 256, 256, 0, stream>>>(W3, pB3h, pB3l, 256, 64);

    int eb = (E + 255) / 256;
    k_count<<<eb, 256, 0, stream>>>(ei, E, counts);
    k_scan<<<1, 1024, 0, stream>>>(counts, indptr, cursor, N);
    k_scatter<<<eb, 256, 0, stream>>>(ei, E, cursor, csr);

    int wb = (N * 64 + 255) / 256;   // one wave per node

    // layer 1: 128 -> 256 (H=4, concat, ELU)
    k_mm<4, 2, 2><<<dim3(RT, 2), 256, 0, stream>>>(x, pB1h, pB1l, bufA,
                                                   a1s, a1d, al_s, al_d, N, 128, 256);
    k_agg<4, true, false><<<wb, 256, 0, stream>>>(bufA, al_s, al_d, indptr, csr, b1, bufB,
                                                  nullptr, nullptr, N);

    // layer 2: 256 -> 256 (H=4, concat, ELU)
    k_mm<4, 2, 2><<<dim3(RT, 2), 256, 0, stream>>>(bufB, pB2h, pB2l, bufA,
                                                   a2s, a2d, al_s, al_d, N, 256, 256);
    k_agg<4, true, false><<<wb, 256, 0, stream>>>(bufA, al_s, al_d, indptr, csr, b2, bufB,
                                                  nullptr, nullptr, N);

    // layer 3: 256 -> 64 (H=1, no concat, no act) + fused mean-pool accumulate
    k_mm<2, 4, 1><<<dim3(RT, 1), 256, 0, stream>>>(bufB, pB3h, pB3l, bufA,
                                                   a3s, a3d, al_s, al_d, N, 256, 64);
    k_agg<1, false, true><<<wb, 256, 0, stream>>>(bufA, al_s, al_d, indptr, csr, b3, gsum,
                                                  batch, gcnt, N);

    int fb = (G * 64 + 255) / 256;
    k_final<<<fb, 256, 0, stream>>>(gsum, gcnt, lw, lb, (float*)d_out, G);
}

// Round 5
// 521.349 us; speedup vs baseline: 2.0193x; 1.2310x over previous
//
#include <hip/hip_runtime.h>
#include <cstdint>
#include <cstddef>

#define NEG_SLOPE 0.2f

typedef __attribute__((ext_vector_type(8))) short short8;
typedef __attribute__((ext_vector_type(4))) float f32x4;

__device__ __forceinline__ float lrelu(float v) { return v > 0.f ? v : NEG_SLOPE * v; }

__device__ __forceinline__ unsigned short f2bf(float x) {
    unsigned u = __float_as_uint(x);
    u = (u + 0x7FFFu + ((u >> 16) & 1u)) >> 16;
    return (unsigned short)u;
}
__device__ __forceinline__ float bf2f(unsigned short h) {
    return __uint_as_float(((unsigned)h) << 16);
}

// ---------------- CSR build ----------------
__global__ void k_count(const int* __restrict__ ei, int E, int* __restrict__ counts) {
    int i = blockIdx.x * blockDim.x + threadIdx.x;
    if (i < E) atomicAdd(&counts[ei[E + i]], 1);
}

__global__ void k_scan(const int* __restrict__ counts, int* __restrict__ indptr,
                       int* __restrict__ cursor, int Nn) {
    __shared__ int sdata[1024];
    int tid = threadIdx.x;
    int chunk = (Nn + 1023) >> 10;
    int start = tid * chunk;
    int end = start + chunk; if (end > Nn) end = Nn;
    int local = 0;
    for (int i = start; i < end; ++i) local += counts[i];
    sdata[tid] = local;
    __syncthreads();
    for (int off = 1; off < 1024; off <<= 1) {
        int v = (tid >= off) ? sdata[tid - off] : 0;
        __syncthreads();
        sdata[tid] += v;
        __syncthreads();
    }
    int run = sdata[tid] - local;  // exclusive prefix
    for (int i = start; i < end; ++i) {
        indptr[i] = run; cursor[i] = run; run += counts[i];
    }
    if (tid == 0) indptr[Nn] = sdata[1023];
}

__global__ void k_scatter(const int* __restrict__ ei, int E, int* __restrict__ cursor,
                          int* __restrict__ csr_src) {
    int i = blockIdx.x * blockDim.x + threadIdx.x;
    if (i < E) {
        int s = ei[i], d = ei[E + i];
        int pos = atomicAdd(&cursor[d], 1);
        csr_src[pos] = s;
    }
}

// ---------------- pack B (W f32 [K,M] -> fragment-packed bf16 hi/lo, RNE) ----------------
__global__ __launch_bounds__(256) void k_packB(const float* __restrict__ W,
        unsigned short* __restrict__ Ph, unsigned short* __restrict__ Pl, int K, int M) {
    int tid = blockIdx.x * 256 + threadIdx.x;
    int KS8 = K >> 3;
    int total = M * KS8;
    if (tid >= total) return;
    int col = tid / KS8;
    int k = (tid - col * KS8) << 3;
    short8 hv, lv;
    #pragma unroll
    for (int j = 0; j < 8; ++j) {
        float x = W[(size_t)(k + j) * M + col];
        unsigned short hb = f2bf(x);
        hv[j] = (short)hb;
        lv[j] = (short)f2bf(x - bf2f(hb));
    }
    int ct64 = col >> 6, c = col & 63;
    int fb = c >> 4, cl = c & 15;
    int ks = k >> 5, kg = (k >> 3) & 3;
    int lane = cl | (kg << 4);
    size_t off = (((size_t)ct64 * (K >> 5) + ks) * 4 + fb) * 64 + lane;
    *reinterpret_cast<short8*>(Ph + off * 8) = hv;
    *reinterpret_cast<short8*>(Pl + off * 8) = lv;
}

// ---------------- split-bf16 MFMA GEMM, A converted in-kernel, C stored bf16 ----------------
// block = 256 threads = 4 waves (WR x WC); wave tile = AF*16 rows x 64 cols (BF=4)
// acc = Al*Bh + Ah*Bl + Ah*Bh ; attention dots computed from f32 acc (exact-ish)
template<int AF, int WR, int WC>
__global__ __launch_bounds__(256) void k_mm(const float* __restrict__ A,
        const unsigned short* __restrict__ Bh, const unsigned short* __restrict__ Bl,
        unsigned short* __restrict__ C, const float* __restrict__ a_src, const float* __restrict__ a_dst,
        float* __restrict__ al_s, float* __restrict__ al_d, int Nrows, int K, int M) {
    constexpr int BF = 4;
    int wave = threadIdx.x >> 6, lane = threadIdx.x & 63;
    int wr = wave / WC, wc = wave % WC;
    int rt = blockIdx.x;
    int ct64 = blockIdx.y * WC + wc;
    int KS = K >> 5;
    int rl = lane & 15, kg = lane >> 4;
    const short8* B8h = reinterpret_cast<const short8*>(Bh);
    const short8* B8l = reinterpret_cast<const short8*>(Bl);

    const float* aptr[AF];
    #pragma unroll
    for (int f = 0; f < AF; ++f) {
        int row = rt * 128 + wr * (AF * 16) + f * 16 + rl;
        if (row > Nrows - 1) row = Nrows - 1;   // clamp: OOB rows produce junk, discarded at store
        aptr[f] = A + (size_t)row * K + kg * 8;
    }

    f32x4 acc[AF][BF];
    #pragma unroll
    for (int i = 0; i < AF; ++i)
        #pragma unroll
        for (int j = 0; j < BF; ++j)
            acc[i][j] = (f32x4){0.f, 0.f, 0.f, 0.f};

    for (int ks = 0; ks < KS; ++ks) {
        short8 a_h[AF], a_l[AF], b_h[BF], b_l[BF];
        #pragma unroll
        for (int f = 0; f < AF; ++f) {
            const float* ap = aptr[f] + ks * 32;
            float4 v0 = *reinterpret_cast<const float4*>(ap);
            float4 v1 = *reinterpret_cast<const float4*>(ap + 4);
            float vv[8] = {v0.x, v0.y, v0.z, v0.w, v1.x, v1.y, v1.z, v1.w};
            #pragma unroll
            for (int j = 0; j < 8; ++j) {
                unsigned u = __float_as_uint(vv[j]);
                unsigned short hb = (unsigned short)(u >> 16);        // trunc split
                float hf = __uint_as_float(u & 0xFFFF0000u);
                float lf = vv[j] - hf;
                unsigned short lb = (unsigned short)(__float_as_uint(lf) >> 16);
                a_h[f][j] = (short)hb;
                a_l[f][j] = (short)lb;
            }
        }
        #pragma unroll
        for (int f = 0; f < BF; ++f) {
            size_t off = (((size_t)ct64 * KS + ks) * 4 + f) * 64 + lane;
            b_h[f] = B8h[off]; b_l[f] = B8l[off];
        }
        #pragma unroll
        for (int i = 0; i < AF; ++i)
            #pragma unroll
            for (int j = 0; j < BF; ++j) {
                acc[i][j] = __builtin_amdgcn_mfma_f32_16x16x32_bf16(a_l[i], b_h[j], acc[i][j], 0, 0, 0);
                acc[i][j] = __builtin_amdgcn_mfma_f32_16x16x32_bf16(a_h[i], b_l[j], acc[i][j], 0, 0, 0);
                acc[i][j] = __builtin_amdgcn_mfma_f32_16x16x32_bf16(a_h[i], b_h[j], acc[i][j], 0, 0, 0);
            }
    }

    int H = M >> 6;
    int head = ct64;                 // wave col span 64 == one head
    int col0 = ct64 * 64;
    int cl = lane & 15, rgrp = lane >> 4;

    float as_[BF], ad_[BF];
    #pragma unroll
    for (int j = 0; j < BF; ++j) {
        as_[j] = a_src[col0 + j * 16 + cl];
        ad_[j] = a_dst[col0 + j * 16 + cl];
    }

    #pragma unroll
    for (int i = 0; i < AF; ++i) {
        int rowb = rt * 128 + wr * (AF * 16) + i * 16 + rgrp * 4;
        #pragma unroll
        for (int r = 0; r < 4; ++r) {
            float sv = acc[i][0][r] * as_[0] + acc[i][1][r] * as_[1]
                     + acc[i][2][r] * as_[2] + acc[i][3][r] * as_[3];
            float dv = acc[i][0][r] * ad_[0] + acc[i][1][r] * ad_[1]
                     + acc[i][2][r] * ad_[2] + acc[i][3][r] * ad_[3];
            #pragma unroll
            for (int o = 1; o < 16; o <<= 1) {
                sv += __shfl_xor(sv, o);
                dv += __shfl_xor(dv, o);
            }
            int row = rowb + r;
            if (row < Nrows) {
                unsigned short* cp = &C[(size_t)row * M + col0 + cl];
                cp[0]  = f2bf(acc[i][0][r]);
                cp[16] = f2bf(acc[i][1][r]);
                cp[32] = f2bf(acc[i][2][r]);
                cp[48] = f2bf(acc[i][3][r]);
                if (cl == 0) {
                    al_s[(size_t)row * H + head] = sv;
                    al_d[(size_t)row * H + head] = dv;
                }
            }
        }
    }
}

// ---------------- fused softmax + aggregate (wave per destination node) ----------------
// hlin is bf16 (values); al_s/al_d are f32 (coefficients) -> weights ~exact.
template <int H, bool ACT, bool POOL>    // TOT = H*64
__global__ __launch_bounds__(256) void k_agg(const unsigned short* __restrict__ hlin,
                      const float* __restrict__ al_s,
                      const float* __restrict__ al_d, const int* __restrict__ indptr,
                      const int* __restrict__ csr_src, const float* __restrict__ bias,
                      float* __restrict__ outf, const int* __restrict__ batch,
                      int* __restrict__ gcnt, int Nn) {
    constexpr int TOT = H * 64;
    constexpr int VEC = TOT / 64;
    constexpr int CAP = 128;
    __shared__ float sp[4][CAP * H];
    __shared__ int   si[4][CAP];
    int w = threadIdx.x >> 6;
    int lane = threadIdx.x & 63;
    int node = (blockIdx.x * blockDim.x + threadIdx.x) >> 6;
    if (node >= Nn) return;
    int d = node;
    int p0 = indptr[d], p1 = indptr[d + 1];
    int deg = p1 - p0;
    int head = (lane * VEC) >> 6;       // H=4: lane>>4 ; H=1: 0

    float ad[H], e_self[H];
    if constexpr (H == 4) {
        float4 adv = *reinterpret_cast<const float4*>(&al_d[(size_t)d * 4]);
        float4 asv = *reinterpret_cast<const float4*>(&al_s[(size_t)d * 4]);
        ad[0] = adv.x; ad[1] = adv.y; ad[2] = adv.z; ad[3] = adv.w;
        e_self[0] = lrelu(asv.x + ad[0]); e_self[1] = lrelu(asv.y + ad[1]);
        e_self[2] = lrelu(asv.z + ad[2]); e_self[3] = lrelu(asv.w + ad[3]);
    } else {
        ad[0] = al_d[d];
        e_self[0] = lrelu(al_s[d] + ad[0]);
    }

    float mh, invden, alpha_self;

    if (deg <= CAP) {
        int nb = (deg + 63) >> 6;
        float m[H];
        #pragma unroll
        for (int h = 0; h < H; ++h) m[h] = e_self[h];
        for (int b = 0; b < nb; ++b) {
            int l = b * 64 + lane;
            float e_h[H];
            if (l < deg) {
                int s = csr_src[p0 + l];
                si[w][l] = s;
                if constexpr (H == 4) {
                    float4 sv = *reinterpret_cast<const float4*>(&al_s[(size_t)s * 4]);
                    e_h[0] = lrelu(sv.x + ad[0]); e_h[1] = lrelu(sv.y + ad[1]);
                    e_h[2] = lrelu(sv.z + ad[2]); e_h[3] = lrelu(sv.w + ad[3]);
                } else {
                    e_h[0] = lrelu(al_s[s] + ad[0]);
                }
            } else {
                #pragma unroll
                for (int h = 0; h < H; ++h) e_h[h] = -1e30f;
            }
            #pragma unroll
            for (int h = 0; h < H; ++h) {
                sp[w][l * H + h] = e_h[h];
                m[h] = fmaxf(m[h], e_h[h]);
            }
        }
        #pragma unroll
        for (int h = 0; h < H; ++h)
            #pragma unroll
            for (int off = 1; off < 64; off <<= 1)
                m[h] = fmaxf(m[h], __shfl_xor(m[h], off));
        float den[H];
        #pragma unroll
        for (int h = 0; h < H; ++h) den[h] = 0.f;
        for (int b = 0; b < nb; ++b) {
            int l = b * 64 + lane;
            #pragma unroll
            for (int h = 0; h < H; ++h) {
                float pv = __expf(sp[w][l * H + h] - m[h]);
                sp[w][l * H + h] = pv;
                den[h] += pv;
            }
        }
        #pragma unroll
        for (int h = 0; h < H; ++h) {
            #pragma unroll
            for (int off = 1; off < 64; off <<= 1)
                den[h] += __shfl_xor(den[h], off);
            den[h] += __expf(e_self[h] - m[h]);
        }
        mh = m[head];
        invden = 1.f / den[head];
        alpha_self = __expf(e_self[head] - mh) * invden;

        float4 accv = make_float4(0.f, 0.f, 0.f, 0.f);
        {
            const unsigned short* hp = hlin + (size_t)d * TOT + lane * VEC;
            if constexpr (VEC == 4) {
                ushort4 hv = *reinterpret_cast<const ushort4*>(hp);
                accv.x = alpha_self * bf2f(hv.x); accv.y = alpha_self * bf2f(hv.y);
                accv.z = alpha_self * bf2f(hv.z); accv.w = alpha_self * bf2f(hv.w);
            } else {
                accv.x = alpha_self * bf2f(hp[0]);
            }
        }
        int e = 0;
        for (; e + 8 <= deg; e += 8) {
            int s0 = si[w][e + 0], s1 = si[w][e + 1], s2 = si[w][e + 2], s3 = si[w][e + 3];
            int s4 = si[w][e + 4], s5 = si[w][e + 5], s6 = si[w][e + 6], s7 = si[w][e + 7];
            float a0 = sp[w][(e + 0) * H + head] * invden;
            float a1 = sp[w][(e + 1) * H + head] * invden;
            float a2 = sp[w][(e + 2) * H + head] * invden;
            float a3 = sp[w][(e + 3) * H + head] * invden;
            float a4 = sp[w][(e + 4) * H + head] * invden;
            float a5 = sp[w][(e + 5) * H + head] * invden;
            float a6 = sp[w][(e + 6) * H + head] * invden;
            float a7 = sp[w][(e + 7) * H + head] * invden;
            if constexpr (VEC == 4) {
                ushort4 r0 = *reinterpret_cast<const ushort4*>(hlin + (size_t)s0 * TOT + lane * 4);
                ushort4 r1 = *reinterpret_cast<const ushort4*>(hlin + (size_t)s1 * TOT + lane * 4);
                ushort4 r2 = *reinterpret_cast<const ushort4*>(hlin + (size_t)s2 * TOT + lane * 4);
                ushort4 r3 = *reinterpret_cast<const ushort4*>(hlin + (size_t)s3 * TOT + lane * 4);
                ushort4 r4 = *reinterpret_cast<const ushort4*>(hlin + (size_t)s4 * TOT + lane * 4);
                ushort4 r5 = *reinterpret_cast<const ushort4*>(hlin + (size_t)s5 * TOT + lane * 4);
                ushort4 r6 = *reinterpret_cast<const ushort4*>(hlin + (size_t)s6 * TOT + lane * 4);
                ushort4 r7 = *reinterpret_cast<const ushort4*>(hlin + (size_t)s7 * TOT + lane * 4);
                accv.x += a0*bf2f(r0.x) + a1*bf2f(r1.x) + a2*bf2f(r2.x) + a3*bf2f(r3.x)
                        + a4*bf2f(r4.x) + a5*bf2f(r5.x) + a6*bf2f(r6.x) + a7*bf2f(r7.x);
                accv.y += a0*bf2f(r0.y) + a1*bf2f(r1.y) + a2*bf2f(r2.y) + a3*bf2f(r3.y)
                        + a4*bf2f(r4.y) + a5*bf2f(r5.y) + a6*bf2f(r6.y) + a7*bf2f(r7.y);
                accv.z += a0*bf2f(r0.z) + a1*bf2f(r1.z) + a2*bf2f(r2.z) + a3*bf2f(r3.z)
                        + a4*bf2f(r4.z) + a5*bf2f(r5.z) + a6*bf2f(r6.z) + a7*bf2f(r7.z);
                accv.w += a0*bf2f(r0.w) + a1*bf2f(r1.w) + a2*bf2f(r2.w) + a3*bf2f(r3.w)
                        + a4*bf2f(r4.w) + a5*bf2f(r5.w) + a6*bf2f(r6.w) + a7*bf2f(r7.w);
            } else {
                float r0 = bf2f(hlin[(size_t)s0 * TOT + lane]);
                float r1 = bf2f(hlin[(size_t)s1 * TOT + lane]);
                float r2 = bf2f(hlin[(size_t)s2 * TOT + lane]);
                float r3 = bf2f(hlin[(size_t)s3 * TOT + lane]);
                float r4 = bf2f(hlin[(size_t)s4 * TOT + lane]);
                float r5 = bf2f(hlin[(size_t)s5 * TOT + lane]);
                float r6 = bf2f(hlin[(size_t)s6 * TOT + lane]);
                float r7 = bf2f(hlin[(size_t)s7 * TOT + lane]);
                accv.x += a0*r0 + a1*r1 + a2*r2 + a3*r3 + a4*r4 + a5*r5 + a6*r6 + a7*r7;
            }
        }
        for (; e + 4 <= deg; e += 4) {
            int s0 = si[w][e + 0], s1 = si[w][e + 1];
            int s2 = si[w][e + 2], s3 = si[w][e + 3];
            float a0 = sp[w][(e + 0) * H + head] * invden;
            float a1 = sp[w][(e + 1) * H + head] * invden;
            float a2 = sp[w][(e + 2) * H + head] * invden;
            float a3 = sp[w][(e + 3) * H + head] * invden;
            if constexpr (VEC == 4) {
                ushort4 r0 = *reinterpret_cast<const ushort4*>(hlin + (size_t)s0 * TOT + lane * 4);
                ushort4 r1 = *reinterpret_cast<const ushort4*>(hlin + (size_t)s1 * TOT + lane * 4);
                ushort4 r2 = *reinterpret_cast<const ushort4*>(hlin + (size_t)s2 * TOT + lane * 4);
                ushort4 r3 = *reinterpret_cast<const ushort4*>(hlin + (size_t)s3 * TOT + lane * 4);
                accv.x += a0*bf2f(r0.x) + a1*bf2f(r1.x) + a2*bf2f(r2.x) + a3*bf2f(r3.x);
                accv.y += a0*bf2f(r0.y) + a1*bf2f(r1.y) + a2*bf2f(r2.y) + a3*bf2f(r3.y);
                accv.z += a0*bf2f(r0.z) + a1*bf2f(r1.z) + a2*bf2f(r2.z) + a3*bf2f(r3.z);
                accv.w += a0*bf2f(r0.w) + a1*bf2f(r1.w) + a2*bf2f(r2.w) + a3*bf2f(r3.w);
            } else {
                float r0 = bf2f(hlin[(size_t)s0 * TOT + lane]);
                float r1 = bf2f(hlin[(size_t)s1 * TOT + lane]);
                float r2 = bf2f(hlin[(size_t)s2 * TOT + lane]);
                float r3 = bf2f(hlin[(size_t)s3 * TOT + lane]);
                accv.x += a0 * r0 + a1 * r1 + a2 * r2 + a3 * r3;
            }
        }
        for (; e < deg; ++e) {
            int s = si[w][e];
            float a = sp[w][e * H + head] * invden;
            if constexpr (VEC == 4) {
                ushort4 rv = *reinterpret_cast<const ushort4*>(hlin + (size_t)s * TOT + lane * 4);
                accv.x += a * bf2f(rv.x); accv.y += a * bf2f(rv.y);
                accv.z += a * bf2f(rv.z); accv.w += a * bf2f(rv.w);
            } else {
                accv.x += a * bf2f(hlin[(size_t)s * TOT + lane]);
            }
        }
        if constexpr (VEC == 4) {
            int c0 = lane * 4;
            accv.x += bias[c0 + 0]; accv.y += bias[c0 + 1];
            accv.z += bias[c0 + 2]; accv.w += bias[c0 + 3];
            if (ACT) {
                accv.x = accv.x > 0.f ? accv.x : expm1f(accv.x);
                accv.y = accv.y > 0.f ? accv.y : expm1f(accv.y);
                accv.z = accv.z > 0.f ? accv.z : expm1f(accv.z);
                accv.w = accv.w > 0.f ? accv.w : expm1f(accv.w);
            }
            *reinterpret_cast<float4*>(&outf[(size_t)d * TOT + lane * 4]) = accv;
        } else {
            float o = accv.x + bias[lane];
            if (ACT) o = o > 0.f ? o : expm1f(o);
            if constexpr (POOL) {
                int g = batch[d];
                atomicAdd(&outf[(size_t)g * 64 + lane], o);
                if (lane == 0) atomicAdd(&gcnt[g], 1);
            } else {
                outf[(size_t)d * TOT + lane] = o;
            }
        }
        return;
    }

    // ---- fallback: deg > CAP, serial 3-pass (no LDS) ----
    {
        float adh = ad[head];
        float es = e_self[head];
        float m = es;
        for (int e = p0; e < p1; ++e) {
            int s = csr_src[e];
            m = fmaxf(m, lrelu(al_s[(size_t)s * H + head] + adh));
        }
        float den = __expf(es - m);
        for (int e = p0; e < p1; ++e) {
            int s = csr_src[e];
            den += __expf(lrelu(al_s[(size_t)s * H + head] + adh) - m);
        }
        den = 1.f / den;
        float accv[VEC] = {};
        {
            float alpha = __expf(es - m) * den;
            const unsigned short* hp = hlin + (size_t)d * TOT + lane * VEC;
            #pragma unroll
            for (int v = 0; v < VEC; ++v) accv[v] = alpha * bf2f(hp[v]);
        }
        for (int e = p0; e < p1; ++e) {
            int s = csr_src[e];
            float alpha = __expf(lrelu(al_s[(size_t)s * H + head] + adh) - m) * den;
            const unsigned short* hp = hlin + (size_t)s * TOT + lane * VEC;
            #pragma unroll
            for (int v = 0; v < VEC; ++v) accv[v] += alpha * bf2f(hp[v]);
        }
        #pragma unroll
        for (int v = 0; v < VEC; ++v) {
            int c = lane * VEC + v;
            float o = accv[v] + bias[c];
            if (ACT) o = o > 0.f ? o : expm1f(o);
            accv[v] = o;
        }
        if constexpr (POOL) {
            int g = batch[d];
            atomicAdd(&outf[(size_t)g * 64 + lane], accv[0]);
            if (lane == 0) atomicAdd(&gcnt[g], 1);
        } else {
            #pragma unroll
            for (int v = 0; v < VEC; ++v)
                outf[(size_t)d * TOT + lane * VEC + v] = accv[v];
        }
    }
}

// ---------------- final linear ----------------
__global__ void k_final(const float* __restrict__ gsum, const int* __restrict__ gcnt,
                        const float* __restrict__ lin_w, const float* __restrict__ lin_b,
                        float* __restrict__ out, int Gn) {
    int g = (blockIdx.x * blockDim.x + threadIdx.x) >> 6;
    int lane = threadIdx.x & 63;
    if (g >= Gn) return;
    float cnt = (float)gcnt[g];
    float inv = 1.f / fmaxf(cnt, 1.f);
    float v = gsum[(size_t)g * 64 + lane] * inv * lin_w[lane];
    #pragma unroll
    for (int off = 32; off >= 1; off >>= 1) v += __shfl_xor(v, off);
    if (lane == 0) out[g] = v + lin_b[0];
}

extern "C" void kernel_launch(void* const* d_in, const int* in_sizes, int n_in,
                              void* d_out, int out_size, void* d_ws, size_t ws_size,
                              hipStream_t stream) {
    const float* x    = (const float*)d_in[0];
    const int*   ei   = (const int*)d_in[1];
    const int*   batch= (const int*)d_in[2];
    const float* W1   = (const float*)d_in[3];
    const float* a1s  = (const float*)d_in[4];
    const float* a1d  = (const float*)d_in[5];
    const float* b1   = (const float*)d_in[6];
    const float* W2   = (const float*)d_in[7];
    const float* a2s  = (const float*)d_in[8];
    const float* a2d  = (const float*)d_in[9];
    const float* b2   = (const float*)d_in[10];
    const float* W3   = (const float*)d_in[11];
    const float* a3s  = (const float*)d_in[12];
    const float* a3d  = (const float*)d_in[13];
    const float* b3   = (const float*)d_in[14];
    const float* lw   = (const float*)d_in[15];
    const float* lb   = (const float*)d_in[16];

    int N = in_sizes[0] / 128;
    int E = in_sizes[1] / 2;
    int G = out_size;
    int RT = (N + 127) >> 7;
    int Np = RT * 128;

    char* p = (char*)d_ws;
    auto alloc = [&](size_t bytes) {
        char* r = p;
        p += (bytes + 255) & ~(size_t)255;
        return r;
    };
    unsigned short* hbuf = (unsigned short*)alloc((size_t)Np * 256 * 2);  // bf16 GEMM output
    float* aggbuf = (float*)alloc((size_t)Np * 256 * 4);                  // f32 agg output
    unsigned short* pB1h = (unsigned short*)alloc((size_t)128 * 256 * 2);
    unsigned short* pB1l = (unsigned short*)alloc((size_t)128 * 256 * 2);
    unsigned short* pB2h = (unsigned short*)alloc((size_t)256 * 256 * 2);
    unsigned short* pB2l = (unsigned short*)alloc((size_t)256 * 256 * 2);
    unsigned short* pB3h = (unsigned short*)alloc((size_t)256 * 64 * 2);
    unsigned short* pB3l = (unsigned short*)alloc((size_t)256 * 64 * 2);
    float* al_s  = (float*)alloc((size_t)N * 4 * 4);
    float* al_d  = (float*)alloc((size_t)N * 4 * 4);
    int* indptr  = (int*)alloc((size_t)(N + 1) * 4);
    int* counts  = (int*)alloc((size_t)N * 4);
    int* cursor  = (int*)alloc((size_t)N * 4);
    int* csr     = (int*)alloc((size_t)E * 4);
    float* gsum  = (float*)alloc((size_t)G * 64 * 4);
    int* gcnt    = (int*)alloc((size_t)G * 4);
    if ((size_t)(p - (char*)d_ws) > ws_size) return;  // workspace too small

    hipMemsetAsync(counts, 0, (size_t)N * 4, stream);
    hipMemsetAsync(gsum, 0, (size_t)G * 64 * 4, stream);
    hipMemsetAsync(gcnt, 0, (size_t)G * 4, stream);

    // pack all weight matrices upfront (tiny)
    k_packB<<<(256 * (128 >> 3) + 255) / 256, 256, 0, stream>>>(W1, pB1h, pB1l, 128, 256);
    k_packB<<<(256 * (256 >> 3) + 255) / 256, 256, 0, stream>>>(W2, pB2h, pB2l, 256, 256);
    k_packB<<<(64 * (256 >> 3) + 255) / 256, 256, 0, stream>>>(W3, pB3h, pB3l, 256, 64);

    int eb = (E + 255) / 256;
    k_count<<<eb, 256, 0, stream>>>(ei, E, counts);
    k_scan<<<1, 1024, 0, stream>>>(counts, indptr, cursor, N);
    k_scatter<<<eb, 256, 0, stream>>>(ei, E, cursor, csr);

    int wb = (N * 64 + 255) / 256;   // one wave per node

    // layer 1: 128 -> 256 (H=4, concat, ELU)
    k_mm<4, 2, 2><<<dim3(RT, 2), 256, 0, stream>>>(x, pB1h, pB1l, hbuf,
                                                   a1s, a1d, al_s, al_d, N, 128, 256);
    k_agg<4, true, false><<<wb, 256, 0, stream>>>(hbuf, al_s, al_d, indptr, csr, b1, aggbuf,
                                                  nullptr, nullptr, N);

    // layer 2: 256 -> 256 (H=4, concat, ELU)
    k_mm<4, 2, 2><<<dim3(RT, 2), 256, 0, stream>>>(aggbuf, pB2h, pB2l, hbuf,
                                                   a2s, a2d, al_s, al_d, N, 256, 256);
    k_agg<4, true, false><<<wb, 256, 0, stream>>>(hbuf, al_s, al_d, indptr, csr, b2, aggbuf,
                                                  nullptr, nullptr, N);

    // layer 3: 256 -> 64 (H=1, no concat, no act) + fused mean-pool accumulate
    k_mm<2, 4, 1><<<dim3(RT, 1), 256, 0, stream>>>(aggbuf, pB3h, pB3l, hbuf,
                                                   a3s, a3d, al_s, al_d, N, 256, 64);
    k_agg<1, false, true><<<wb, 256, 0, stream>>>(hbuf, al_s, al_d, indptr, csr, b3, gsum,
                                                  batch, gcnt, N);

    int fb = (G * 64 + 255) / 256;
    k_final<<<fb, 256, 0, stream>>>(gsum, gcnt, lw, lb, (float*)d_out, G);
}

// Round 6
// 422.688 us; speedup vs baseline: 2.4906x; 1.2334x over previous
//
#include <hip/hip_runtime.h>
#include <cstdint>
#include <cstddef>

#define NEG_SLOPE 0.2f

typedef __attribute__((ext_vector_type(8))) short short8;
typedef __attribute__((ext_vector_type(4))) float f32x4;

__device__ __forceinline__ float lrelu(float v) { return v > 0.f ? v : NEG_SLOPE * v; }

__device__ __forceinline__ unsigned short f2bf(float x) {
    unsigned u = __float_as_uint(x);
    u = (u + 0x7FFFu + ((u >> 16) & 1u)) >> 16;
    return (unsigned short)u;
}
__device__ __forceinline__ float bf2f(unsigned short h) {
    return __uint_as_float(((unsigned)h) << 16);
}

// ---------------- CSR build ----------------
__global__ void k_count(const int* __restrict__ ei, int E, int* __restrict__ counts) {
    int i = blockIdx.x * blockDim.x + threadIdx.x;
    if (i < E) atomicAdd(&counts[ei[E + i]], 1);
}

// hierarchical scan, step 1: per-block (1024 elems) local exclusive scan + block sum
__global__ __launch_bounds__(256) void k_scan_local(const int* __restrict__ counts,
        int* __restrict__ local_ex, int* __restrict__ bsums, int Nn) {
    int base = blockIdx.x * 1024;
    int tid = threadIdx.x;
    int idx = base + tid * 4;
    int4 v = make_int4(0, 0, 0, 0);
    if (idx + 3 < Nn) {
        v = *reinterpret_cast<const int4*>(&counts[idx]);
    } else {
        if (idx + 0 < Nn) v.x = counts[idx + 0];
        if (idx + 1 < Nn) v.y = counts[idx + 1];
        if (idx + 2 < Nn) v.z = counts[idx + 2];
        if (idx + 3 < Nn) v.w = counts[idx + 3];
    }
    int t = v.x + v.y + v.z + v.w;
    int lane = tid & 63, wave = tid >> 6;
    int s = t;
    #pragma unroll
    for (int off = 1; off < 64; off <<= 1) {
        int u = __shfl_up(s, off);
        if (lane >= off) s += u;
    }
    __shared__ int wsum[4];
    if (lane == 63) wsum[wave] = s;
    __syncthreads();
    int wo = 0;
    #pragma unroll
    for (int wv = 0; wv < 4; ++wv) wo += (wv < wave) ? wsum[wv] : 0;
    int ex = wo + s - t;
    int4 o;
    o.x = ex; o.y = ex + v.x; o.z = ex + v.x + v.y; o.w = ex + v.x + v.y + v.z;
    if (idx + 3 < Nn) {
        *reinterpret_cast<int4*>(&local_ex[idx]) = o;
    } else {
        if (idx + 0 < Nn) local_ex[idx + 0] = o.x;
        if (idx + 1 < Nn) local_ex[idx + 1] = o.y;
        if (idx + 2 < Nn) local_ex[idx + 2] = o.z;
        if (idx + 3 < Nn) local_ex[idx + 3] = o.w;
    }
    if (tid == 255) bsums[blockIdx.x] = wo + s;
}

// step 2: single block scans block sums in-place (exclusive). nb <= 256.
__global__ __launch_bounds__(256) void k_scan_bsums(int* __restrict__ bsums, int nb) {
    int tid = threadIdx.x;
    int v = (tid < nb) ? bsums[tid] : 0;
    int lane = tid & 63, wave = tid >> 6;
    int s = v;
    #pragma unroll
    for (int off = 1; off < 64; off <<= 1) {
        int u = __shfl_up(s, off);
        if (lane >= off) s += u;
    }
    __shared__ int wsum[4];
    if (lane == 63) wsum[wave] = s;
    __syncthreads();
    int wo = 0;
    #pragma unroll
    for (int wv = 0; wv < 4; ++wv) wo += (wv < wave) ? wsum[wv] : 0;
    if (tid < nb) bsums[tid] = wo + s - v;
}

// step 3: add block offsets; write indptr + cursor; indptr[Nn] = E.
__global__ __launch_bounds__(256) void k_scan_add(const int* __restrict__ local_ex,
        const int* __restrict__ bsums, int* __restrict__ indptr, int* __restrict__ cursor,
        int Nn, int Etot) {
    int i = blockIdx.x * 256 + threadIdx.x;
    if (i < Nn) {
        int val = local_ex[i] + bsums[i >> 10];
        indptr[i] = val;
        cursor[i] = val;
    } else if (i == Nn) {
        indptr[Nn] = Etot;
    }
}

__global__ void k_scatter(const int* __restrict__ ei, int E, int* __restrict__ cursor,
                          int* __restrict__ csr_src) {
    int i = blockIdx.x * blockDim.x + threadIdx.x;
    if (i < E) {
        int s = ei[i], d = ei[E + i];
        int pos = atomicAdd(&cursor[d], 1);
        csr_src[pos] = s;
    }
}

// ---------------- pack B (W f32 [K,M] -> fragment-packed bf16 hi/lo, RNE) ----------------
__global__ __launch_bounds__(256) void k_packB(const float* __restrict__ W,
        unsigned short* __restrict__ Ph, unsigned short* __restrict__ Pl, int K, int M) {
    int tid = blockIdx.x * 256 + threadIdx.x;
    int KS8 = K >> 3;
    int total = M * KS8;
    if (tid >= total) return;
    int col = tid / KS8;
    int k = (tid - col * KS8) << 3;
    short8 hv, lv;
    #pragma unroll
    for (int j = 0; j < 8; ++j) {
        float x = W[(size_t)(k + j) * M + col];
        unsigned short hb = f2bf(x);
        hv[j] = (short)hb;
        lv[j] = (short)f2bf(x - bf2f(hb));
    }
    int ct64 = col >> 6, c = col & 63;
    int fb = c >> 4, cl = c & 15;
    int ks = k >> 5, kg = (k >> 3) & 3;
    int lane = cl | (kg << 4);
    size_t off = (((size_t)ct64 * (K >> 5) + ks) * 4 + fb) * 64 + lane;
    *reinterpret_cast<short8*>(Ph + off * 8) = hv;
    *reinterpret_cast<short8*>(Pl + off * 8) = lv;
}

// ---------------- split-bf16 MFMA GEMM, A converted in-kernel, C stored bf16 ----------------
template<int AF, int WR, int WC>
__global__ __launch_bounds__(256) void k_mm(const float* __restrict__ A,
        const unsigned short* __restrict__ Bh, const unsigned short* __restrict__ Bl,
        unsigned short* __restrict__ C, const float* __restrict__ a_src, const float* __restrict__ a_dst,
        float* __restrict__ al_s, float* __restrict__ al_d, int Nrows, int K, int M) {
    constexpr int BF = 4;
    int wave = threadIdx.x >> 6, lane = threadIdx.x & 63;
    int wr = wave / WC, wc = wave % WC;
    int rt = blockIdx.x;
    int ct64 = blockIdx.y * WC + wc;
    int KS = K >> 5;
    int rl = lane & 15, kg = lane >> 4;
    const short8* B8h = reinterpret_cast<const short8*>(Bh);
    const short8* B8l = reinterpret_cast<const short8*>(Bl);

    const float* aptr[AF];
    #pragma unroll
    for (int f = 0; f < AF; ++f) {
        int row = rt * 128 + wr * (AF * 16) + f * 16 + rl;
        if (row > Nrows - 1) row = Nrows - 1;   // clamp: OOB rows produce junk, discarded at store
        aptr[f] = A + (size_t)row * K + kg * 8;
    }

    f32x4 acc[AF][BF];
    #pragma unroll
    for (int i = 0; i < AF; ++i)
        #pragma unroll
        for (int j = 0; j < BF; ++j)
            acc[i][j] = (f32x4){0.f, 0.f, 0.f, 0.f};

    for (int ks = 0; ks < KS; ++ks) {
        short8 a_h[AF], a_l[AF], b_h[BF], b_l[BF];
        #pragma unroll
        for (int f = 0; f < AF; ++f) {
            const float* ap = aptr[f] + ks * 32;
            float4 v0 = *reinterpret_cast<const float4*>(ap);
            float4 v1 = *reinterpret_cast<const float4*>(ap + 4);
            float vv[8] = {v0.x, v0.y, v0.z, v0.w, v1.x, v1.y, v1.z, v1.w};
            #pragma unroll
            for (int j = 0; j < 8; ++j) {
                unsigned u = __float_as_uint(vv[j]);
                unsigned short hb = (unsigned short)(u >> 16);        // trunc split
                float hf = __uint_as_float(u & 0xFFFF0000u);
                float lf = vv[j] - hf;
                unsigned short lb = (unsigned short)(__float_as_uint(lf) >> 16);
                a_h[f][j] = (short)hb;
                a_l[f][j] = (short)lb;
            }
        }
        #pragma unroll
        for (int f = 0; f < BF; ++f) {
            size_t off = (((size_t)ct64 * KS + ks) * 4 + f) * 64 + lane;
            b_h[f] = B8h[off]; b_l[f] = B8l[off];
        }
        #pragma unroll
        for (int i = 0; i < AF; ++i)
            #pragma unroll
            for (int j = 0; j < BF; ++j) {
                acc[i][j] = __builtin_amdgcn_mfma_f32_16x16x32_bf16(a_l[i], b_h[j], acc[i][j], 0, 0, 0);
                acc[i][j] = __builtin_amdgcn_mfma_f32_16x16x32_bf16(a_h[i], b_l[j], acc[i][j], 0, 0, 0);
                acc[i][j] = __builtin_amdgcn_mfma_f32_16x16x32_bf16(a_h[i], b_h[j], acc[i][j], 0, 0, 0);
            }
    }

    int H = M >> 6;
    int head = ct64;                 // wave col span 64 == one head
    int col0 = ct64 * 64;
    int cl = lane & 15, rgrp = lane >> 4;

    float as_[BF], ad_[BF];
    #pragma unroll
    for (int j = 0; j < BF; ++j) {
        as_[j] = a_src[col0 + j * 16 + cl];
        ad_[j] = a_dst[col0 + j * 16 + cl];
    }

    #pragma unroll
    for (int i = 0; i < AF; ++i) {
        int rowb = rt * 128 + wr * (AF * 16) + i * 16 + rgrp * 4;
        #pragma unroll
        for (int r = 0; r < 4; ++r) {
            float sv = acc[i][0][r] * as_[0] + acc[i][1][r] * as_[1]
                     + acc[i][2][r] * as_[2] + acc[i][3][r] * as_[3];
            float dv = acc[i][0][r] * ad_[0] + acc[i][1][r] * ad_[1]
                     + acc[i][2][r] * ad_[2] + acc[i][3][r] * ad_[3];
            #pragma unroll
            for (int o = 1; o < 16; o <<= 1) {
                sv += __shfl_xor(sv, o);
                dv += __shfl_xor(dv, o);
            }
            int row = rowb + r;
            if (row < Nrows) {
                unsigned short* cp = &C[(size_t)row * M + col0 + cl];
                cp[0]  = f2bf(acc[i][0][r]);
                cp[16] = f2bf(acc[i][1][r]);
                cp[32] = f2bf(acc[i][2][r]);
                cp[48] = f2bf(acc[i][3][r]);
                if (cl == 0) {
                    al_s[(size_t)row * H + head] = sv;
                    al_d[(size_t)row * H + head] = dv;
                }
            }
        }
    }
}

// ---------------- fused softmax + aggregate (wave per destination node) ----------------
// hlin is bf16 (values); al_s/al_d are f32 (coefficients) -> weights ~exact.
template <int H, bool ACT, bool POOL>    // TOT = H*64
__global__ __launch_bounds__(256) void k_agg(const unsigned short* __restrict__ hlin,
                      const float* __restrict__ al_s,
                      const float* __restrict__ al_d, const int* __restrict__ indptr,
                      const int* __restrict__ csr_src, const float* __restrict__ bias,
                      float* __restrict__ outf, const int* __restrict__ batch,
                      int* __restrict__ gcnt, int Nn) {
    constexpr int TOT = H * 64;
    constexpr int VEC = TOT / 64;
    constexpr int CAP = 128;
    __shared__ float sp[4][CAP * H];
    __shared__ int   si[4][CAP];
    int w = threadIdx.x >> 6;
    int lane = threadIdx.x & 63;
    int node = (blockIdx.x * blockDim.x + threadIdx.x) >> 6;
    if (node >= Nn) return;
    int d = node;
    int p0 = indptr[d], p1 = indptr[d + 1];
    int deg = p1 - p0;
    int head = (lane * VEC) >> 6;       // H=4: lane>>4 ; H=1: 0

    float ad[H], e_self[H];
    if constexpr (H == 4) {
        float4 adv = *reinterpret_cast<const float4*>(&al_d[(size_t)d * 4]);
        float4 asv = *reinterpret_cast<const float4*>(&al_s[(size_t)d * 4]);
        ad[0] = adv.x; ad[1] = adv.y; ad[2] = adv.z; ad[3] = adv.w;
        e_self[0] = lrelu(asv.x + ad[0]); e_self[1] = lrelu(asv.y + ad[1]);
        e_self[2] = lrelu(asv.z + ad[2]); e_self[3] = lrelu(asv.w + ad[3]);
    } else {
        ad[0] = al_d[d];
        e_self[0] = lrelu(al_s[d] + ad[0]);
    }

    float mh, invden, alpha_self;

    if (deg <= CAP) {
        int nb = (deg + 63) >> 6;
        float m[H];
        #pragma unroll
        for (int h = 0; h < H; ++h) m[h] = e_self[h];
        for (int b = 0; b < nb; ++b) {
            int l = b * 64 + lane;
            float e_h[H];
            if (l < deg) {
                int s = csr_src[p0 + l];
                si[w][l] = s;
                if constexpr (H == 4) {
                    float4 sv = *reinterpret_cast<const float4*>(&al_s[(size_t)s * 4]);
                    e_h[0] = lrelu(sv.x + ad[0]); e_h[1] = lrelu(sv.y + ad[1]);
                    e_h[2] = lrelu(sv.z + ad[2]); e_h[3] = lrelu(sv.w + ad[3]);
                } else {
                    e_h[0] = lrelu(al_s[s] + ad[0]);
                }
            } else {
                #pragma unroll
                for (int h = 0; h < H; ++h) e_h[h] = -1e30f;
            }
            #pragma unroll
            for (int h = 0; h < H; ++h) {
                sp[w][l * H + h] = e_h[h];
                m[h] = fmaxf(m[h], e_h[h]);
            }
        }
        #pragma unroll
        for (int h = 0; h < H; ++h)
            #pragma unroll
            for (int off = 1; off < 64; off <<= 1)
                m[h] = fmaxf(m[h], __shfl_xor(m[h], off));
        float den[H];
        #pragma unroll
        for (int h = 0; h < H; ++h) den[h] = 0.f;
        for (int b = 0; b < nb; ++b) {
            int l = b * 64 + lane;
            #pragma unroll
            for (int h = 0; h < H; ++h) {
                float pv = __expf(sp[w][l * H + h] - m[h]);
                sp[w][l * H + h] = pv;
                den[h] += pv;
            }
        }
        #pragma unroll
        for (int h = 0; h < H; ++h) {
            #pragma unroll
            for (int off = 1; off < 64; off <<= 1)
                den[h] += __shfl_xor(den[h], off);
            den[h] += __expf(e_self[h] - m[h]);
        }
        mh = m[head];
        invden = 1.f / den[head];
        alpha_self = __expf(e_self[head] - mh) * invden;

        float4 accv = make_float4(0.f, 0.f, 0.f, 0.f);
        {
            const unsigned short* hp = hlin + (size_t)d * TOT + lane * VEC;
            if constexpr (VEC == 4) {
                ushort4 hv = *reinterpret_cast<const ushort4*>(hp);
                accv.x = alpha_self * bf2f(hv.x); accv.y = alpha_self * bf2f(hv.y);
                accv.z = alpha_self * bf2f(hv.z); accv.w = alpha_self * bf2f(hv.w);
            } else {
                accv.x = alpha_self * bf2f(hp[0]);
            }
        }
        int e = 0;
        for (; e + 8 <= deg; e += 8) {
            int s0 = si[w][e + 0], s1 = si[w][e + 1], s2 = si[w][e + 2], s3 = si[w][e + 3];
            int s4 = si[w][e + 4], s5 = si[w][e + 5], s6 = si[w][e + 6], s7 = si[w][e + 7];
            float a0 = sp[w][(e + 0) * H + head] * invden;
            float a1 = sp[w][(e + 1) * H + head] * invden;
            float a2 = sp[w][(e + 2) * H + head] * invden;
            float a3 = sp[w][(e + 3) * H + head] * invden;
            float a4 = sp[w][(e + 4) * H + head] * invden;
            float a5 = sp[w][(e + 5) * H + head] * invden;
            float a6 = sp[w][(e + 6) * H + head] * invden;
            float a7 = sp[w][(e + 7) * H + head] * invden;
            if constexpr (VEC == 4) {
                ushort4 r0 = *reinterpret_cast<const ushort4*>(hlin + (size_t)s0 * TOT + lane * 4);
                ushort4 r1 = *reinterpret_cast<const ushort4*>(hlin + (size_t)s1 * TOT + lane * 4);
                ushort4 r2 = *reinterpret_cast<const ushort4*>(hlin + (size_t)s2 * TOT + lane * 4);
                ushort4 r3 = *reinterpret_cast<const ushort4*>(hlin + (size_t)s3 * TOT + lane * 4);
                ushort4 r4 = *reinterpret_cast<const ushort4*>(hlin + (size_t)s4 * TOT + lane * 4);
                ushort4 r5 = *reinterpret_cast<const ushort4*>(hlin + (size_t)s5 * TOT + lane * 4);
                ushort4 r6 = *reinterpret_cast<const ushort4*>(hlin + (size_t)s6 * TOT + lane * 4);
                ushort4 r7 = *reinterpret_cast<const ushort4*>(hlin + (size_t)s7 * TOT + lane * 4);
                accv.x += a0*bf2f(r0.x) + a1*bf2f(r1.x) + a2*bf2f(r2.x) + a3*bf2f(r3.x)
                        + a4*bf2f(r4.x) + a5*bf2f(r5.x) + a6*bf2f(r6.x) + a7*bf2f(r7.x);
                accv.y += a0*bf2f(r0.y) + a1*bf2f(r1.y) + a2*bf2f(r2.y) + a3*bf2f(r3.y)
                        + a4*bf2f(r4.y) + a5*bf2f(r5.y) + a6*bf2f(r6.y) + a7*bf2f(r7.y);
                accv.z += a0*bf2f(r0.z) + a1*bf2f(r1.z) + a2*bf2f(r2.z) + a3*bf2f(r3.z)
                        + a4*bf2f(r4.z) + a5*bf2f(r5.z) + a6*bf2f(r6.z) + a7*bf2f(r7.z);
                accv.w += a0*bf2f(r0.w) + a1*bf2f(r1.w) + a2*bf2f(r2.w) + a3*bf2f(r3.w)
                        + a4*bf2f(r4.w) + a5*bf2f(r5.w) + a6*bf2f(r6.w) + a7*bf2f(r7.w);
            } else {
                float r0 = bf2f(hlin[(size_t)s0 * TOT + lane]);
                float r1 = bf2f(hlin[(size_t)s1 * TOT + lane]);
                float r2 = bf2f(hlin[(size_t)s2 * TOT + lane]);
                float r3 = bf2f(hlin[(size_t)s3 * TOT + lane]);
                float r4 = bf2f(hlin[(size_t)s4 * TOT + lane]);
                float r5 = bf2f(hlin[(size_t)s5 * TOT + lane]);
                float r6 = bf2f(hlin[(size_t)s6 * TOT + lane]);
                float r7 = bf2f(hlin[(size_t)s7 * TOT + lane]);
                accv.x += a0*r0 + a1*r1 + a2*r2 + a3*r3 + a4*r4 + a5*r5 + a6*r6 + a7*r7;
            }
        }
        for (; e + 4 <= deg; e += 4) {
            int s0 = si[w][e + 0], s1 = si[w][e + 1];
            int s2 = si[w][e + 2], s3 = si[w][e + 3];
            float a0 = sp[w][(e + 0) * H + head] * invden;
            float a1 = sp[w][(e + 1) * H + head] * invden;
            float a2 = sp[w][(e + 2) * H + head] * invden;
            float a3 = sp[w][(e + 3) * H + head] * invden;
            if constexpr (VEC == 4) {
                ushort4 r0 = *reinterpret_cast<const ushort4*>(hlin + (size_t)s0 * TOT + lane * 4);
                ushort4 r1 = *reinterpret_cast<const ushort4*>(hlin + (size_t)s1 * TOT + lane * 4);
                ushort4 r2 = *reinterpret_cast<const ushort4*>(hlin + (size_t)s2 * TOT + lane * 4);
                ushort4 r3 = *reinterpret_cast<const ushort4*>(hlin + (size_t)s3 * TOT + lane * 4);
                accv.x += a0*bf2f(r0.x) + a1*bf2f(r1.x) + a2*bf2f(r2.x) + a3*bf2f(r3.x);
                accv.y += a0*bf2f(r0.y) + a1*bf2f(r1.y) + a2*bf2f(r2.y) + a3*bf2f(r3.y);
                accv.z += a0*bf2f(r0.z) + a1*bf2f(r1.z) + a2*bf2f(r2.z) + a3*bf2f(r3.z);
                accv.w += a0*bf2f(r0.w) + a1*bf2f(r1.w) + a2*bf2f(r2.w) + a3*bf2f(r3.w);
            } else {
                float r0 = bf2f(hlin[(size_t)s0 * TOT + lane]);
                float r1 = bf2f(hlin[(size_t)s1 * TOT + lane]);
                float r2 = bf2f(hlin[(size_t)s2 * TOT + lane]);
                float r3 = bf2f(hlin[(size_t)s3 * TOT + lane]);
                accv.x += a0 * r0 + a1 * r1 + a2 * r2 + a3 * r3;
            }
        }
        for (; e < deg; ++e) {
            int s = si[w][e];
            float a = sp[w][e * H + head] * invden;
            if constexpr (VEC == 4) {
                ushort4 rv = *reinterpret_cast<const ushort4*>(hlin + (size_t)s * TOT + lane * 4);
                accv.x += a * bf2f(rv.x); accv.y += a * bf2f(rv.y);
                accv.z += a * bf2f(rv.z); accv.w += a * bf2f(rv.w);
            } else {
                accv.x += a * bf2f(hlin[(size_t)s * TOT + lane]);
            }
        }
        if constexpr (VEC == 4) {
            int c0 = lane * 4;
            accv.x += bias[c0 + 0]; accv.y += bias[c0 + 1];
            accv.z += bias[c0 + 2]; accv.w += bias[c0 + 3];
            if (ACT) {
                accv.x = accv.x > 0.f ? accv.x : expm1f(accv.x);
                accv.y = accv.y > 0.f ? accv.y : expm1f(accv.y);
                accv.z = accv.z > 0.f ? accv.z : expm1f(accv.z);
                accv.w = accv.w > 0.f ? accv.w : expm1f(accv.w);
            }
            *reinterpret_cast<float4*>(&outf[(size_t)d * TOT + lane * 4]) = accv;
        } else {
            float o = accv.x + bias[lane];
            if (ACT) o = o > 0.f ? o : expm1f(o);
            if constexpr (POOL) {
                int g = batch[d];
                atomicAdd(&outf[(size_t)g * 64 + lane], o);
                if (lane == 0) atomicAdd(&gcnt[g], 1);
            } else {
                outf[(size_t)d * TOT + lane] = o;
            }
        }
        return;
    }

    // ---- fallback: deg > CAP, serial 3-pass (no LDS) ----
    {
        float adh = ad[head];
        float es = e_self[head];
        float m = es;
        for (int e = p0; e < p1; ++e) {
            int s = csr_src[e];
            m = fmaxf(m, lrelu(al_s[(size_t)s * H + head] + adh));
        }
        float den = __expf(es - m);
        for (int e = p0; e < p1; ++e) {
            int s = csr_src[e];
            den += __expf(lrelu(al_s[(size_t)s * H + head] + adh) - m);
        }
        den = 1.f / den;
        float accv[VEC] = {};
        {
            float alpha = __expf(es - m) * den;
            const unsigned short* hp = hlin + (size_t)d * TOT + lane * VEC;
            #pragma unroll
            for (int v = 0; v < VEC; ++v) accv[v] = alpha * bf2f(hp[v]);
        }
        for (int e = p0; e < p1; ++e) {
            int s = csr_src[e];
            float alpha = __expf(lrelu(al_s[(size_t)s * H + head] + adh) - m) * den;
            const unsigned short* hp = hlin + (size_t)s * TOT + lane * VEC;
            #pragma unroll
            for (int v = 0; v < VEC; ++v) accv[v] += alpha * bf2f(hp[v]);
        }
        #pragma unroll
        for (int v = 0; v < VEC; ++v) {
            int c = lane * VEC + v;
            float o = accv[v] + bias[c];
            if (ACT) o = o > 0.f ? o : expm1f(o);
            accv[v] = o;
        }
        if constexpr (POOL) {
            int g = batch[d];
            atomicAdd(&outf[(size_t)g * 64 + lane], accv[0]);
            if (lane == 0) atomicAdd(&gcnt[g], 1);
        } else {
            #pragma unroll
            for (int v = 0; v < VEC; ++v)
                outf[(size_t)d * TOT + lane * VEC + v] = accv[v];
        }
    }
}

// ---------------- final linear ----------------
__global__ void k_final(const float* __restrict__ gsum, const int* __restrict__ gcnt,
                        const float* __restrict__ lin_w, const float* __restrict__ lin_b,
                        float* __restrict__ out, int Gn) {
    int g = (blockIdx.x * blockDim.x + threadIdx.x) >> 6;
    int lane = threadIdx.x & 63;
    if (g >= Gn) return;
    float cnt = (float)gcnt[g];
    float inv = 1.f / fmaxf(cnt, 1.f);
    float v = gsum[(size_t)g * 64 + lane] * inv * lin_w[lane];
    #pragma unroll
    for (int off = 32; off >= 1; off >>= 1) v += __shfl_xor(v, off);
    if (lane == 0) out[g] = v + lin_b[0];
}

extern "C" void kernel_launch(void* const* d_in, const int* in_sizes, int n_in,
                              void* d_out, int out_size, void* d_ws, size_t ws_size,
                              hipStream_t stream) {
    const float* x    = (const float*)d_in[0];
    const int*   ei   = (const int*)d_in[1];
    const int*   batch= (const int*)d_in[2];
    const float* W1   = (const float*)d_in[3];
    const float* a1s  = (const float*)d_in[4];
    const float* a1d  = (const float*)d_in[5];
    const float* b1   = (const float*)d_in[6];
    const float* W2   = (const float*)d_in[7];
    const float* a2s  = (const float*)d_in[8];
    const float* a2d  = (const float*)d_in[9];
    const float* b2   = (const float*)d_in[10];
    const float* W3   = (const float*)d_in[11];
    const float* a3s  = (const float*)d_in[12];
    const float* a3d  = (const float*)d_in[13];
    const float* b3   = (const float*)d_in[14];
    const float* lw   = (const float*)d_in[15];
    const float* lb   = (const float*)d_in[16];

    int N = in_sizes[0] / 128;
    int E = in_sizes[1] / 2;
    int G = out_size;
    int RT = (N + 127) >> 7;
    int Np = RT * 128;
    int NB = (N + 1023) >> 10;   // scan blocks (<=256 supported)

    char* p = (char*)d_ws;
    auto alloc = [&](size_t bytes) {
        char* r = p;
        p += (bytes + 255) & ~(size_t)255;
        return r;
    };
    unsigned short* hbuf = (unsigned short*)alloc((size_t)Np * 256 * 2);  // bf16 GEMM output
    float* aggbuf = (float*)alloc((size_t)Np * 256 * 4);                  // f32 agg output
    unsigned short* pB1h = (unsigned short*)alloc((size_t)128 * 256 * 2);
    unsigned short* pB1l = (unsigned short*)alloc((size_t)128 * 256 * 2);
    unsigned short* pB2h = (unsigned short*)alloc((size_t)256 * 256 * 2);
    unsigned short* pB2l = (unsigned short*)alloc((size_t)256 * 256 * 2);
    unsigned short* pB3h = (unsigned short*)alloc((size_t)256 * 64 * 2);
    unsigned short* pB3l = (unsigned short*)alloc((size_t)256 * 64 * 2);
    float* al_s  = (float*)alloc((size_t)N * 4 * 4);
    float* al_d  = (float*)alloc((size_t)N * 4 * 4);
    int* indptr  = (int*)alloc((size_t)(N + 1) * 4);
    int* counts  = (int*)alloc((size_t)N * 4);
    int* cursor  = (int*)alloc((size_t)N * 4);
    int* lex     = (int*)alloc((size_t)N * 4);
    int* bsums   = (int*)alloc((size_t)256 * 4);
    int* csr     = (int*)alloc((size_t)E * 4);
    float* gsum  = (float*)alloc((size_t)G * 64 * 4);
    int* gcnt    = (int*)alloc((size_t)G * 4);
    if ((size_t)(p - (char*)d_ws) > ws_size) return;  // workspace too small

    hipMemsetAsync(counts, 0, (size_t)N * 4, stream);
    hipMemsetAsync(gsum, 0, (size_t)G * 64 * 4, stream);
    hipMemsetAsync(gcnt, 0, (size_t)G * 4, stream);

    // pack all weight matrices upfront (tiny)
    k_packB<<<(256 * (128 >> 3) + 255) / 256, 256, 0, stream>>>(W1, pB1h, pB1l, 128, 256);
    k_packB<<<(256 * (256 >> 3) + 255) / 256, 256, 0, stream>>>(W2, pB2h, pB2l, 256, 256);
    k_packB<<<(64 * (256 >> 3) + 255) / 256, 256, 0, stream>>>(W3, pB3h, pB3l, 256, 64);

    int eb = (E + 255) / 256;
    k_count<<<eb, 256, 0, stream>>>(ei, E, counts);
    k_scan_local<<<NB, 256, 0, stream>>>(counts, lex, bsums, N);
    k_scan_bsums<<<1, 256, 0, stream>>>(bsums, NB);
    k_scan_add<<<(N + 1 + 255) / 256, 256, 0, stream>>>(lex, bsums, indptr, cursor, N, E);
    k_scatter<<<eb, 256, 0, stream>>>(ei, E, cursor, csr);

    int wb = (N * 64 + 255) / 256;   // one wave per node

    // layer 1: 128 -> 256 (H=4, concat, ELU)
    k_mm<4, 2, 2><<<dim3(RT, 2), 256, 0, stream>>>(x, pB1h, pB1l, hbuf,
                                                   a1s, a1d, al_s, al_d, N, 128, 256);
    k_agg<4, true, false><<<wb, 256, 0, stream>>>(hbuf, al_s, al_d, indptr, csr, b1, aggbuf,
                                                  nullptr, nullptr, N);

    // layer 2: 256 -> 256 (H=4, concat, ELU)
    k_mm<4, 2, 2><<<dim3(RT, 2), 256, 0, stream>>>(aggbuf, pB2h, pB2l, hbuf,
                                                   a2s, a2d, al_s, al_d, N, 256, 256);
    k_agg<4, true, false><<<wb, 256, 0, stream>>>(hbuf, al_s, al_d, indptr, csr, b2, aggbuf,
                                                  nullptr, nullptr, N);

    // layer 3: 256 -> 64 (H=1, no concat, no act) + fused mean-pool accumulate
    k_mm<2, 4, 1><<<dim3(RT, 1), 256, 0, stream>>>(aggbuf, pB3h, pB3l, hbuf,
                                                   a3s, a3d, al_s, al_d, N, 256, 64);
    k_agg<1, false, true><<<wb, 256, 0, stream>>>(hbuf, al_s, al_d, indptr, csr, b3, gsum,
                                                  batch, gcnt, N);

    int fb = (G * 64 + 255) / 256;
    k_final<<<fb, 256, 0, stream>>>(gsum, gcnt, lw, lb, (float*)d_out, G);
}

// Round 7
// 421.443 us; speedup vs baseline: 2.4980x; 1.0030x over previous
//
#include <hip/hip_runtime.h>
#include <cstdint>
#include <cstddef>

#define NEG_SLOPE 0.2f

typedef __attribute__((ext_vector_type(8))) short short8;
typedef __attribute__((ext_vector_type(4))) float f32x4;

__device__ __forceinline__ float lrelu(float v) { return v > 0.f ? v : NEG_SLOPE * v; }

__device__ __forceinline__ unsigned short f2bf(float x) {
    unsigned u = __float_as_uint(x);
    u = (u + 0x7FFFu + ((u >> 16) & 1u)) >> 16;
    return (unsigned short)u;
}
__device__ __forceinline__ float bf2f(unsigned short h) {
    return __uint_as_float(((unsigned)h) << 16);
}

// trunc split: hi = top 16 bits, lo = bf16_trunc(x - hi). Must stay identical
// everywhere it is used (k_mm CONV path and k_agg split-store).
__device__ __forceinline__ void splitbf(float v, unsigned short& hb, unsigned short& lb) {
    unsigned u = __float_as_uint(v);
    hb = (unsigned short)(u >> 16);
    float hf = __uint_as_float(u & 0xFFFF0000u);
    float lf = v - hf;
    lb = (unsigned short)(__float_as_uint(lf) >> 16);
}

// ---------------- CSR build ----------------
__global__ void k_count(const int* __restrict__ ei, int E, int* __restrict__ counts) {
    int i = blockIdx.x * blockDim.x + threadIdx.x;
    if (i < E) atomicAdd(&counts[ei[E + i]], 1);
}

// hierarchical scan, step 1: per-block (1024 elems) local exclusive scan + block sum
__global__ __launch_bounds__(256) void k_scan_local(const int* __restrict__ counts,
        int* __restrict__ local_ex, int* __restrict__ bsums, int Nn) {
    int base = blockIdx.x * 1024;
    int tid = threadIdx.x;
    int idx = base + tid * 4;
    int4 v = make_int4(0, 0, 0, 0);
    if (idx + 3 < Nn) {
        v = *reinterpret_cast<const int4*>(&counts[idx]);
    } else {
        if (idx + 0 < Nn) v.x = counts[idx + 0];
        if (idx + 1 < Nn) v.y = counts[idx + 1];
        if (idx + 2 < Nn) v.z = counts[idx + 2];
        if (idx + 3 < Nn) v.w = counts[idx + 3];
    }
    int t = v.x + v.y + v.z + v.w;
    int lane = tid & 63, wave = tid >> 6;
    int s = t;
    #pragma unroll
    for (int off = 1; off < 64; off <<= 1) {
        int u = __shfl_up(s, off);
        if (lane >= off) s += u;
    }
    __shared__ int wsum[4];
    if (lane == 63) wsum[wave] = s;
    __syncthreads();
    int wo = 0;
    #pragma unroll
    for (int wv = 0; wv < 4; ++wv) wo += (wv < wave) ? wsum[wv] : 0;
    int ex = wo + s - t;
    int4 o;
    o.x = ex; o.y = ex + v.x; o.z = ex + v.x + v.y; o.w = ex + v.x + v.y + v.z;
    if (idx + 3 < Nn) {
        *reinterpret_cast<int4*>(&local_ex[idx]) = o;
    } else {
        if (idx + 0 < Nn) local_ex[idx + 0] = o.x;
        if (idx + 1 < Nn) local_ex[idx + 1] = o.y;
        if (idx + 2 < Nn) local_ex[idx + 2] = o.z;
        if (idx + 3 < Nn) local_ex[idx + 3] = o.w;
    }
    if (tid == 255) bsums[blockIdx.x] = wo + s;
}

// step 2: single block scans block sums in-place (exclusive). nb <= 256.
__global__ __launch_bounds__(256) void k_scan_bsums(int* __restrict__ bsums, int nb) {
    int tid = threadIdx.x;
    int v = (tid < nb) ? bsums[tid] : 0;
    int lane = tid & 63, wave = tid >> 6;
    int s = v;
    #pragma unroll
    for (int off = 1; off < 64; off <<= 1) {
        int u = __shfl_up(s, off);
        if (lane >= off) s += u;
    }
    __shared__ int wsum[4];
    if (lane == 63) wsum[wave] = s;
    __syncthreads();
    int wo = 0;
    #pragma unroll
    for (int wv = 0; wv < 4; ++wv) wo += (wv < wave) ? wsum[wv] : 0;
    if (tid < nb) bsums[tid] = wo + s - v;
}

// step 3: add block offsets; write indptr + cursor; indptr[Nn] = E.
__global__ __launch_bounds__(256) void k_scan_add(const int* __restrict__ local_ex,
        const int* __restrict__ bsums, int* __restrict__ indptr, int* __restrict__ cursor,
        int Nn, int Etot) {
    int i = blockIdx.x * 256 + threadIdx.x;
    if (i < Nn) {
        int val = local_ex[i] + bsums[i >> 10];
        indptr[i] = val;
        cursor[i] = val;
    } else if (i == Nn) {
        indptr[Nn] = Etot;
    }
}

__global__ void k_scatter(const int* __restrict__ ei, int E, int* __restrict__ cursor,
                          int* __restrict__ csr_src) {
    int i = blockIdx.x * blockDim.x + threadIdx.x;
    if (i < E) {
        int s = ei[i], d = ei[E + i];
        int pos = atomicAdd(&cursor[d], 1);
        csr_src[pos] = s;
    }
}

// ---------------- pack B (W f32 [K,M] -> fragment-packed bf16 hi/lo, RNE) ----------------
__global__ __launch_bounds__(256) void k_packB(const float* __restrict__ W,
        unsigned short* __restrict__ Ph, unsigned short* __restrict__ Pl, int K, int M) {
    int tid = blockIdx.x * 256 + threadIdx.x;
    int KS8 = K >> 3;
    int total = M * KS8;
    if (tid >= total) return;
    int col = tid / KS8;
    int k = (tid - col * KS8) << 3;
    short8 hv, lv;
    #pragma unroll
    for (int j = 0; j < 8; ++j) {
        float x = W[(size_t)(k + j) * M + col];
        unsigned short hb = f2bf(x);
        hv[j] = (short)hb;
        lv[j] = (short)f2bf(x - bf2f(hb));
    }
    int ct64 = col >> 6, c = col & 63;
    int fb = c >> 4, cl = c & 15;
    int ks = k >> 5, kg = (k >> 3) & 3;
    int lane = cl | (kg << 4);
    size_t off = (((size_t)ct64 * (K >> 5) + ks) * 4 + fb) * 64 + lane;
    *reinterpret_cast<short8*>(Ph + off * 8) = hv;
    *reinterpret_cast<short8*>(Pl + off * 8) = lv;
}

// ---------------- split-bf16 MFMA GEMM ----------------
// block = 256 threads = 4 waves (WR x WC); wave tile = AF*16 rows x 64 cols (BF=4)
// CONV=true : A is row-major f32, trunc-split in kernel.
// CONV=false: A pre-split row-major bf16 planes (Aph/Apl) — zero conversion.
// acc = Al*Bh + Ah*Bl + Ah*Bh ; attention dots from f32 acc.
template<int AF, int WR, int WC, bool CONV>
__global__ __launch_bounds__(256) void k_mm(const float* __restrict__ A,
        const unsigned short* __restrict__ Aph, const unsigned short* __restrict__ Apl,
        const unsigned short* __restrict__ Bh, const unsigned short* __restrict__ Bl,
        unsigned short* __restrict__ C, const float* __restrict__ a_src, const float* __restrict__ a_dst,
        float* __restrict__ al_s, float* __restrict__ al_d, int Nrows, int K, int M) {
    constexpr int BF = 4;
    constexpr int BR = WR * AF * 16;   // block rows
    int wave = threadIdx.x >> 6, lane = threadIdx.x & 63;
    int wr = wave / WC, wc = wave % WC;
    int rt = blockIdx.x;
    int ct64 = blockIdx.y * WC + wc;
    int KS = K >> 5;
    int rl = lane & 15, kg = lane >> 4;
    const short8* B8h = reinterpret_cast<const short8*>(Bh);
    const short8* B8l = reinterpret_cast<const short8*>(Bl);

    const float* aptr[AF];
    const unsigned short *ahp[AF], *alp[AF];
    #pragma unroll
    for (int f = 0; f < AF; ++f) {
        int row = rt * BR + wr * (AF * 16) + f * 16 + rl;
        if (row > Nrows - 1) row = Nrows - 1;   // clamp: junk rows discarded at store
        if constexpr (CONV) {
            aptr[f] = A + (size_t)row * K + kg * 8;
        } else {
            ahp[f] = Aph + (size_t)row * K + kg * 8;
            alp[f] = Apl + (size_t)row * K + kg * 8;
        }
    }

    f32x4 acc[AF][BF];
    #pragma unroll
    for (int i = 0; i < AF; ++i)
        #pragma unroll
        for (int j = 0; j < BF; ++j)
            acc[i][j] = (f32x4){0.f, 0.f, 0.f, 0.f};

    for (int ks = 0; ks < KS; ++ks) {
        short8 a_h[AF], a_l[AF], b_h[BF], b_l[BF];
        #pragma unroll
        for (int f = 0; f < AF; ++f) {
            if constexpr (CONV) {
                const float* ap = aptr[f] + ks * 32;
                float4 v0 = *reinterpret_cast<const float4*>(ap);
                float4 v1 = *reinterpret_cast<const float4*>(ap + 4);
                float vv[8] = {v0.x, v0.y, v0.z, v0.w, v1.x, v1.y, v1.z, v1.w};
                #pragma unroll
                for (int j = 0; j < 8; ++j) {
                    unsigned short hb, lb;
                    splitbf(vv[j], hb, lb);
                    a_h[f][j] = (short)hb;
                    a_l[f][j] = (short)lb;
                }
            } else {
                a_h[f] = *reinterpret_cast<const short8*>(ahp[f] + ks * 32);
                a_l[f] = *reinterpret_cast<const short8*>(alp[f] + ks * 32);
            }
        }
        #pragma unroll
        for (int f = 0; f < BF; ++f) {
            size_t off = (((size_t)ct64 * KS + ks) * 4 + f) * 64 + lane;
            b_h[f] = B8h[off]; b_l[f] = B8l[off];
        }
        #pragma unroll
        for (int i = 0; i < AF; ++i)
            #pragma unroll
            for (int j = 0; j < BF; ++j) {
                acc[i][j] = __builtin_amdgcn_mfma_f32_16x16x32_bf16(a_l[i], b_h[j], acc[i][j], 0, 0, 0);
                acc[i][j] = __builtin_amdgcn_mfma_f32_16x16x32_bf16(a_h[i], b_l[j], acc[i][j], 0, 0, 0);
                acc[i][j] = __builtin_amdgcn_mfma_f32_16x16x32_bf16(a_h[i], b_h[j], acc[i][j], 0, 0, 0);
            }
    }

    int H = M >> 6;
    int head = ct64;                 // wave col span 64 == one head
    int col0 = ct64 * 64;
    int cl = lane & 15, rgrp = lane >> 4;

    float as_[BF], ad_[BF];
    #pragma unroll
    for (int j = 0; j < BF; ++j) {
        as_[j] = a_src[col0 + j * 16 + cl];
        ad_[j] = a_dst[col0 + j * 16 + cl];
    }

    #pragma unroll
    for (int i = 0; i < AF; ++i) {
        int rowb = rt * BR + wr * (AF * 16) + i * 16 + rgrp * 4;
        #pragma unroll
        for (int r = 0; r < 4; ++r) {
            float sv = acc[i][0][r] * as_[0] + acc[i][1][r] * as_[1]
                     + acc[i][2][r] * as_[2] + acc[i][3][r] * as_[3];
            float dv = acc[i][0][r] * ad_[0] + acc[i][1][r] * ad_[1]
                     + acc[i][2][r] * ad_[2] + acc[i][3][r] * ad_[3];
            #pragma unroll
            for (int o = 1; o < 16; o <<= 1) {
                sv += __shfl_xor(sv, o);
                dv += __shfl_xor(dv, o);
            }
            int row = rowb + r;
            if (row < Nrows) {
                unsigned short* cp = &C[(size_t)row * M + col0 + cl];
                cp[0]  = f2bf(acc[i][0][r]);
                cp[16] = f2bf(acc[i][1][r]);
                cp[32] = f2bf(acc[i][2][r]);
                cp[48] = f2bf(acc[i][3][r]);
                if (cl == 0) {
                    al_s[(size_t)row * H + head] = sv;
                    al_d[(size_t)row * H + head] = dv;
                }
            }
        }
    }
}

// ---------------- fused softmax + aggregate (wave per destination node) ----------------
// hlin bf16 values (gather); al_s/al_d f32 coefficients.
// Non-POOL output: pre-split hi/lo bf16 planes (identical bits to k_mm's CONV split).
template <int H, bool ACT, bool POOL>    // TOT = H*64
__global__ __launch_bounds__(256) void k_agg(const unsigned short* __restrict__ hlin,
                      const float* __restrict__ al_s,
                      const float* __restrict__ al_d, const int* __restrict__ indptr,
                      const int* __restrict__ csr_src, const float* __restrict__ bias,
                      unsigned short* __restrict__ out_hi, unsigned short* __restrict__ out_lo,
                      float* __restrict__ outf, const int* __restrict__ batch,
                      int* __restrict__ gcnt, int Nn) {
    constexpr int TOT = H * 64;
    constexpr int VEC = TOT / 64;
    constexpr int CAP = 128;
    __shared__ float sp[4][CAP * H];
    __shared__ int   si[4][CAP];
    int w = threadIdx.x >> 6;
    int lane = threadIdx.x & 63;
    int node = (blockIdx.x * blockDim.x + threadIdx.x) >> 6;
    if (node >= Nn) return;
    int d = node;
    int p0 = indptr[d], p1 = indptr[d + 1];
    int deg = p1 - p0;
    int head = (lane * VEC) >> 6;       // H=4: lane>>4 ; H=1: 0

    float ad[H], e_self[H];
    if constexpr (H == 4) {
        float4 adv = *reinterpret_cast<const float4*>(&al_d[(size_t)d * 4]);
        float4 asv = *reinterpret_cast<const float4*>(&al_s[(size_t)d * 4]);
        ad[0] = adv.x; ad[1] = adv.y; ad[2] = adv.z; ad[3] = adv.w;
        e_self[0] = lrelu(asv.x + ad[0]); e_self[1] = lrelu(asv.y + ad[1]);
        e_self[2] = lrelu(asv.z + ad[2]); e_self[3] = lrelu(asv.w + ad[3]);
    } else {
        ad[0] = al_d[d];
        e_self[0] = lrelu(al_s[d] + ad[0]);
    }

    float mh, invden, alpha_self;

    if (deg <= CAP) {
        int nb = (deg + 63) >> 6;
        float m[H];
        #pragma unroll
        for (int h = 0; h < H; ++h) m[h] = e_self[h];
        for (int b = 0; b < nb; ++b) {
            int l = b * 64 + lane;
            float e_h[H];
            if (l < deg) {
                int s = csr_src[p0 + l];
                si[w][l] = s;
                if constexpr (H == 4) {
                    float4 sv = *reinterpret_cast<const float4*>(&al_s[(size_t)s * 4]);
                    e_h[0] = lrelu(sv.x + ad[0]); e_h[1] = lrelu(sv.y + ad[1]);
                    e_h[2] = lrelu(sv.z + ad[2]); e_h[3] = lrelu(sv.w + ad[3]);
                } else {
                    e_h[0] = lrelu(al_s[s] + ad[0]);
                }
            } else {
                #pragma unroll
                for (int h = 0; h < H; ++h) e_h[h] = -1e30f;
            }
            #pragma unroll
            for (int h = 0; h < H; ++h) {
                sp[w][l * H + h] = e_h[h];
                m[h] = fmaxf(m[h], e_h[h]);
            }
        }
        #pragma unroll
        for (int h = 0; h < H; ++h)
            #pragma unroll
            for (int off = 1; off < 64; off <<= 1)
                m[h] = fmaxf(m[h], __shfl_xor(m[h], off));
        float den[H];
        #pragma unroll
        for (int h = 0; h < H; ++h) den[h] = 0.f;
        for (int b = 0; b < nb; ++b) {
            int l = b * 64 + lane;
            #pragma unroll
            for (int h = 0; h < H; ++h) {
                float pv = __expf(sp[w][l * H + h] - m[h]);
                sp[w][l * H + h] = pv;
                den[h] += pv;
            }
        }
        #pragma unroll
        for (int h = 0; h < H; ++h) {
            #pragma unroll
            for (int off = 1; off < 64; off <<= 1)
                den[h] += __shfl_xor(den[h], off);
            den[h] += __expf(e_self[h] - m[h]);
        }
        mh = m[head];
        invden = 1.f / den[head];
        alpha_self = __expf(e_self[head] - mh) * invden;

        float4 accv = make_float4(0.f, 0.f, 0.f, 0.f);
        {
            const unsigned short* hp = hlin + (size_t)d * TOT + lane * VEC;
            if constexpr (VEC == 4) {
                ushort4 hv = *reinterpret_cast<const ushort4*>(hp);
                accv.x = alpha_self * bf2f(hv.x); accv.y = alpha_self * bf2f(hv.y);
                accv.z = alpha_self * bf2f(hv.z); accv.w = alpha_self * bf2f(hv.w);
            } else {
                accv.x = alpha_self * bf2f(hp[0]);
            }
        }
        int e = 0;
        for (; e + 8 <= deg; e += 8) {
            int s0 = si[w][e + 0], s1 = si[w][e + 1], s2 = si[w][e + 2], s3 = si[w][e + 3];
            int s4 = si[w][e + 4], s5 = si[w][e + 5], s6 = si[w][e + 6], s7 = si[w][e + 7];
            float a0 = sp[w][(e + 0) * H + head] * invden;
            float a1 = sp[w][(e + 1) * H + head] * invden;
            float a2 = sp[w][(e + 2) * H + head] * invden;
            float a3 = sp[w][(e + 3) * H + head] * invden;
            float a4 = sp[w][(e + 4) * H + head] * invden;
            float a5 = sp[w][(e + 5) * H + head] * invden;
            float a6 = sp[w][(e + 6) * H + head] * invden;
            float a7 = sp[w][(e + 7) * H + head] * invden;
            if constexpr (VEC == 4) {
                ushort4 r0 = *reinterpret_cast<const ushort4*>(hlin + (size_t)s0 * TOT + lane * 4);
                ushort4 r1 = *reinterpret_cast<const ushort4*>(hlin + (size_t)s1 * TOT + lane * 4);
                ushort4 r2 = *reinterpret_cast<const ushort4*>(hlin + (size_t)s2 * TOT + lane * 4);
                ushort4 r3 = *reinterpret_cast<const ushort4*>(hlin + (size_t)s3 * TOT + lane * 4);
                ushort4 r4 = *reinterpret_cast<const ushort4*>(hlin + (size_t)s4 * TOT + lane * 4);
                ushort4 r5 = *reinterpret_cast<const ushort4*>(hlin + (size_t)s5 * TOT + lane * 4);
                ushort4 r6 = *reinterpret_cast<const ushort4*>(hlin + (size_t)s6 * TOT + lane * 4);
                ushort4 r7 = *reinterpret_cast<const ushort4*>(hlin + (size_t)s7 * TOT + lane * 4);
                accv.x += a0*bf2f(r0.x) + a1*bf2f(r1.x) + a2*bf2f(r2.x) + a3*bf2f(r3.x)
                        + a4*bf2f(r4.x) + a5*bf2f(r5.x) + a6*bf2f(r6.x) + a7*bf2f(r7.x);
                accv.y += a0*bf2f(r0.y) + a1*bf2f(r1.y) + a2*bf2f(r2.y) + a3*bf2f(r3.y)
                        + a4*bf2f(r4.y) + a5*bf2f(r5.y) + a6*bf2f(r6.y) + a7*bf2f(r7.y);
                accv.z += a0*bf2f(r0.z) + a1*bf2f(r1.z) + a2*bf2f(r2.z) + a3*bf2f(r3.z)
                        + a4*bf2f(r4.z) + a5*bf2f(r5.z) + a6*bf2f(r6.z) + a7*bf2f(r7.z);
                accv.w += a0*bf2f(r0.w) + a1*bf2f(r1.w) + a2*bf2f(r2.w) + a3*bf2f(r3.w)
                        + a4*bf2f(r4.w) + a5*bf2f(r5.w) + a6*bf2f(r6.w) + a7*bf2f(r7.w);
            } else {
                float r0 = bf2f(hlin[(size_t)s0 * TOT + lane]);
                float r1 = bf2f(hlin[(size_t)s1 * TOT + lane]);
                float r2 = bf2f(hlin[(size_t)s2 * TOT + lane]);
                float r3 = bf2f(hlin[(size_t)s3 * TOT + lane]);
                float r4 = bf2f(hlin[(size_t)s4 * TOT + lane]);
                float r5 = bf2f(hlin[(size_t)s5 * TOT + lane]);
                float r6 = bf2f(hlin[(size_t)s6 * TOT + lane]);
                float r7 = bf2f(hlin[(size_t)s7 * TOT + lane]);
                accv.x += a0*r0 + a1*r1 + a2*r2 + a3*r3 + a4*r4 + a5*r5 + a6*r6 + a7*r7;
            }
        }
        for (; e + 4 <= deg; e += 4) {
            int s0 = si[w][e + 0], s1 = si[w][e + 1];
            int s2 = si[w][e + 2], s3 = si[w][e + 3];
            float a0 = sp[w][(e + 0) * H + head] * invden;
            float a1 = sp[w][(e + 1) * H + head] * invden;
            float a2 = sp[w][(e + 2) * H + head] * invden;
            float a3 = sp[w][(e + 3) * H + head] * invden;
            if constexpr (VEC == 4) {
                ushort4 r0 = *reinterpret_cast<const ushort4*>(hlin + (size_t)s0 * TOT + lane * 4);
                ushort4 r1 = *reinterpret_cast<const ushort4*>(hlin + (size_t)s1 * TOT + lane * 4);
                ushort4 r2 = *reinterpret_cast<const ushort4*>(hlin + (size_t)s2 * TOT + lane * 4);
                ushort4 r3 = *reinterpret_cast<const ushort4*>(hlin + (size_t)s3 * TOT + lane * 4);
                accv.x += a0*bf2f(r0.x) + a1*bf2f(r1.x) + a2*bf2f(r2.x) + a3*bf2f(r3.x);
                accv.y += a0*bf2f(r0.y) + a1*bf2f(r1.y) + a2*bf2f(r2.y) + a3*bf2f(r3.y);
                accv.z += a0*bf2f(r0.z) + a1*bf2f(r1.z) + a2*bf2f(r2.z) + a3*bf2f(r3.z);
                accv.w += a0*bf2f(r0.w) + a1*bf2f(r1.w) + a2*bf2f(r2.w) + a3*bf2f(r3.w);
            } else {
                float r0 = bf2f(hlin[(size_t)s0 * TOT + lane]);
                float r1 = bf2f(hlin[(size_t)s1 * TOT + lane]);
                float r2 = bf2f(hlin[(size_t)s2 * TOT + lane]);
                float r3 = bf2f(hlin[(size_t)s3 * TOT + lane]);
                accv.x += a0 * r0 + a1 * r1 + a2 * r2 + a3 * r3;
            }
        }
        for (; e < deg; ++e) {
            int s = si[w][e];
            float a = sp[w][e * H + head] * invden;
            if constexpr (VEC == 4) {
                ushort4 rv = *reinterpret_cast<const ushort4*>(hlin + (size_t)s * TOT + lane * 4);
                accv.x += a * bf2f(rv.x); accv.y += a * bf2f(rv.y);
                accv.z += a * bf2f(rv.z); accv.w += a * bf2f(rv.w);
            } else {
                accv.x += a * bf2f(hlin[(size_t)s * TOT + lane]);
            }
        }
        if constexpr (VEC == 4) {
            int c0 = lane * 4;
            accv.x += bias[c0 + 0]; accv.y += bias[c0 + 1];
            accv.z += bias[c0 + 2]; accv.w += bias[c0 + 3];
            if (ACT) {
                accv.x = accv.x > 0.f ? accv.x : expm1f(accv.x);
                accv.y = accv.y > 0.f ? accv.y : expm1f(accv.y);
                accv.z = accv.z > 0.f ? accv.z : expm1f(accv.z);
                accv.w = accv.w > 0.f ? accv.w : expm1f(accv.w);
            }
            ushort4 hv, lv;
            splitbf(accv.x, hv.x, lv.x);
            splitbf(accv.y, hv.y, lv.y);
            splitbf(accv.z, hv.z, lv.z);
            splitbf(accv.w, hv.w, lv.w);
            *reinterpret_cast<ushort4*>(&out_hi[(size_t)d * TOT + c0]) = hv;
            *reinterpret_cast<ushort4*>(&out_lo[(size_t)d * TOT + c0]) = lv;
        } else {
            float o = accv.x + bias[lane];
            if (ACT) o = o > 0.f ? o : expm1f(o);
            if constexpr (POOL) {
                int g = batch[d];
                atomicAdd(&outf[(size_t)g * 64 + lane], o);
                if (lane == 0) atomicAdd(&gcnt[g], 1);
            } else {
                unsigned short hb, lb;
                splitbf(o, hb, lb);
                out_hi[(size_t)d * TOT + lane] = hb;
                out_lo[(size_t)d * TOT + lane] = lb;
            }
        }
        return;
    }

    // ---- fallback: deg > CAP, serial 3-pass (no LDS) ----
    {
        float adh = ad[head];
        float es = e_self[head];
        float m = es;
        for (int e = p0; e < p1; ++e) {
            int s = csr_src[e];
            m = fmaxf(m, lrelu(al_s[(size_t)s * H + head] + adh));
        }
        float den = __expf(es - m);
        for (int e = p0; e < p1; ++e) {
            int s = csr_src[e];
            den += __expf(lrelu(al_s[(size_t)s * H + head] + adh) - m);
        }
        den = 1.f / den;
        float accv[VEC] = {};
        {
            float alpha = __expf(es - m) * den;
            const unsigned short* hp = hlin + (size_t)d * TOT + lane * VEC;
            #pragma unroll
            for (int v = 0; v < VEC; ++v) accv[v] = alpha * bf2f(hp[v]);
        }
        for (int e = p0; e < p1; ++e) {
            int s = csr_src[e];
            float alpha = __expf(lrelu(al_s[(size_t)s * H + head] + adh) - m) * den;
            const unsigned short* hp = hlin + (size_t)s * TOT + lane * VEC;
            #pragma unroll
            for (int v = 0; v < VEC; ++v) accv[v] += alpha * bf2f(hp[v]);
        }
        #pragma unroll
        for (int v = 0; v < VEC; ++v) {
            int c = lane * VEC + v;
            float o = accv[v] + bias[c];
            if (ACT) o = o > 0.f ? o : expm1f(o);
            accv[v] = o;
        }
        if constexpr (POOL) {
            int g = batch[d];
            atomicAdd(&outf[(size_t)g * 64 + lane], accv[0]);
            if (lane == 0) atomicAdd(&gcnt[g], 1);
        } else {
            #pragma unroll
            for (int v = 0; v < VEC; ++v) {
                unsigned short hb, lb;
                splitbf(accv[v], hb, lb);
                out_hi[(size_t)d * TOT + lane * VEC + v] = hb;
                out_lo[(size_t)d * TOT + lane * VEC + v] = lb;
            }
        }
    }
}

// ---------------- final linear ----------------
__global__ void k_final(const float* __restrict__ gsum, const int* __restrict__ gcnt,
                        const float* __restrict__ lin_w, const float* __restrict__ lin_b,
                        float* __restrict__ out, int Gn) {
    int g = (blockIdx.x * blockDim.x + threadIdx.x) >> 6;
    int lane = threadIdx.x & 63;
    if (g >= Gn) return;
    float cnt = (float)gcnt[g];
    float inv = 1.f / fmaxf(cnt, 1.f);
    float v = gsum[(size_t)g * 64 + lane] * inv * lin_w[lane];
    #pragma unroll
    for (int off = 32; off >= 1; off >>= 1) v += __shfl_xor(v, off);
    if (lane == 0) out[g] = v + lin_b[0];
}

extern "C" void kernel_launch(void* const* d_in, const int* in_sizes, int n_in,
                              void* d_out, int out_size, void* d_ws, size_t ws_size,
                              hipStream_t stream) {
    const float* x    = (const float*)d_in[0];
    const int*   ei   = (const int*)d_in[1];
    const int*   batch= (const int*)d_in[2];
    const float* W1   = (const float*)d_in[3];
    const float* a1s  = (const float*)d_in[4];
    const float* a1d  = (const float*)d_in[5];
    const float* b1   = (const float*)d_in[6];
    const float* W2   = (const float*)d_in[7];
    const float* a2s  = (const float*)d_in[8];
    const float* a2d  = (const float*)d_in[9];
    const float* b2   = (const float*)d_in[10];
    const float* W3   = (const float*)d_in[11];
    const float* a3s  = (const float*)d_in[12];
    const float* a3d  = (const float*)d_in[13];
    const float* b3   = (const float*)d_in[14];
    const float* lw   = (const float*)d_in[15];
    const float* lb   = (const float*)d_in[16];

    int N = in_sizes[0] / 128;
    int E = in_sizes[1] / 2;
    int G = out_size;
    int RT = (N + 127) >> 7;       // 128-row tiles (layer 3)
    int RT64 = (N + 63) >> 6;      // 64-row tiles (layers 1-2)
    int Np = RT * 128;
    int NB = (N + 1023) >> 10;     // scan blocks (<=256 supported)

    char* p = (char*)d_ws;
    auto alloc = [&](size_t bytes) {
        char* r = p;
        p += (bytes + 255) & ~(size_t)255;
        return r;
    };
    unsigned short* hbuf = (unsigned short*)alloc((size_t)Np * 256 * 2);  // bf16 GEMM output
    unsigned short* aggh = (unsigned short*)alloc((size_t)Np * 256 * 2);  // agg out hi plane
    unsigned short* aggl = (unsigned short*)alloc((size_t)Np * 256 * 2);  // agg out lo plane
    unsigned short* pB1h = (unsigned short*)alloc((size_t)128 * 256 * 2);
    unsigned short* pB1l = (unsigned short*)alloc((size_t)128 * 256 * 2);
    unsigned short* pB2h = (unsigned short*)alloc((size_t)256 * 256 * 2);
    unsigned short* pB2l = (unsigned short*)alloc((size_t)256 * 256 * 2);
    unsigned short* pB3h = (unsigned short*)alloc((size_t)256 * 64 * 2);
    unsigned short* pB3l = (unsigned short*)alloc((size_t)256 * 64 * 2);
    float* al_s  = (float*)alloc((size_t)N * 4 * 4);
    float* al_d  = (float*)alloc((size_t)N * 4 * 4);
    int* indptr  = (int*)alloc((size_t)(N + 1) * 4);
    int* counts  = (int*)alloc((size_t)N * 4);
    int* cursor  = (int*)alloc((size_t)N * 4);
    int* lex     = (int*)alloc((size_t)N * 4);
    int* bsums   = (int*)alloc((size_t)256 * 4);
    int* csr     = (int*)alloc((size_t)E * 4);
    float* gsum  = (float*)alloc((size_t)G * 64 * 4);
    int* gcnt    = (int*)alloc((size_t)G * 4);
    if ((size_t)(p - (char*)d_ws) > ws_size) return;  // workspace too small

    hipMemsetAsync(counts, 0, (size_t)N * 4, stream);
    hipMemsetAsync(gsum, 0, (size_t)G * 64 * 4, stream);
    hipMemsetAsync(gcnt, 0, (size_t)G * 4, stream);

    // pack all weight matrices upfront (tiny)
    k_packB<<<(256 * (128 >> 3) + 255) / 256, 256, 0, stream>>>(W1, pB1h, pB1l, 128, 256);
    k_packB<<<(256 * (256 >> 3) + 255) / 256, 256, 0, stream>>>(W2, pB2h, pB2l, 256, 256);
    k_packB<<<(64 * (256 >> 3) + 255) / 256, 256, 0, stream>>>(W3, pB3h, pB3l, 256, 64);

    int eb = (E + 255) / 256;
    k_count<<<eb, 256, 0, stream>>>(ei, E, counts);
    k_scan_local<<<NB, 256, 0, stream>>>(counts, lex, bsums, N);
    k_scan_bsums<<<1, 256, 0, stream>>>(bsums, NB);
    k_scan_add<<<(N + 1 + 255) / 256, 256, 0, stream>>>(lex, bsums, indptr, cursor, N, E);
    k_scatter<<<eb, 256, 0, stream>>>(ei, E, cursor, csr);

    int wb = (N * 64 + 255) / 256;   // one wave per node

    // layer 1: 128 -> 256 (H=4, concat, ELU); A = x f32 (CONV), 64-row blocks, cols once
    k_mm<4, 1, 4, true><<<dim3(RT64, 1), 256, 0, stream>>>(x, nullptr, nullptr,
        pB1h, pB1l, hbuf, a1s, a1d, al_s, al_d, N, 128, 256);
    k_agg<4, true, false><<<wb, 256, 0, stream>>>(hbuf, al_s, al_d, indptr, csr, b1,
        aggh, aggl, nullptr, nullptr, nullptr, N);

    // layer 2: 256 -> 256 (H=4, concat, ELU); A pre-split (PRE)
    k_mm<4, 1, 4, false><<<dim3(RT64, 1), 256, 0, stream>>>(nullptr, aggh, aggl,
        pB2h, pB2l, hbuf, a2s, a2d, al_s, al_d, N, 256, 256);
    k_agg<4, true, false><<<wb, 256, 0, stream>>>(hbuf, al_s, al_d, indptr, csr, b2,
        aggh, aggl, nullptr, nullptr, nullptr, N);

    // layer 3: 256 -> 64 (H=1, no concat, no act) + fused mean-pool; A pre-split
    k_mm<2, 4, 1, false><<<dim3(RT, 1), 256, 0, stream>>>(nullptr, aggh, aggl,
        pB3h, pB3l, hbuf, a3s, a3d, al_s, al_d, N, 256, 64);
    k_agg<1, false, true><<<wb, 256, 0, stream>>>(hbuf, al_s, al_d, indptr, csr, b3,
        nullptr, nullptr, gsum, batch, gcnt, N);

    int fb = (G * 64 + 255) / 256;
    k_final<<<fb, 256, 0, stream>>>(gsum, gcnt, lw, lb, (float*)d_out, G);
}

// Round 8
// 416.819 us; speedup vs baseline: 2.5257x; 1.0111x over previous
//
#include <hip/hip_runtime.h>
#include <cstdint>
#include <cstddef>

#define NEG_SLOPE 0.2f

typedef __attribute__((ext_vector_type(8))) short short8;
typedef __attribute__((ext_vector_type(4))) float f32x4;

__device__ __forceinline__ float lrelu(float v) { return v > 0.f ? v : NEG_SLOPE * v; }

__device__ __forceinline__ unsigned short f2bf(float x) {
    unsigned u = __float_as_uint(x);
    u = (u + 0x7FFFu + ((u >> 16) & 1u)) >> 16;
    return (unsigned short)u;
}
__device__ __forceinline__ float bf2f(unsigned short h) {
    return __uint_as_float(((unsigned)h) << 16);
}

// trunc split: hi = top 16 bits, lo = bf16_trunc(x - hi). Must stay identical
// everywhere it is used (k_mm CONV path and k_agg split-store).
__device__ __forceinline__ void splitbf(float v, unsigned short& hb, unsigned short& lb) {
    unsigned u = __float_as_uint(v);
    hb = (unsigned short)(u >> 16);
    float hf = __uint_as_float(u & 0xFFFF0000u);
    float lf = v - hf;
    lb = (unsigned short)(__float_as_uint(lf) >> 16);
}

// ---------------- CSR build ----------------
__global__ void k_count(const int* __restrict__ ei, int E, int* __restrict__ counts) {
    int i = blockIdx.x * blockDim.x + threadIdx.x;
    if (i < E) atomicAdd(&counts[ei[E + i]], 1);
}

// hierarchical scan, step 1: per-block (1024 elems) local exclusive scan + block sum
__global__ __launch_bounds__(256) void k_scan_local(const int* __restrict__ counts,
        int* __restrict__ local_ex, int* __restrict__ bsums, int Nn) {
    int base = blockIdx.x * 1024;
    int tid = threadIdx.x;
    int idx = base + tid * 4;
    int4 v = make_int4(0, 0, 0, 0);
    if (idx + 3 < Nn) {
        v = *reinterpret_cast<const int4*>(&counts[idx]);
    } else {
        if (idx + 0 < Nn) v.x = counts[idx + 0];
        if (idx + 1 < Nn) v.y = counts[idx + 1];
        if (idx + 2 < Nn) v.z = counts[idx + 2];
        if (idx + 3 < Nn) v.w = counts[idx + 3];
    }
    int t = v.x + v.y + v.z + v.w;
    int lane = tid & 63, wave = tid >> 6;
    int s = t;
    #pragma unroll
    for (int off = 1; off < 64; off <<= 1) {
        int u = __shfl_up(s, off);
        if (lane >= off) s += u;
    }
    __shared__ int wsum[4];
    if (lane == 63) wsum[wave] = s;
    __syncthreads();
    int wo = 0;
    #pragma unroll
    for (int wv = 0; wv < 4; ++wv) wo += (wv < wave) ? wsum[wv] : 0;
    int ex = wo + s - t;
    int4 o;
    o.x = ex; o.y = ex + v.x; o.z = ex + v.x + v.y; o.w = ex + v.x + v.y + v.z;
    if (idx + 3 < Nn) {
        *reinterpret_cast<int4*>(&local_ex[idx]) = o;
    } else {
        if (idx + 0 < Nn) local_ex[idx + 0] = o.x;
        if (idx + 1 < Nn) local_ex[idx + 1] = o.y;
        if (idx + 2 < Nn) local_ex[idx + 2] = o.z;
        if (idx + 3 < Nn) local_ex[idx + 3] = o.w;
    }
    if (tid == 255) bsums[blockIdx.x] = wo + s;
}

// step 2: single block scans block sums in-place (exclusive). nb <= 256.
__global__ __launch_bounds__(256) void k_scan_bsums(int* __restrict__ bsums, int nb) {
    int tid = threadIdx.x;
    int v = (tid < nb) ? bsums[tid] : 0;
    int lane = tid & 63, wave = tid >> 6;
    int s = v;
    #pragma unroll
    for (int off = 1; off < 64; off <<= 1) {
        int u = __shfl_up(s, off);
        if (lane >= off) s += u;
    }
    __shared__ int wsum[4];
    if (lane == 63) wsum[wave] = s;
    __syncthreads();
    int wo = 0;
    #pragma unroll
    for (int wv = 0; wv < 4; ++wv) wo += (wv < wave) ? wsum[wv] : 0;
    if (tid < nb) bsums[tid] = wo + s - v;
}

// step 3: add block offsets; write indptr + cursor; indptr[Nn] = E.
__global__ __launch_bounds__(256) void k_scan_add(const int* __restrict__ local_ex,
        const int* __restrict__ bsums, int* __restrict__ indptr, int* __restrict__ cursor,
        int Nn, int Etot) {
    int i = blockIdx.x * 256 + threadIdx.x;
    if (i < Nn) {
        int val = local_ex[i] + bsums[i >> 10];
        indptr[i] = val;
        cursor[i] = val;
    } else if (i == Nn) {
        indptr[Nn] = Etot;
    }
}

__global__ void k_scatter(const int* __restrict__ ei, int E, int* __restrict__ cursor,
                          int* __restrict__ csr_src) {
    int i = blockIdx.x * blockDim.x + threadIdx.x;
    if (i < E) {
        int s = ei[i], d = ei[E + i];
        int pos = atomicAdd(&cursor[d], 1);
        csr_src[pos] = s;
    }
}

// ---------------- pack B (W f32 [K,M] -> fragment-packed bf16 hi/lo, RNE) ----------------
__global__ __launch_bounds__(256) void k_packB(const float* __restrict__ W,
        unsigned short* __restrict__ Ph, unsigned short* __restrict__ Pl, int K, int M) {
    int tid = blockIdx.x * 256 + threadIdx.x;
    int KS8 = K >> 3;
    int total = M * KS8;
    if (tid >= total) return;
    int col = tid / KS8;
    int k = (tid - col * KS8) << 3;
    short8 hv, lv;
    #pragma unroll
    for (int j = 0; j < 8; ++j) {
        float x = W[(size_t)(k + j) * M + col];
        unsigned short hb = f2bf(x);
        hv[j] = (short)hb;
        lv[j] = (short)f2bf(x - bf2f(hb));
    }
    int ct64 = col >> 6, c = col & 63;
    int fb = c >> 4, cl = c & 15;
    int ks = k >> 5, kg = (k >> 3) & 3;
    int lane = cl | (kg << 4);
    size_t off = (((size_t)ct64 * (K >> 5) + ks) * 4 + fb) * 64 + lane;
    *reinterpret_cast<short8*>(Ph + off * 8) = hv;
    *reinterpret_cast<short8*>(Pl + off * 8) = lv;
}

// ---------------- split-bf16 MFMA GEMM ----------------
// block = 256 threads = 4 waves (WR x WC); wave tile = AF*16 rows x 64 cols (BF=4)
// K compile-time -> full unroll -> compiler software-pipelines loads over MFMAs.
// CONV=true : A row-major f32, trunc-split in registers.
// CONV=false: A pre-split row-major bf16 planes (Aph/Apl).
// acc = Al*Bh + Ah*Bl + Ah*Bh ; attention dots from f32 acc.
template<int AF, int WR, int WC, bool CONV, int K>
__global__ __launch_bounds__(256) void k_mm(const float* __restrict__ A,
        const unsigned short* __restrict__ Aph, const unsigned short* __restrict__ Apl,
        const unsigned short* __restrict__ Bh, const unsigned short* __restrict__ Bl,
        unsigned short* __restrict__ C, const float* __restrict__ a_src, const float* __restrict__ a_dst,
        float* __restrict__ al_s, float* __restrict__ al_d, int Nrows, int M) {
    constexpr int BF = 4;
    constexpr int BR = WR * AF * 16;   // block rows
    constexpr int KS = K >> 5;
    int wave = threadIdx.x >> 6, lane = threadIdx.x & 63;
    int wr = wave / WC, wc = wave % WC;
    int rt = blockIdx.x;
    int ct64 = blockIdx.y * WC + wc;
    int rl = lane & 15, kg = lane >> 4;
    const short8* B8h = reinterpret_cast<const short8*>(Bh);
    const short8* B8l = reinterpret_cast<const short8*>(Bl);

    const float* aptr[AF];
    const unsigned short *ahp[AF], *alp[AF];
    #pragma unroll
    for (int f = 0; f < AF; ++f) {
        int row = rt * BR + wr * (AF * 16) + f * 16 + rl;
        if (row > Nrows - 1) row = Nrows - 1;   // clamp: junk rows discarded at store
        if constexpr (CONV) {
            aptr[f] = A + (size_t)row * K + kg * 8;
        } else {
            ahp[f] = Aph + (size_t)row * K + kg * 8;
            alp[f] = Apl + (size_t)row * K + kg * 8;
        }
    }

    f32x4 acc[AF][BF];
    #pragma unroll
    for (int i = 0; i < AF; ++i)
        #pragma unroll
        for (int j = 0; j < BF; ++j)
            acc[i][j] = (f32x4){0.f, 0.f, 0.f, 0.f};

    #pragma unroll
    for (int ks = 0; ks < KS; ++ks) {
        short8 a_h[AF], a_l[AF], b_h[BF], b_l[BF];
        #pragma unroll
        for (int f = 0; f < AF; ++f) {
            if constexpr (CONV) {
                const float* ap = aptr[f] + ks * 32;
                float4 v0 = *reinterpret_cast<const float4*>(ap);
                float4 v1 = *reinterpret_cast<const float4*>(ap + 4);
                float vv[8] = {v0.x, v0.y, v0.z, v0.w, v1.x, v1.y, v1.z, v1.w};
                #pragma unroll
                for (int j = 0; j < 8; ++j) {
                    unsigned short hb, lb;
                    splitbf(vv[j], hb, lb);
                    a_h[f][j] = (short)hb;
                    a_l[f][j] = (short)lb;
                }
            } else {
                a_h[f] = *reinterpret_cast<const short8*>(ahp[f] + ks * 32);
                a_l[f] = *reinterpret_cast<const short8*>(alp[f] + ks * 32);
            }
        }
        #pragma unroll
        for (int f = 0; f < BF; ++f) {
            size_t off = (((size_t)ct64 * KS + ks) * 4 + f) * 64 + lane;
            b_h[f] = B8h[off]; b_l[f] = B8l[off];
        }
        #pragma unroll
        for (int i = 0; i < AF; ++i)
            #pragma unroll
            for (int j = 0; j < BF; ++j) {
                acc[i][j] = __builtin_amdgcn_mfma_f32_16x16x32_bf16(a_l[i], b_h[j], acc[i][j], 0, 0, 0);
                acc[i][j] = __builtin_amdgcn_mfma_f32_16x16x32_bf16(a_h[i], b_l[j], acc[i][j], 0, 0, 0);
                acc[i][j] = __builtin_amdgcn_mfma_f32_16x16x32_bf16(a_h[i], b_h[j], acc[i][j], 0, 0, 0);
            }
    }

    int H = M >> 6;
    int head = ct64;                 // wave col span 64 == one head
    int col0 = ct64 * 64;
    int cl = lane & 15, rgrp = lane >> 4;

    float as_[BF], ad_[BF];
    #pragma unroll
    for (int j = 0; j < BF; ++j) {
        as_[j] = a_src[col0 + j * 16 + cl];
        ad_[j] = a_dst[col0 + j * 16 + cl];
    }

    #pragma unroll
    for (int i = 0; i < AF; ++i) {
        int rowb = rt * BR + wr * (AF * 16) + i * 16 + rgrp * 4;
        #pragma unroll
        for (int r = 0; r < 4; ++r) {
            float sv = acc[i][0][r] * as_[0] + acc[i][1][r] * as_[1]
                     + acc[i][2][r] * as_[2] + acc[i][3][r] * as_[3];
            float dv = acc[i][0][r] * ad_[0] + acc[i][1][r] * ad_[1]
                     + acc[i][2][r] * ad_[2] + acc[i][3][r] * ad_[3];
            #pragma unroll
            for (int o = 1; o < 16; o <<= 1) {
                sv += __shfl_xor(sv, o);
                dv += __shfl_xor(dv, o);
            }
            int row = rowb + r;
            if (row < Nrows) {
                unsigned short* cp = &C[(size_t)row * M + col0 + cl];
                cp[0]  = f2bf(acc[i][0][r]);
                cp[16] = f2bf(acc[i][1][r]);
                cp[32] = f2bf(acc[i][2][r]);
                cp[48] = f2bf(acc[i][3][r]);
                if (cl == 0) {
                    al_s[(size_t)row * H + head] = sv;
                    al_d[(size_t)row * H + head] = dv;
                }
            }
        }
    }
}

// ---------------- fused softmax + aggregate (wave per destination node) ----------------
// hlin bf16 values (gather); al_s/al_d f32 coefficients.
// Non-POOL output: pre-split hi/lo bf16 planes (identical bits to k_mm's CONV split).
template <int H, bool ACT, bool POOL>    // TOT = H*64
__global__ __launch_bounds__(256) void k_agg(const unsigned short* __restrict__ hlin,
                      const float* __restrict__ al_s,
                      const float* __restrict__ al_d, const int* __restrict__ indptr,
                      const int* __restrict__ csr_src, const float* __restrict__ bias,
                      unsigned short* __restrict__ out_hi, unsigned short* __restrict__ out_lo,
                      float* __restrict__ outf, const int* __restrict__ batch,
                      int* __restrict__ gcnt, int Nn) {
    constexpr int TOT = H * 64;
    constexpr int VEC = TOT / 64;
    constexpr int CAP = 128;
    __shared__ float sp[4][CAP * H];
    __shared__ int   si[4][CAP];
    int w = threadIdx.x >> 6;
    int lane = threadIdx.x & 63;
    int node = (blockIdx.x * blockDim.x + threadIdx.x) >> 6;
    if (node >= Nn) return;
    int d = node;
    int p0 = indptr[d], p1 = indptr[d + 1];
    int deg = p1 - p0;
    int head = (lane * VEC) >> 6;       // H=4: lane>>4 ; H=1: 0

    float ad[H], e_self[H];
    if constexpr (H == 4) {
        float4 adv = *reinterpret_cast<const float4*>(&al_d[(size_t)d * 4]);
        float4 asv = *reinterpret_cast<const float4*>(&al_s[(size_t)d * 4]);
        ad[0] = adv.x; ad[1] = adv.y; ad[2] = adv.z; ad[3] = adv.w;
        e_self[0] = lrelu(asv.x + ad[0]); e_self[1] = lrelu(asv.y + ad[1]);
        e_self[2] = lrelu(asv.z + ad[2]); e_self[3] = lrelu(asv.w + ad[3]);
    } else {
        ad[0] = al_d[d];
        e_self[0] = lrelu(al_s[d] + ad[0]);
    }

    float mh, invden, alpha_self;

    if (deg <= CAP) {
        int nb = (deg + 63) >> 6;
        float m[H];
        #pragma unroll
        for (int h = 0; h < H; ++h) m[h] = e_self[h];
        for (int b = 0; b < nb; ++b) {
            int l = b * 64 + lane;
            float e_h[H];
            if (l < deg) {
                int s = csr_src[p0 + l];
                si[w][l] = s;
                if constexpr (H == 4) {
                    float4 sv = *reinterpret_cast<const float4*>(&al_s[(size_t)s * 4]);
                    e_h[0] = lrelu(sv.x + ad[0]); e_h[1] = lrelu(sv.y + ad[1]);
                    e_h[2] = lrelu(sv.z + ad[2]); e_h[3] = lrelu(sv.w + ad[3]);
                } else {
                    e_h[0] = lrelu(al_s[s] + ad[0]);
                }
            } else {
                #pragma unroll
                for (int h = 0; h < H; ++h) e_h[h] = -1e30f;
            }
            #pragma unroll
            for (int h = 0; h < H; ++h) {
                sp[w][l * H + h] = e_h[h];
                m[h] = fmaxf(m[h], e_h[h]);
            }
        }
        #pragma unroll
        for (int h = 0; h < H; ++h)
            #pragma unroll
            for (int off = 1; off < 64; off <<= 1)
                m[h] = fmaxf(m[h], __shfl_xor(m[h], off));
        float den[H];
        #pragma unroll
        for (int h = 0; h < H; ++h) den[h] = 0.f;
        for (int b = 0; b < nb; ++b) {
            int l = b * 64 + lane;
            #pragma unroll
            for (int h = 0; h < H; ++h) {
                float pv = __expf(sp[w][l * H + h] - m[h]);
                sp[w][l * H + h] = pv;
                den[h] += pv;
            }
        }
        #pragma unroll
        for (int h = 0; h < H; ++h) {
            #pragma unroll
            for (int off = 1; off < 64; off <<= 1)
                den[h] += __shfl_xor(den[h], off);
            den[h] += __expf(e_self[h] - m[h]);
        }
        mh = m[head];
        invden = 1.f / den[head];
        alpha_self = __expf(e_self[head] - mh) * invden;

        float4 accv = make_float4(0.f, 0.f, 0.f, 0.f);
        {
            const unsigned short* hp = hlin + (size_t)d * TOT + lane * VEC;
            if constexpr (VEC == 4) {
                ushort4 hv = *reinterpret_cast<const ushort4*>(hp);
                accv.x = alpha_self * bf2f(hv.x); accv.y = alpha_self * bf2f(hv.y);
                accv.z = alpha_self * bf2f(hv.z); accv.w = alpha_self * bf2f(hv.w);
            } else {
                accv.x = alpha_self * bf2f(hp[0]);
            }
        }
        int e = 0;
        for (; e + 8 <= deg; e += 8) {
            int s0 = si[w][e + 0], s1 = si[w][e + 1], s2 = si[w][e + 2], s3 = si[w][e + 3];
            int s4 = si[w][e + 4], s5 = si[w][e + 5], s6 = si[w][e + 6], s7 = si[w][e + 7];
            float a0 = sp[w][(e + 0) * H + head] * invden;
            float a1 = sp[w][(e + 1) * H + head] * invden;
            float a2 = sp[w][(e + 2) * H + head] * invden;
            float a3 = sp[w][(e + 3) * H + head] * invden;
            float a4 = sp[w][(e + 4) * H + head] * invden;
            float a5 = sp[w][(e + 5) * H + head] * invden;
            float a6 = sp[w][(e + 6) * H + head] * invden;
            float a7 = sp[w][(e + 7) * H + head] * invden;
            if constexpr (VEC == 4) {
                ushort4 r0 = *reinterpret_cast<const ushort4*>(hlin + (size_t)s0 * TOT + lane * 4);
                ushort4 r1 = *reinterpret_cast<const ushort4*>(hlin + (size_t)s1 * TOT + lane * 4);
                ushort4 r2 = *reinterpret_cast<const ushort4*>(hlin + (size_t)s2 * TOT + lane * 4);
                ushort4 r3 = *reinterpret_cast<const ushort4*>(hlin + (size_t)s3 * TOT + lane * 4);
                ushort4 r4 = *reinterpret_cast<const ushort4*>(hlin + (size_t)s4 * TOT + lane * 4);
                ushort4 r5 = *reinterpret_cast<const ushort4*>(hlin + (size_t)s5 * TOT + lane * 4);
                ushort4 r6 = *reinterpret_cast<const ushort4*>(hlin + (size_t)s6 * TOT + lane * 4);
                ushort4 r7 = *reinterpret_cast<const ushort4*>(hlin + (size_t)s7 * TOT + lane * 4);
                accv.x += a0*bf2f(r0.x) + a1*bf2f(r1.x) + a2*bf2f(r2.x) + a3*bf2f(r3.x)
                        + a4*bf2f(r4.x) + a5*bf2f(r5.x) + a6*bf2f(r6.x) + a7*bf2f(r7.x);
                accv.y += a0*bf2f(r0.y) + a1*bf2f(r1.y) + a2*bf2f(r2.y) + a3*bf2f(r3.y)
                        + a4*bf2f(r4.y) + a5*bf2f(r5.y) + a6*bf2f(r6.y) + a7*bf2f(r7.y);
                accv.z += a0*bf2f(r0.z) + a1*bf2f(r1.z) + a2*bf2f(r2.z) + a3*bf2f(r3.z)
                        + a4*bf2f(r4.z) + a5*bf2f(r5.z) + a6*bf2f(r6.z) + a7*bf2f(r7.z);
                accv.w += a0*bf2f(r0.w) + a1*bf2f(r1.w) + a2*bf2f(r2.w) + a3*bf2f(r3.w)
                        + a4*bf2f(r4.w) + a5*bf2f(r5.w) + a6*bf2f(r6.w) + a7*bf2f(r7.w);
            } else {
                float r0 = bf2f(hlin[(size_t)s0 * TOT + lane]);
                float r1 = bf2f(hlin[(size_t)s1 * TOT + lane]);
                float r2 = bf2f(hlin[(size_t)s2 * TOT + lane]);
                float r3 = bf2f(hlin[(size_t)s3 * TOT + lane]);
                float r4 = bf2f(hlin[(size_t)s4 * TOT + lane]);
                float r5 = bf2f(hlin[(size_t)s5 * TOT + lane]);
                float r6 = bf2f(hlin[(size_t)s6 * TOT + lane]);
                float r7 = bf2f(hlin[(size_t)s7 * TOT + lane]);
                accv.x += a0*r0 + a1*r1 + a2*r2 + a3*r3 + a4*r4 + a5*r5 + a6*r6 + a7*r7;
            }
        }
        for (; e + 4 <= deg; e += 4) {
            int s0 = si[w][e + 0], s1 = si[w][e + 1];
            int s2 = si[w][e + 2], s3 = si[w][e + 3];
            float a0 = sp[w][(e + 0) * H + head] * invden;
            float a1 = sp[w][(e + 1) * H + head] * invden;
            float a2 = sp[w][(e + 2) * H + head] * invden;
            float a3 = sp[w][(e + 3) * H + head] * invden;
            if constexpr (VEC == 4) {
                ushort4 r0 = *reinterpret_cast<const ushort4*>(hlin + (size_t)s0 * TOT + lane * 4);
                ushort4 r1 = *reinterpret_cast<const ushort4*>(hlin + (size_t)s1 * TOT + lane * 4);
                ushort4 r2 = *reinterpret_cast<const ushort4*>(hlin + (size_t)s2 * TOT + lane * 4);
                ushort4 r3 = *reinterpret_cast<const ushort4*>(hlin + (size_t)s3 * TOT + lane * 4);
                accv.x += a0*bf2f(r0.x) + a1*bf2f(r1.x) + a2*bf2f(r2.x) + a3*bf2f(r3.x);
                accv.y += a0*bf2f(r0.y) + a1*bf2f(r1.y) + a2*bf2f(r2.y) + a3*bf2f(r3.y);
                accv.z += a0*bf2f(r0.z) + a1*bf2f(r1.z) + a2*bf2f(r2.z) + a3*bf2f(r3.z);
                accv.w += a0*bf2f(r0.w) + a1*bf2f(r1.w) + a2*bf2f(r2.w) + a3*bf2f(r3.w);
            } else {
                float r0 = bf2f(hlin[(size_t)s0 * TOT + lane]);
                float r1 = bf2f(hlin[(size_t)s1 * TOT + lane]);
                float r2 = bf2f(hlin[(size_t)s2 * TOT + lane]);
                float r3 = bf2f(hlin[(size_t)s3 * TOT + lane]);
                accv.x += a0 * r0 + a1 * r1 + a2 * r2 + a3 * r3;
            }
        }
        for (; e < deg; ++e) {
            int s = si[w][e];
            float a = sp[w][e * H + head] * invden;
            if constexpr (VEC == 4) {
                ushort4 rv = *reinterpret_cast<const ushort4*>(hlin + (size_t)s * TOT + lane * 4);
                accv.x += a * bf2f(rv.x); accv.y += a * bf2f(rv.y);
                accv.z += a * bf2f(rv.z); accv.w += a * bf2f(rv.w);
            } else {
                accv.x += a * bf2f(hlin[(size_t)s * TOT + lane]);
            }
        }
        if constexpr (VEC == 4) {
            int c0 = lane * 4;
            accv.x += bias[c0 + 0]; accv.y += bias[c0 + 1];
            accv.z += bias[c0 + 2]; accv.w += bias[c0 + 3];
            if (ACT) {
                accv.x = accv.x > 0.f ? accv.x : expm1f(accv.x);
                accv.y = accv.y > 0.f ? accv.y : expm1f(accv.y);
                accv.z = accv.z > 0.f ? accv.z : expm1f(accv.z);
                accv.w = accv.w > 0.f ? accv.w : expm1f(accv.w);
            }
            ushort4 hv, lv;
            splitbf(accv.x, hv.x, lv.x);
            splitbf(accv.y, hv.y, lv.y);
            splitbf(accv.z, hv.z, lv.z);
            splitbf(accv.w, hv.w, lv.w);
            *reinterpret_cast<ushort4*>(&out_hi[(size_t)d * TOT + c0]) = hv;
            *reinterpret_cast<ushort4*>(&out_lo[(size_t)d * TOT + c0]) = lv;
        } else {
            float o = accv.x + bias[lane];
            if (ACT) o = o > 0.f ? o : expm1f(o);
            if constexpr (POOL) {
                int g = batch[d];
                atomicAdd(&outf[(size_t)g * 64 + lane], o);
                if (lane == 0) atomicAdd(&gcnt[g], 1);
            } else {
                unsigned short hb, lb;
                splitbf(o, hb, lb);
                out_hi[(size_t)d * TOT + lane] = hb;
                out_lo[(size_t)d * TOT + lane] = lb;
            }
        }
        return;
    }

    // ---- fallback: deg > CAP, serial 3-pass (no LDS) ----
    {
        float adh = ad[head];
        float es = e_self[head];
        float m = es;
        for (int e = p0; e < p1; ++e) {
            int s = csr_src[e];
            m = fmaxf(m, lrelu(al_s[(size_t)s * H + head] + adh));
        }
        float den = __expf(es - m);
        for (int e = p0; e < p1; ++e) {
            int s = csr_src[e];
            den += __expf(lrelu(al_s[(size_t)s * H + head] + adh) - m);
        }
        den = 1.f / den;
        float accv[VEC] = {};
        {
            float alpha = __expf(es - m) * den;
            const unsigned short* hp = hlin + (size_t)d * TOT + lane * VEC;
            #pragma unroll
            for (int v = 0; v < VEC; ++v) accv[v] = alpha * bf2f(hp[v]);
        }
        for (int e = p0; e < p1; ++e) {
            int s = csr_src[e];
            float alpha = __expf(lrelu(al_s[(size_t)s * H + head] + adh) - m) * den;
            const unsigned short* hp = hlin + (size_t)s * TOT + lane * VEC;
            #pragma unroll
            for (int v = 0; v < VEC; ++v) accv[v] += alpha * bf2f(hp[v]);
        }
        #pragma unroll
        for (int v = 0; v < VEC; ++v) {
            int c = lane * VEC + v;
            float o = accv[v] + bias[c];
            if (ACT) o = o > 0.f ? o : expm1f(o);
            accv[v] = o;
        }
        if constexpr (POOL) {
            int g = batch[d];
            atomicAdd(&outf[(size_t)g * 64 + lane], accv[0]);
            if (lane == 0) atomicAdd(&gcnt[g], 1);
        } else {
            #pragma unroll
            for (int v = 0; v < VEC; ++v) {
                unsigned short hb, lb;
                splitbf(accv[v], hb, lb);
                out_hi[(size_t)d * TOT + lane * VEC + v] = hb;
                out_lo[(size_t)d * TOT + lane * VEC + v] = lb;
            }
        }
    }
}

// ---------------- final linear ----------------
__global__ void k_final(const float* __restrict__ gsum, const int* __restrict__ gcnt,
                        const float* __restrict__ lin_w, const float* __restrict__ lin_b,
                        float* __restrict__ out, int Gn) {
    int g = (blockIdx.x * blockDim.x + threadIdx.x) >> 6;
    int lane = threadIdx.x & 63;
    if (g >= Gn) return;
    float cnt = (float)gcnt[g];
    float inv = 1.f / fmaxf(cnt, 1.f);
    float v = gsum[(size_t)g * 64 + lane] * inv * lin_w[lane];
    #pragma unroll
    for (int off = 32; off >= 1; off >>= 1) v += __shfl_xor(v, off);
    if (lane == 0) out[g] = v + lin_b[0];
}

extern "C" void kernel_launch(void* const* d_in, const int* in_sizes, int n_in,
                              void* d_out, int out_size, void* d_ws, size_t ws_size,
                              hipStream_t stream) {
    const float* x    = (const float*)d_in[0];
    const int*   ei   = (const int*)d_in[1];
    const int*   batch= (const int*)d_in[2];
    const float* W1   = (const float*)d_in[3];
    const float* a1s  = (const float*)d_in[4];
    const float* a1d  = (const float*)d_in[5];
    const float* b1   = (const float*)d_in[6];
    const float* W2   = (const float*)d_in[7];
    const float* a2s  = (const float*)d_in[8];
    const float* a2d  = (const float*)d_in[9];
    const float* b2   = (const float*)d_in[10];
    const float* W3   = (const float*)d_in[11];
    const float* a3s  = (const float*)d_in[12];
    const float* a3d  = (const float*)d_in[13];
    const float* b3   = (const float*)d_in[14];
    const float* lw   = (const float*)d_in[15];
    const float* lb   = (const float*)d_in[16];

    int N = in_sizes[0] / 128;
    int E = in_sizes[1] / 2;
    int G = out_size;
    int RT32 = (N + 31) >> 5;      // 32-row tiles (layers 1-2)
    int RT64 = (N + 63) >> 6;      // 64-row tiles (layer 3)
    int Np = ((N + 127) >> 7) * 128;
    int NB = (N + 1023) >> 10;     // scan blocks (<=256 supported)

    char* p = (char*)d_ws;
    auto alloc = [&](size_t bytes) {
        char* r = p;
        p += (bytes + 255) & ~(size_t)255;
        return r;
    };
    unsigned short* hbuf = (unsigned short*)alloc((size_t)Np * 256 * 2);  // bf16 GEMM output
    unsigned short* aggh = (unsigned short*)alloc((size_t)Np * 256 * 2);  // agg out hi plane
    unsigned short* aggl = (unsigned short*)alloc((size_t)Np * 256 * 2);  // agg out lo plane
    unsigned short* pB1h = (unsigned short*)alloc((size_t)128 * 256 * 2);
    unsigned short* pB1l = (unsigned short*)alloc((size_t)128 * 256 * 2);
    unsigned short* pB2h = (unsigned short*)alloc((size_t)256 * 256 * 2);
    unsigned short* pB2l = (unsigned short*)alloc((size_t)256 * 256 * 2);
    unsigned short* pB3h = (unsigned short*)alloc((size_t)256 * 64 * 2);
    unsigned short* pB3l = (unsigned short*)alloc((size_t)256 * 64 * 2);
    float* al_s  = (float*)alloc((size_t)N * 4 * 4);
    float* al_d  = (float*)alloc((size_t)N * 4 * 4);
    int* indptr  = (int*)alloc((size_t)(N + 1) * 4);
    int* counts  = (int*)alloc((size_t)N * 4);
    int* cursor  = (int*)alloc((size_t)N * 4);
    int* lex     = (int*)alloc((size_t)N * 4);
    int* bsums   = (int*)alloc((size_t)256 * 4);
    int* csr     = (int*)alloc((size_t)E * 4);
    float* gsum  = (float*)alloc((size_t)G * 64 * 4);
    int* gcnt    = (int*)alloc((size_t)G * 4);
    if ((size_t)(p - (char*)d_ws) > ws_size) return;  // workspace too small

    hipMemsetAsync(counts, 0, (size_t)N * 4, stream);
    hipMemsetAsync(gsum, 0, (size_t)G * 64 * 4, stream);
    hipMemsetAsync(gcnt, 0, (size_t)G * 4, stream);

    // pack all weight matrices upfront (tiny)
    k_packB<<<(256 * (128 >> 3) + 255) / 256, 256, 0, stream>>>(W1, pB1h, pB1l, 128, 256);
    k_packB<<<(256 * (256 >> 3) + 255) / 256, 256, 0, stream>>>(W2, pB2h, pB2l, 256, 256);
    k_packB<<<(64 * (256 >> 3) + 255) / 256, 256, 0, stream>>>(W3, pB3h, pB3l, 256, 64);

    int eb = (E + 255) / 256;
    k_count<<<eb, 256, 0, stream>>>(ei, E, counts);
    k_scan_local<<<NB, 256, 0, stream>>>(counts, lex, bsums, N);
    k_scan_bsums<<<1, 256, 0, stream>>>(bsums, NB);
    k_scan_add<<<(N + 1 + 255) / 256, 256, 0, stream>>>(lex, bsums, indptr, cursor, N, E);
    k_scatter<<<eb, 256, 0, stream>>>(ei, E, cursor, csr);

    int wb = (N * 64 + 255) / 256;   // one wave per node

    // layer 1: 128 -> 256 (H=4, concat, ELU); A = x f32 (CONV); 32-row blocks
    k_mm<2, 1, 4, true, 128><<<dim3(RT32, 1), 256, 0, stream>>>(x, nullptr, nullptr,
        pB1h, pB1l, hbuf, a1s, a1d, al_s, al_d, N, 256);
    k_agg<4, true, false><<<wb, 256, 0, stream>>>(hbuf, al_s, al_d, indptr, csr, b1,
        aggh, aggl, nullptr, nullptr, nullptr, N);

    // layer 2: 256 -> 256 (H=4, concat, ELU); A pre-split; 32-row blocks
    k_mm<2, 1, 4, false, 256><<<dim3(RT32, 1), 256, 0, stream>>>(nullptr, aggh, aggl,
        pB2h, pB2l, hbuf, a2s, a2d, al_s, al_d, N, 256);
    k_agg<4, true, false><<<wb, 256, 0, stream>>>(hbuf, al_s, al_d, indptr, csr, b2,
        aggh, aggl, nullptr, nullptr, nullptr, N);

    // layer 3: 256 -> 64 (H=1, no concat, no act) + fused mean-pool; 64-row blocks
    k_mm<1, 4, 1, false, 256><<<dim3(RT64, 1), 256, 0, stream>>>(nullptr, aggh, aggl,
        pB3h, pB3l, hbuf, a3s, a3d, al_s, al_d, N, 64);
    k_agg<1, false, true><<<wb, 256, 0, stream>>>(hbuf, al_s, al_d, indptr, csr, b3,
        nullptr, nullptr, gsum, batch, gcnt, N);

    int fb = (G * 64 + 255) / 256;
    k_final<<<fb, 256, 0, stream>>>(gsum, gcnt, lw, lb, (float*)d_out, G);
}

// Round 9
// 407.350 us; speedup vs baseline: 2.5844x; 1.0232x over previous
//
#include <hip/hip_runtime.h>
#include <cstdint>
#include <cstddef>

#define NEG_SLOPE 0.2f

typedef __attribute__((ext_vector_type(8))) short short8;
typedef __attribute__((ext_vector_type(4))) float f32x4;

__device__ __forceinline__ float lrelu(float v) { return v > 0.f ? v : NEG_SLOPE * v; }

__device__ __forceinline__ unsigned short f2bf(float x) {
    unsigned u = __float_as_uint(x);
    u = (u + 0x7FFFu + ((u >> 16) & 1u)) >> 16;
    return (unsigned short)u;
}
__device__ __forceinline__ float bf2f(unsigned short h) {
    return __uint_as_float(((unsigned)h) << 16);
}

// trunc split: hi = top 16 bits, lo = bf16_trunc(x - hi). Must stay identical
// everywhere it is used (k_mm CONV path and k_agg split-store).
__device__ __forceinline__ void splitbf(float v, unsigned short& hb, unsigned short& lb) {
    unsigned u = __float_as_uint(v);
    hb = (unsigned short)(u >> 16);
    float hf = __uint_as_float(u & 0xFFFF0000u);
    float lf = v - hf;
    lb = (unsigned short)(__float_as_uint(lf) >> 16);
}

// ---------------- CSR build ----------------
__global__ void k_count(const int* __restrict__ ei, int E, int* __restrict__ counts) {
    int i = blockIdx.x * blockDim.x + threadIdx.x;
    if (i < E) atomicAdd(&counts[ei[E + i]], 1);
}

// hierarchical scan, step 1: per-block (1024 elems) local exclusive scan + block sum
__global__ __launch_bounds__(256) void k_scan_local(const int* __restrict__ counts,
        int* __restrict__ local_ex, int* __restrict__ bsums, int Nn) {
    int base = blockIdx.x * 1024;
    int tid = threadIdx.x;
    int idx = base + tid * 4;
    int4 v = make_int4(0, 0, 0, 0);
    if (idx + 3 < Nn) {
        v = *reinterpret_cast<const int4*>(&counts[idx]);
    } else {
        if (idx + 0 < Nn) v.x = counts[idx + 0];
        if (idx + 1 < Nn) v.y = counts[idx + 1];
        if (idx + 2 < Nn) v.z = counts[idx + 2];
        if (idx + 3 < Nn) v.w = counts[idx + 3];
    }
    int t = v.x + v.y + v.z + v.w;
    int lane = tid & 63, wave = tid >> 6;
    int s = t;
    #pragma unroll
    for (int off = 1; off < 64; off <<= 1) {
        int u = __shfl_up(s, off);
        if (lane >= off) s += u;
    }
    __shared__ int wsum[4];
    if (lane == 63) wsum[wave] = s;
    __syncthreads();
    int wo = 0;
    #pragma unroll
    for (int wv = 0; wv < 4; ++wv) wo += (wv < wave) ? wsum[wv] : 0;
    int ex = wo + s - t;
    int4 o;
    o.x = ex; o.y = ex + v.x; o.z = ex + v.x + v.y; o.w = ex + v.x + v.y + v.z;
    if (idx + 3 < Nn) {
        *reinterpret_cast<int4*>(&local_ex[idx]) = o;
    } else {
        if (idx + 0 < Nn) local_ex[idx + 0] = o.x;
        if (idx + 1 < Nn) local_ex[idx + 1] = o.y;
        if (idx + 2 < Nn) local_ex[idx + 2] = o.z;
        if (idx + 3 < Nn) local_ex[idx + 3] = o.w;
    }
    if (tid == 255) bsums[blockIdx.x] = wo + s;
}

// step 2 (fused): every block redundantly wave-scans bsums (NB <= 64), then adds
// block offsets; writes indptr + cursor; indptr[Nn] = E.
__global__ __launch_bounds__(256) void k_scan_add(const int* __restrict__ local_ex,
        const int* __restrict__ bsums, int* __restrict__ indptr, int* __restrict__ cursor,
        int Nn, int Etot, int NB) {
    __shared__ int pref[64];
    int tid = threadIdx.x;
    if (tid < 64) {
        int v = (tid < NB) ? bsums[tid] : 0;
        int s = v;
        #pragma unroll
        for (int off = 1; off < 64; off <<= 1) {
            int u = __shfl_up(s, off);
            if ((tid & 63) >= off) s += u;
        }
        pref[tid] = s - v;   // exclusive prefix
    }
    __syncthreads();
    int i = blockIdx.x * 256 + tid;
    if (i < Nn) {
        int val = local_ex[i] + pref[i >> 10];
        indptr[i] = val;
        cursor[i] = val;
    } else if (i == Nn) {
        indptr[Nn] = Etot;
    }
}

__global__ void k_scatter(const int* __restrict__ ei, int E, int* __restrict__ cursor,
                          int* __restrict__ csr_src) {
    int i = blockIdx.x * blockDim.x + threadIdx.x;
    if (i < E) {
        int s = ei[i], d = ei[E + i];
        int pos = atomicAdd(&cursor[d], 1);
        csr_src[pos] = s;
    }
}

// ---------------- pack B (W f32 [K,M] -> fragment-packed bf16 hi/lo, RNE) ----------------
__device__ __forceinline__ void packB_one(const float* __restrict__ W,
        unsigned short* __restrict__ Ph, unsigned short* __restrict__ Pl,
        int K, int M, int tid) {
    int KS8 = K >> 3;
    int col = tid / KS8;
    int k = (tid - col * KS8) << 3;
    short8 hv, lv;
    #pragma unroll
    for (int j = 0; j < 8; ++j) {
        float x = W[(size_t)(k + j) * M + col];
        unsigned short hb = f2bf(x);
        hv[j] = (short)hb;
        lv[j] = (short)f2bf(x - bf2f(hb));
    }
    int ct64 = col >> 6, c = col & 63;
    int fb = c >> 4, cl = c & 15;
    int ks = k >> 5, kg = (k >> 3) & 3;
    int lane = cl | (kg << 4);
    size_t off = (((size_t)ct64 * (K >> 5) + ks) * 4 + fb) * 64 + lane;
    *reinterpret_cast<short8*>(Ph + off * 8) = hv;
    *reinterpret_cast<short8*>(Pl + off * 8) = lv;
}

// fused: packs W1 (128x256 -> 4096 slots), W2 (256x256 -> 8192), W3 (256x64 -> 2048)
__global__ __launch_bounds__(256) void k_packB3(const float* __restrict__ W1,
        const float* __restrict__ W2, const float* __restrict__ W3,
        unsigned short* p1h, unsigned short* p1l,
        unsigned short* p2h, unsigned short* p2l,
        unsigned short* p3h, unsigned short* p3l) {
    int tid = blockIdx.x * 256 + threadIdx.x;
    if (tid < 4096)        packB_one(W1, p1h, p1l, 128, 256, tid);
    else if (tid < 12288)  packB_one(W2, p2h, p2l, 256, 256, tid - 4096);
    else if (tid < 14336)  packB_one(W3, p3h, p3l, 256, 64, tid - 12288);
}

// ---------------- split-bf16 MFMA GEMM ----------------
// block = 256 threads = 4 waves (WR x WC); wave tile = AF*16 rows x 64 cols (BF=4)
// K compile-time -> full unroll. CONV: A row-major f32, trunc-split in registers;
// else A pre-split row-major bf16 planes. acc = Al*Bh + Ah*Bl + Ah*Bh.
template<int AF, int WR, int WC, bool CONV, int K>
__global__ __launch_bounds__(256) void k_mm(const float* __restrict__ A,
        const unsigned short* __restrict__ Aph, const unsigned short* __restrict__ Apl,
        const unsigned short* __restrict__ Bh, const unsigned short* __restrict__ Bl,
        unsigned short* __restrict__ C, const float* __restrict__ a_src, const float* __restrict__ a_dst,
        float* __restrict__ al_s, float* __restrict__ al_d, int Nrows, int M) {
    constexpr int BF = 4;
    constexpr int BR = WR * AF * 16;   // block rows
    constexpr int KS = K >> 5;
    int wave = threadIdx.x >> 6, lane = threadIdx.x & 63;
    int wr = wave / WC, wc = wave % WC;
    int rt = blockIdx.x;
    int ct64 = blockIdx.y * WC + wc;
    int rl = lane & 15, kg = lane >> 4;
    const short8* B8h = reinterpret_cast<const short8*>(Bh);
    const short8* B8l = reinterpret_cast<const short8*>(Bl);

    const float* aptr[AF];
    const unsigned short *ahp[AF], *alp[AF];
    #pragma unroll
    for (int f = 0; f < AF; ++f) {
        int row = rt * BR + wr * (AF * 16) + f * 16 + rl;
        if (row > Nrows - 1) row = Nrows - 1;   // clamp: junk rows discarded at store
        if constexpr (CONV) {
            aptr[f] = A + (size_t)row * K + kg * 8;
        } else {
            ahp[f] = Aph + (size_t)row * K + kg * 8;
            alp[f] = Apl + (size_t)row * K + kg * 8;
        }
    }

    f32x4 acc[AF][BF];
    #pragma unroll
    for (int i = 0; i < AF; ++i)
        #pragma unroll
        for (int j = 0; j < BF; ++j)
            acc[i][j] = (f32x4){0.f, 0.f, 0.f, 0.f};

    #pragma unroll
    for (int ks = 0; ks < KS; ++ks) {
        short8 a_h[AF], a_l[AF], b_h[BF], b_l[BF];
        #pragma unroll
        for (int f = 0; f < AF; ++f) {
            if constexpr (CONV) {
                const float* ap = aptr[f] + ks * 32;
                float4 v0 = *reinterpret_cast<const float4*>(ap);
                float4 v1 = *reinterpret_cast<const float4*>(ap + 4);
                float vv[8] = {v0.x, v0.y, v0.z, v0.w, v1.x, v1.y, v1.z, v1.w};
                #pragma unroll
                for (int j = 0; j < 8; ++j) {
                    unsigned short hb, lb;
                    splitbf(vv[j], hb, lb);
                    a_h[f][j] = (short)hb;
                    a_l[f][j] = (short)lb;
                }
            } else {
                a_h[f] = *reinterpret_cast<const short8*>(ahp[f] + ks * 32);
                a_l[f] = *reinterpret_cast<const short8*>(alp[f] + ks * 32);
            }
        }
        #pragma unroll
        for (int f = 0; f < BF; ++f) {
            size_t off = (((size_t)ct64 * KS + ks) * 4 + f) * 64 + lane;
            b_h[f] = B8h[off]; b_l[f] = B8l[off];
        }
        #pragma unroll
        for (int i = 0; i < AF; ++i)
            #pragma unroll
            for (int j = 0; j < BF; ++j) {
                acc[i][j] = __builtin_amdgcn_mfma_f32_16x16x32_bf16(a_l[i], b_h[j], acc[i][j], 0, 0, 0);
                acc[i][j] = __builtin_amdgcn_mfma_f32_16x16x32_bf16(a_h[i], b_l[j], acc[i][j], 0, 0, 0);
                acc[i][j] = __builtin_amdgcn_mfma_f32_16x16x32_bf16(a_h[i], b_h[j], acc[i][j], 0, 0, 0);
            }
    }

    int H = M >> 6;
    int head = ct64;                 // wave col span 64 == one head
    int col0 = ct64 * 64;
    int cl = lane & 15, rgrp = lane >> 4;

    float as_[BF], ad_[BF];
    #pragma unroll
    for (int j = 0; j < BF; ++j) {
        as_[j] = a_src[col0 + j * 16 + cl];
        ad_[j] = a_dst[col0 + j * 16 + cl];
    }

    #pragma unroll
    for (int i = 0; i < AF; ++i) {
        int rowb = rt * BR + wr * (AF * 16) + i * 16 + rgrp * 4;
        #pragma unroll
        for (int r = 0; r < 4; ++r) {
            float sv = acc[i][0][r] * as_[0] + acc[i][1][r] * as_[1]
                     + acc[i][2][r] * as_[2] + acc[i][3][r] * as_[3];
            float dv = acc[i][0][r] * ad_[0] + acc[i][1][r] * ad_[1]
                     + acc[i][2][r] * ad_[2] + acc[i][3][r] * ad_[3];
            #pragma unroll
            for (int o = 1; o < 16; o <<= 1) {
                sv += __shfl_xor(sv, o);
                dv += __shfl_xor(dv, o);
            }
            int row = rowb + r;
            if (row < Nrows) {
                unsigned short* cp = &C[(size_t)row * M + col0 + cl];
                cp[0]  = f2bf(acc[i][0][r]);
                cp[16] = f2bf(acc[i][1][r]);
                cp[32] = f2bf(acc[i][2][r]);
                cp[48] = f2bf(acc[i][3][r]);
                if (cl == 0) {
                    al_s[(size_t)row * H + head] = sv;
                    al_d[(size_t)row * H + head] = dv;
                }
            }
        }
    }
}

// ---------------- fused softmax + aggregate (wave per destination node) ----------------
// hlin bf16 values (gather); al_s/al_d f32 coefficients.
// Softmax reductions are per-head lane-group (GRPW = 64/H) strided over LDS.
// invden applied once in epilogue (weights kept raw exp(e-m)).
template <int H, bool ACT, bool POOL>    // TOT = H*64
__global__ __launch_bounds__(256) void k_agg(const unsigned short* __restrict__ hlin,
                      const float* __restrict__ al_s,
                      const float* __restrict__ al_d, const int* __restrict__ indptr,
                      const int* __restrict__ csr_src, const float* __restrict__ bias,
                      unsigned short* __restrict__ out_hi, unsigned short* __restrict__ out_lo,
                      float* __restrict__ outf, const int* __restrict__ batch,
                      int* __restrict__ gcnt, int Nn) {
    constexpr int TOT = H * 64;
    constexpr int VEC = TOT / 64;
    constexpr int CAP = 128;
    constexpr int GRPW = 64 / H;   // lanes per head group
    __shared__ float sp[4][CAP * H];
    __shared__ int   si[4][CAP];
    int w = threadIdx.x >> 6;
    int lane = threadIdx.x & 63;
    int node = (blockIdx.x * blockDim.x + threadIdx.x) >> 6;
    if (node >= Nn) return;
    int d = node;
    int p0 = indptr[d], p1 = indptr[d + 1];
    int deg = p1 - p0;
    int head = (lane * VEC) >> 6;       // == lane / GRPW

    float ad[H], e_self[H];
    if constexpr (H == 4) {
        float4 adv = *reinterpret_cast<const float4*>(&al_d[(size_t)d * 4]);
        float4 asv = *reinterpret_cast<const float4*>(&al_s[(size_t)d * 4]);
        ad[0] = adv.x; ad[1] = adv.y; ad[2] = adv.z; ad[3] = adv.w;
        e_self[0] = lrelu(asv.x + ad[0]); e_self[1] = lrelu(asv.y + ad[1]);
        e_self[2] = lrelu(asv.z + ad[2]); e_self[3] = lrelu(asv.w + ad[3]);
    } else {
        ad[0] = al_d[d];
        e_self[0] = lrelu(al_s[d] + ad[0]);
    }

    if (deg <= CAP) {
        int nb = (deg + 63) >> 6;
        // phase A: compute e per lane-edge (all heads), stash in LDS
        for (int b = 0; b < nb; ++b) {
            int l = b * 64 + lane;
            float e_h[H];
            if (l < deg) {
                int s = csr_src[p0 + l];
                si[w][l] = s;
                if constexpr (H == 4) {
                    float4 sv = *reinterpret_cast<const float4*>(&al_s[(size_t)s * 4]);
                    e_h[0] = lrelu(sv.x + ad[0]); e_h[1] = lrelu(sv.y + ad[1]);
                    e_h[2] = lrelu(sv.z + ad[2]); e_h[3] = lrelu(sv.w + ad[3]);
                } else {
                    e_h[0] = lrelu(al_s[s] + ad[0]);
                }
            } else {
                #pragma unroll
                for (int h = 0; h < H; ++h) e_h[h] = -1e30f;
            }
            #pragma unroll
            for (int h = 0; h < H; ++h) sp[w][l * H + h] = e_h[h];
        }
        // per-head group reduction: max
        int li = lane & (GRPW - 1);
        int tot = nb * 64;
        float mg = e_self[head];
        for (int l = li; l < tot; l += GRPW)
            mg = fmaxf(mg, sp[w][l * H + head]);
        #pragma unroll
        for (int o = 1; o < GRPW; o <<= 1)
            mg = fmaxf(mg, __shfl_xor(mg, o));
        // exp + denom (own head only), pv written back raw
        float deng = 0.f;
        for (int l = li; l < tot; l += GRPW) {
            float pv = __expf(sp[w][l * H + head] - mg);
            sp[w][l * H + head] = pv;
            deng += pv;
        }
        #pragma unroll
        for (int o = 1; o < GRPW; o <<= 1)
            deng += __shfl_xor(deng, o);
        float esx = __expf(e_self[head] - mg);
        deng += esx;
        float invden = 1.f / deng;

        // gather with raw weights; invden applied once at end
        float4 accv = make_float4(0.f, 0.f, 0.f, 0.f);
        {
            const unsigned short* hp = hlin + (size_t)d * TOT + lane * VEC;
            if constexpr (VEC == 4) {
                ushort4 hv = *reinterpret_cast<const ushort4*>(hp);
                accv.x = esx * bf2f(hv.x); accv.y = esx * bf2f(hv.y);
                accv.z = esx * bf2f(hv.z); accv.w = esx * bf2f(hv.w);
            } else {
                accv.x = esx * bf2f(hp[0]);
            }
        }
        int e = 0;
        for (; e + 8 <= deg; e += 8) {
            int s0 = si[w][e + 0], s1 = si[w][e + 1], s2 = si[w][e + 2], s3 = si[w][e + 3];
            int s4 = si[w][e + 4], s5 = si[w][e + 5], s6 = si[w][e + 6], s7 = si[w][e + 7];
            float a0 = sp[w][(e + 0) * H + head];
            float a1 = sp[w][(e + 1) * H + head];
            float a2 = sp[w][(e + 2) * H + head];
            float a3 = sp[w][(e + 3) * H + head];
            float a4 = sp[w][(e + 4) * H + head];
            float a5 = sp[w][(e + 5) * H + head];
            float a6 = sp[w][(e + 6) * H + head];
            float a7 = sp[w][(e + 7) * H + head];
            if constexpr (VEC == 4) {
                ushort4 r0 = *reinterpret_cast<const ushort4*>(hlin + (size_t)s0 * TOT + lane * 4);
                ushort4 r1 = *reinterpret_cast<const ushort4*>(hlin + (size_t)s1 * TOT + lane * 4);
                ushort4 r2 = *reinterpret_cast<const ushort4*>(hlin + (size_t)s2 * TOT + lane * 4);
                ushort4 r3 = *reinterpret_cast<const ushort4*>(hlin + (size_t)s3 * TOT + lane * 4);
                ushort4 r4 = *reinterpret_cast<const ushort4*>(hlin + (size_t)s4 * TOT + lane * 4);
                ushort4 r5 = *reinterpret_cast<const ushort4*>(hlin + (size_t)s5 * TOT + lane * 4);
                ushort4 r6 = *reinterpret_cast<const ushort4*>(hlin + (size_t)s6 * TOT + lane * 4);
                ushort4 r7 = *reinterpret_cast<const ushort4*>(hlin + (size_t)s7 * TOT + lane * 4);
                accv.x += a0*bf2f(r0.x) + a1*bf2f(r1.x) + a2*bf2f(r2.x) + a3*bf2f(r3.x)
                        + a4*bf2f(r4.x) + a5*bf2f(r5.x) + a6*bf2f(r6.x) + a7*bf2f(r7.x);
                accv.y += a0*bf2f(r0.y) + a1*bf2f(r1.y) + a2*bf2f(r2.y) + a3*bf2f(r3.y)
                        + a4*bf2f(r4.y) + a5*bf2f(r5.y) + a6*bf2f(r6.y) + a7*bf2f(r7.y);
                accv.z += a0*bf2f(r0.z) + a1*bf2f(r1.z) + a2*bf2f(r2.z) + a3*bf2f(r3.z)
                        + a4*bf2f(r4.z) + a5*bf2f(r5.z) + a6*bf2f(r6.z) + a7*bf2f(r7.z);
                accv.w += a0*bf2f(r0.w) + a1*bf2f(r1.w) + a2*bf2f(r2.w) + a3*bf2f(r3.w)
                        + a4*bf2f(r4.w) + a5*bf2f(r5.w) + a6*bf2f(r6.w) + a7*bf2f(r7.w);
            } else {
                float r0 = bf2f(hlin[(size_t)s0 * TOT + lane]);
                float r1 = bf2f(hlin[(size_t)s1 * TOT + lane]);
                float r2 = bf2f(hlin[(size_t)s2 * TOT + lane]);
                float r3 = bf2f(hlin[(size_t)s3 * TOT + lane]);
                float r4 = bf2f(hlin[(size_t)s4 * TOT + lane]);
                float r5 = bf2f(hlin[(size_t)s5 * TOT + lane]);
                float r6 = bf2f(hlin[(size_t)s6 * TOT + lane]);
                float r7 = bf2f(hlin[(size_t)s7 * TOT + lane]);
                accv.x += a0*r0 + a1*r1 + a2*r2 + a3*r3 + a4*r4 + a5*r5 + a6*r6 + a7*r7;
            }
        }
        for (; e + 4 <= deg; e += 4) {
            int s0 = si[w][e + 0], s1 = si[w][e + 1];
            int s2 = si[w][e + 2], s3 = si[w][e + 3];
            float a0 = sp[w][(e + 0) * H + head];
            float a1 = sp[w][(e + 1) * H + head];
            float a2 = sp[w][(e + 2) * H + head];
            float a3 = sp[w][(e + 3) * H + head];
            if constexpr (VEC == 4) {
                ushort4 r0 = *reinterpret_cast<const ushort4*>(hlin + (size_t)s0 * TOT + lane * 4);
                ushort4 r1 = *reinterpret_cast<const ushort4*>(hlin + (size_t)s1 * TOT + lane * 4);
                ushort4 r2 = *reinterpret_cast<const ushort4*>(hlin + (size_t)s2 * TOT + lane * 4);
                ushort4 r3 = *reinterpret_cast<const ushort4*>(hlin + (size_t)s3 * TOT + lane * 4);
                accv.x += a0*bf2f(r0.x) + a1*bf2f(r1.x) + a2*bf2f(r2.x) + a3*bf2f(r3.x);
                accv.y += a0*bf2f(r0.y) + a1*bf2f(r1.y) + a2*bf2f(r2.y) + a3*bf2f(r3.y);
                accv.z += a0*bf2f(r0.z) + a1*bf2f(r1.z) + a2*bf2f(r2.z) + a3*bf2f(r3.z);
                accv.w += a0*bf2f(r0.w) + a1*bf2f(r1.w) + a2*bf2f(r2.w) + a3*bf2f(r3.w);
            } else {
                float r0 = bf2f(hlin[(size_t)s0 * TOT + lane]);
                float r1 = bf2f(hlin[(size_t)s1 * TOT + lane]);
                float r2 = bf2f(hlin[(size_t)s2 * TOT + lane]);
                float r3 = bf2f(hlin[(size_t)s3 * TOT + lane]);
                accv.x += a0 * r0 + a1 * r1 + a2 * r2 + a3 * r3;
            }
        }
        for (; e < deg; ++e) {
            int s = si[w][e];
            float a = sp[w][e * H + head];
            if constexpr (VEC == 4) {
                ushort4 rv = *reinterpret_cast<const ushort4*>(hlin + (size_t)s * TOT + lane * 4);
                accv.x += a * bf2f(rv.x); accv.y += a * bf2f(rv.y);
                accv.z += a * bf2f(rv.z); accv.w += a * bf2f(rv.w);
            } else {
                accv.x += a * bf2f(hlin[(size_t)s * TOT + lane]);
            }
        }
        if constexpr (VEC == 4) {
            int c0 = lane * 4;
            accv.x = accv.x * invden + bias[c0 + 0];
            accv.y = accv.y * invden + bias[c0 + 1];
            accv.z = accv.z * invden + bias[c0 + 2];
            accv.w = accv.w * invden + bias[c0 + 3];
            if (ACT) {
                accv.x = accv.x > 0.f ? accv.x : expm1f(accv.x);
                accv.y = accv.y > 0.f ? accv.y : expm1f(accv.y);
                accv.z = accv.z > 0.f ? accv.z : expm1f(accv.z);
                accv.w = accv.w > 0.f ? accv.w : expm1f(accv.w);
            }
            ushort4 hv, lv;
            splitbf(accv.x, hv.x, lv.x);
            splitbf(accv.y, hv.y, lv.y);
            splitbf(accv.z, hv.z, lv.z);
            splitbf(accv.w, hv.w, lv.w);
            *reinterpret_cast<ushort4*>(&out_hi[(size_t)d * TOT + c0]) = hv;
            *reinterpret_cast<ushort4*>(&out_lo[(size_t)d * TOT + c0]) = lv;
        } else {
            float o = accv.x * invden + bias[lane];
            if (ACT) o = o > 0.f ? o : expm1f(o);
            if constexpr (POOL) {
                int g = batch[d];
                atomicAdd(&outf[(size_t)g * 64 + lane], o);
                if (lane == 0) atomicAdd(&gcnt[g], 1);
            } else {
                unsigned short hb, lb;
                splitbf(o, hb, lb);
                out_hi[(size_t)d * TOT + lane] = hb;
                out_lo[(size_t)d * TOT + lane] = lb;
            }
        }
        return;
    }

    // ---- fallback: deg > CAP, serial 3-pass (no LDS) ----
    {
        float adh = ad[head];
        float es = e_self[head];
        float m = es;
        for (int e = p0; e < p1; ++e) {
            int s = csr_src[e];
            m = fmaxf(m, lrelu(al_s[(size_t)s * H + head] + adh));
        }
        float den = __expf(es - m);
        for (int e = p0; e < p1; ++e) {
            int s = csr_src[e];
            den += __expf(lrelu(al_s[(size_t)s * H + head] + adh) - m);
        }
        den = 1.f / den;
        float accv[VEC] = {};
        {
            float alpha = __expf(es - m) * den;
            const unsigned short* hp = hlin + (size_t)d * TOT + lane * VEC;
            #pragma unroll
            for (int v = 0; v < VEC; ++v) accv[v] = alpha * bf2f(hp[v]);
        }
        for (int e = p0; e < p1; ++e) {
            int s = csr_src[e];
            float alpha = __expf(lrelu(al_s[(size_t)s * H + head] + adh) - m) * den;
            const unsigned short* hp = hlin + (size_t)s * TOT + lane * VEC;
            #pragma unroll
            for (int v = 0; v < VEC; ++v) accv[v] += alpha * bf2f(hp[v]);
        }
        #pragma unroll
        for (int v = 0; v < VEC; ++v) {
            int c = lane * VEC + v;
            float o = accv[v] + bias[c];
            if (ACT) o = o > 0.f ? o : expm1f(o);
            accv[v] = o;
        }
        if constexpr (POOL) {
            int g = batch[d];
            atomicAdd(&outf[(size_t)g * 64 + lane], accv[0]);
            if (lane == 0) atomicAdd(&gcnt[g], 1);
        } else {
            #pragma unroll
            for (int v = 0; v < VEC; ++v) {
                unsigned short hb, lb;
                splitbf(accv[v], hb, lb);
                out_hi[(size_t)d * TOT + lane * VEC + v] = hb;
                out_lo[(size_t)d * TOT + lane * VEC + v] = lb;
            }
        }
    }
}

// ---------------- final linear ----------------
__global__ void k_final(const float* __restrict__ gsum, const int* __restrict__ gcnt,
                        const float* __restrict__ lin_w, const float* __restrict__ lin_b,
                        float* __restrict__ out, int Gn) {
    int g = (blockIdx.x * blockDim.x + threadIdx.x) >> 6;
    int lane = threadIdx.x & 63;
    if (g >= Gn) return;
    float cnt = (float)gcnt[g];
    float inv = 1.f / fmaxf(cnt, 1.f);
    float v = gsum[(size_t)g * 64 + lane] * inv * lin_w[lane];
    #pragma unroll
    for (int off = 32; off >= 1; off >>= 1) v += __shfl_xor(v, off);
    if (lane == 0) out[g] = v + lin_b[0];
}

extern "C" void kernel_launch(void* const* d_in, const int* in_sizes, int n_in,
                              void* d_out, int out_size, void* d_ws, size_t ws_size,
                              hipStream_t stream) {
    const float* x    = (const float*)d_in[0];
    const int*   ei   = (const int*)d_in[1];
    const int*   batch= (const int*)d_in[2];
    const float* W1   = (const float*)d_in[3];
    const float* a1s  = (const float*)d_in[4];
    const float* a1d  = (const float*)d_in[5];
    const float* b1   = (const float*)d_in[6];
    const float* W2   = (const float*)d_in[7];
    const float* a2s  = (const float*)d_in[8];
    const float* a2d  = (const float*)d_in[9];
    const float* b2   = (const float*)d_in[10];
    const float* W3   = (const float*)d_in[11];
    const float* a3s  = (const float*)d_in[12];
    const float* a3d  = (const float*)d_in[13];
    const float* b3   = (const float*)d_in[14];
    const float* lw   = (const float*)d_in[15];
    const float* lb   = (const float*)d_in[16];

    int N = in_sizes[0] / 128;
    int E = in_sizes[1] / 2;
    int G = out_size;
    int RT32 = (N + 31) >> 5;      // 32-row tiles (layers 1-2)
    int RT64 = (N + 63) >> 6;      // 64-row tiles (layer 3)
    int Np = ((N + 127) >> 7) * 128;
    int NB = (N + 1023) >> 10;     // scan blocks (<=64 supported)

    char* p = (char*)d_ws;
    auto alloc = [&](size_t bytes) {
        char* r = p;
        p += (bytes + 255) & ~(size_t)255;
        return r;
    };
    unsigned short* hbuf = (unsigned short*)alloc((size_t)Np * 256 * 2);  // bf16 GEMM output
    unsigned short* aggh = (unsigned short*)alloc((size_t)Np * 256 * 2);  // agg out hi plane
    unsigned short* aggl = (unsigned short*)alloc((size_t)Np * 256 * 2);  // agg out lo plane
    unsigned short* pB1h = (unsigned short*)alloc((size_t)128 * 256 * 2);
    unsigned short* pB1l = (unsigned short*)alloc((size_t)128 * 256 * 2);
    unsigned short* pB2h = (unsigned short*)alloc((size_t)256 * 256 * 2);
    unsigned short* pB2l = (unsigned short*)alloc((size_t)256 * 256 * 2);
    unsigned short* pB3h = (unsigned short*)alloc((size_t)256 * 64 * 2);
    unsigned short* pB3l = (unsigned short*)alloc((size_t)256 * 64 * 2);
    float* al_s  = (float*)alloc((size_t)N * 4 * 4);
    float* al_d  = (float*)alloc((size_t)N * 4 * 4);
    int* indptr  = (int*)alloc((size_t)(N + 1) * 4);
    int* counts  = (int*)alloc((size_t)N * 4);
    int* cursor  = (int*)alloc((size_t)N * 4);
    int* lex     = (int*)alloc((size_t)N * 4);
    int* bsums   = (int*)alloc((size_t)256 * 4);
    int* csr     = (int*)alloc((size_t)E * 4);
    float* gsum  = (float*)alloc((size_t)G * 64 * 4);
    int* gcnt    = (int*)alloc((size_t)G * 4);
    if ((size_t)(p - (char*)d_ws) > ws_size) return;  // workspace too small

    hipMemsetAsync(counts, 0, (size_t)N * 4, stream);
    hipMemsetAsync(gsum, 0, (size_t)G * 64 * 4, stream);
    hipMemsetAsync(gcnt, 0, (size_t)G * 4, stream);

    // pack all weight matrices upfront (one fused launch; 14336 pack-slots)
    k_packB3<<<(14336 + 255) / 256, 256, 0, stream>>>(W1, W2, W3,
        pB1h, pB1l, pB2h, pB2l, pB3h, pB3l);

    int eb = (E + 255) / 256;
    k_count<<<eb, 256, 0, stream>>>(ei, E, counts);
    k_scan_local<<<NB, 256, 0, stream>>>(counts, lex, bsums, N);
    k_scan_add<<<(N + 1 + 255) / 256, 256, 0, stream>>>(lex, bsums, indptr, cursor, N, E, NB);
    k_scatter<<<eb, 256, 0, stream>>>(ei, E, cursor, csr);

    int wb = (N * 64 + 255) / 256;   // one wave per node

    // layer 1: 128 -> 256 (H=4, concat, ELU); A = x f32 (CONV); 32-row blocks
    k_mm<2, 1, 4, true, 128><<<dim3(RT32, 1), 256, 0, stream>>>(x, nullptr, nullptr,
        pB1h, pB1l, hbuf, a1s, a1d, al_s, al_d, N, 256);
    k_agg<4, true, false><<<wb, 256, 0, stream>>>(hbuf, al_s, al_d, indptr, csr, b1,
        aggh, aggl, nullptr, nullptr, nullptr, N);

    // layer 2: 256 -> 256 (H=4, concat, ELU); A pre-split; 32-row blocks
    k_mm<2, 1, 4, false, 256><<<dim3(RT32, 1), 256, 0, stream>>>(nullptr, aggh, aggl,
        pB2h, pB2l, hbuf, a2s, a2d, al_s, al_d, N, 256);
    k_agg<4, true, false><<<wb, 256, 0, stream>>>(hbuf, al_s, al_d, indptr, csr, b2,
        aggh, aggl, nullptr, nullptr, nullptr, N);

    // layer 3: 256 -> 64 (H=1, no concat, no act) + fused mean-pool; 64-row blocks
    k_mm<1, 4, 1, false, 256><<<dim3(RT64, 1), 256, 0, stream>>>(nullptr, aggh, aggl,
        pB3h, pB3l, hbuf, a3s, a3d, al_s, al_d, N, 64);
    k_agg<1, false, true><<<wb, 256, 0, stream>>>(hbuf, al_s, al_d, indptr, csr, b3,
        nullptr, nullptr, gsum, batch, gcnt, N);

    int fb = (G * 64 + 255) / 256;
    k_final<<<fb, 256, 0, stream>>>(gsum, gcnt, lw, lb, (float*)d_out, G);
}